// Round 1
// baseline (4139.785 us; speedup 1.0000x reference)
//
#include <hip/hip_runtime.h>
#include <hip/hip_bf16.h>

// ---------------- workspace layout (float offsets) ----------------
#define OFF_WT1   0            // (3,3,3,6,16)        2592
#define OFF_WT2   2592         // (3,3,3,16,32)       13824
#define OFF_WT3   16416        // (3,3,3,32,64)       55296
#define OFF_WIHT  71712        // w_init_h^T  (64,256)   16384
#define OFF_WIH1T 88096        // wih1^T      (64,256)   16384
#define OFF_WI2T  104480       // w_init_h2^T (256,256)  65536
#define OFF_WHH1P 170016       // whh1 bf16 packed [k2][t][2]  (65536 bf16 = 32768 f)
#define OFF_WIH2P 202784
#define OFF_WHH2P 235552
#define OFF_WL1P  268320       // w_lin1 bf16 packed [k2<2592][t][2] (1327104 bf16)
#define OFF_ME    931872       // mean_enc (512,64)
#define OFF_H     964640       // h0  (512,256)
#define OFF_H2    1095712      // h2_0(512,256)
#define OFF_IHC   1226784      // ih_const (512,256)
#define OFF_P1    1357856      // (512,12,36,3,16)
#define OFF_P2    11974688     // (512,6,18,3,32)
#define OFF_P3    17283104     // (512,3,9,3,64)  == flat

// ---------------- prep: weight transposes + bf16 packs ----------------
__global__ __launch_bounds__(256) void prep_kernel(
    const float* __restrict__ w1, const float* __restrict__ w2, const float* __restrict__ w3,
    const float* __restrict__ w_init_h, const float* __restrict__ wih1,
    const float* __restrict__ w_init_h2, const float* __restrict__ whh1,
    const float* __restrict__ wih2, const float* __restrict__ whh2,
    const float* __restrict__ w_lin1, float* __restrict__ ws) {
  int i = blockIdx.x * 256 + threadIdx.x;
  if (i < 2592) {
    int oc = i & 15, r = i >> 4; int ic = r % 6; r /= 6;
    int kw = r % 3; r /= 3; int kh = r % 3; int kd = r / 3;
    ws[OFF_WT1 + i] = w1[(((oc*6+ic)*3+kd)*3+kh)*3+kw];
    return;
  }
  i -= 2592;
  if (i < 13824) {
    int oc = i & 31, r = i >> 5; int ic = r & 15; r >>= 4;
    int kw = r % 3; r /= 3; int kh = r % 3; int kd = r / 3;
    ws[OFF_WT2 + i] = w2[(((oc*16+ic)*3+kd)*3+kh)*3+kw];
    return;
  }
  i -= 13824;
  if (i < 55296) {
    int oc = i & 63, r = i >> 6; int ic = r & 31; r >>= 5;
    int kw = r % 3; r /= 3; int kh = r % 3; int kd = r / 3;
    ws[OFF_WT3 + i] = w3[(((oc*32+ic)*3+kd)*3+kh)*3+kw];
    return;
  }
  i -= 55296;
  if (i < 16384) { int t = i & 255, k = i >> 8; ws[OFF_WIHT + i]  = w_init_h[t*64 + k];  return; }
  i -= 16384;
  if (i < 16384) { int t = i & 255, k = i >> 8; ws[OFF_WIH1T + i] = wih1[t*64 + k];      return; }
  i -= 16384;
  if (i < 65536) { int t = i & 255, k = i >> 8; ws[OFF_WI2T + i]  = w_init_h2[t*256 + k]; return; }
  i -= 65536;
  if (i < 65536) {
    int j = i & 1, t = (i >> 1) & 255, k2 = i >> 9;
    ((__hip_bfloat16*)(ws + OFF_WHH1P))[i] = __float2bfloat16(whh1[t*256 + 2*k2 + j]);
    return;
  }
  i -= 65536;
  if (i < 65536) {
    int j = i & 1, t = (i >> 1) & 255, k2 = i >> 9;
    ((__hip_bfloat16*)(ws + OFF_WIH2P))[i] = __float2bfloat16(wih2[t*256 + 2*k2 + j]);
    return;
  }
  i -= 65536;
  if (i < 65536) {
    int j = i & 1, t = (i >> 1) & 255, k2 = i >> 9;
    ((__hip_bfloat16*)(ws + OFF_WHH2P))[i] = __float2bfloat16(whh2[t*256 + 2*k2 + j]);
    return;
  }
  i -= 65536;
  if (i < 1327104) {
    int j = i & 1, t = (i >> 1) & 255, k2 = i >> 9;
    ((__hip_bfloat16*)(ws + OFF_WL1P))[i] = __float2bfloat16(w_lin1[t*5184 + 2*k2 + j]);
    return;
  }
}

// ---------------- conv1 + relu + pool:  x NCDHW (512,6,24,72,3) -> p1 (512,12,36,3,16) CL
__global__ __launch_bounds__(256) void conv1_kernel(
    const float* __restrict__ x, const float* __restrict__ wt,
    const float* __restrict__ bias, float* __restrict__ p1) {
  int t = blockIdx.x * 256 + threadIdx.x;            // 512*12*36 = 221184
  int ph = t % 36; int r = t / 36; int pd = r % 12; int b = r / 12;
  float best[48];                                    // [oc16][w3]
  #pragma unroll
  for (int i = 0; i < 48; ++i) best[i] = -1e30f;
  #pragma unroll 1
  for (int dd = 0; dd < 2; ++dd) {
    #pragma unroll 1
    for (int dh = 0; dh < 2; ++dh) {
      float acc[48];
      #pragma unroll
      for (int i = 0; i < 48; ++i) acc[i] = 0.f;
      int d0 = 2*pd + dd, h0 = 2*ph + dh;
      #pragma unroll 1
      for (int ic = 0; ic < 6; ++ic) {
        const float* xb = x + (size_t)(b*6 + ic) * 5184;
        #pragma unroll
        for (int kd = 0; kd < 3; ++kd) {
          int d = d0 + kd - 1;
          bool okd = (unsigned)d < 24u;
          int dc = okd ? d : 0;
          #pragma unroll
          for (int kh = 0; kh < 3; ++kh) {
            int h = h0 + kh - 1;
            bool ok = okd && ((unsigned)h < 72u);
            int hc = ((unsigned)h < 72u) ? h : 0;
            const float* row = xb + (dc*72 + hc) * 3;
            float x0 = row[0], x1 = row[1], x2 = row[2];
            x0 = ok ? x0 : 0.f; x1 = ok ? x1 : 0.f; x2 = ok ? x2 : 0.f;
            const float* wp = wt + (kd*3 + kh)*3*96 + ic*16;  // [kw][ic][16]
            #pragma unroll
            for (int oc = 0; oc < 16; ++oc) {
              float wk0 = wp[oc], wk1 = wp[96 + oc], wk2 = wp[192 + oc];
              acc[oc*3+0] += x0*wk1 + x1*wk2;
              acc[oc*3+1] += x0*wk0 + x1*wk1 + x2*wk2;
              acc[oc*3+2] += x1*wk0 + x2*wk1;
            }
          }
        }
      }
      #pragma unroll
      for (int i = 0; i < 48; ++i) best[i] = fmaxf(best[i], acc[i]);
    }
  }
  float* op = p1 + ((size_t)(b*12 + pd)*36 + ph) * 48;
  #pragma unroll
  for (int w = 0; w < 3; ++w) {
    float4 o0, o1, o2, o3;
    o0.x = fmaxf(best[0*3+w]  + bias[0],  0.f); o0.y = fmaxf(best[1*3+w]  + bias[1],  0.f);
    o0.z = fmaxf(best[2*3+w]  + bias[2],  0.f); o0.w = fmaxf(best[3*3+w]  + bias[3],  0.f);
    o1.x = fmaxf(best[4*3+w]  + bias[4],  0.f); o1.y = fmaxf(best[5*3+w]  + bias[5],  0.f);
    o1.z = fmaxf(best[6*3+w]  + bias[6],  0.f); o1.w = fmaxf(best[7*3+w]  + bias[7],  0.f);
    o2.x = fmaxf(best[8*3+w]  + bias[8],  0.f); o2.y = fmaxf(best[9*3+w]  + bias[9],  0.f);
    o2.z = fmaxf(best[10*3+w] + bias[10], 0.f); o2.w = fmaxf(best[11*3+w] + bias[11], 0.f);
    o3.x = fmaxf(best[12*3+w] + bias[12], 0.f); o3.y = fmaxf(best[13*3+w] + bias[13], 0.f);
    o3.z = fmaxf(best[14*3+w] + bias[14], 0.f); o3.w = fmaxf(best[15*3+w] + bias[15], 0.f);
    float4* o4 = (float4*)(op + w*16);
    o4[0] = o0; o4[1] = o1; o4[2] = o2; o4[3] = o3;
  }
}

// ---------------- conv2 + relu + pool:  p1 (512,12,36,3,16) -> p2 (512,6,18,3,32)
__global__ __launch_bounds__(256) void conv2_kernel(
    const float* __restrict__ p1, const float* __restrict__ wt,
    const float* __restrict__ bias, float* __restrict__ p2) {
  int t = blockIdx.x * 256 + threadIdx.x;            // 512*6*18 = 55296
  int ph = t % 18; int r = t / 18; int pd = r % 6; int b = r / 6;
  int ocb = blockIdx.y * 16;
  float best[48];                                    // [oc16][w3]
  #pragma unroll
  for (int i = 0; i < 48; ++i) best[i] = -1e30f;
  #pragma unroll 1
  for (int dd = 0; dd < 2; ++dd) {
    #pragma unroll 1
    for (int dh = 0; dh < 2; ++dh) {
      float acc[48];
      #pragma unroll
      for (int i = 0; i < 48; ++i) acc[i] = 0.f;
      int d0 = 2*pd + dd, h0 = 2*ph + dh;
      #pragma unroll 1
      for (int kd = 0; kd < 3; ++kd) {
        int d = d0 + kd - 1;
        bool okd = (unsigned)d < 12u;
        int dc = okd ? d : 0;
        #pragma unroll 1
        for (int kh = 0; kh < 3; ++kh) {
          int h = h0 + kh - 1;
          bool ok = okd && ((unsigned)h < 36u);
          int hc = ((unsigned)h < 36u) ? h : 0;
          const float* ip = p1 + ((size_t)(b*12 + dc)*36 + hc) * 48;
          const float* wb = wt + (kd*3 + kh)*3*512 + ocb;
          #pragma unroll
          for (int wc = 0; wc < 3; ++wc) {
            const float4* q = (const float4*)(ip + wc*16);
            float4 v0 = q[0], v1 = q[1], v2 = q[2], v3 = q[3];
            float in16[16];
            in16[0]=v0.x; in16[1]=v0.y; in16[2]=v0.z; in16[3]=v0.w;
            in16[4]=v1.x; in16[5]=v1.y; in16[6]=v1.z; in16[7]=v1.w;
            in16[8]=v2.x; in16[9]=v2.y; in16[10]=v2.z; in16[11]=v2.w;
            in16[12]=v3.x; in16[13]=v3.y; in16[14]=v3.z; in16[15]=v3.w;
            #pragma unroll
            for (int ii = 0; ii < 16; ++ii) in16[ii] = ok ? in16[ii] : 0.f;
            #pragma unroll
            for (int ic = 0; ic < 16; ++ic) {
              float xv = in16[ic];
              #pragma unroll
              for (int kw = 0; kw < 3; ++kw) {
                int w = wc + 1 - kw;
                if (w >= 0 && w < 3) {
                  const float* wr = wb + kw*512 + ic*32;
                  #pragma unroll
                  for (int oc = 0; oc < 16; ++oc)
                    acc[oc*3+w] += xv * wr[oc];
                }
              }
            }
          }
        }
      }
      #pragma unroll
      for (int i = 0; i < 48; ++i) best[i] = fmaxf(best[i], acc[i]);
    }
  }
  float* op = p2 + ((size_t)(b*6 + pd)*18 + ph) * 96 + ocb;
  #pragma unroll
  for (int w = 0; w < 3; ++w) {
    float ov[16];
    #pragma unroll
    for (int oc = 0; oc < 16; ++oc) ov[oc] = fmaxf(best[oc*3+w] + bias[ocb+oc], 0.f);
    float4* o4 = (float4*)(op + w*32);
    float4 q0, q1, q2, q3;
    q0.x=ov[0]; q0.y=ov[1]; q0.z=ov[2]; q0.w=ov[3];
    q1.x=ov[4]; q1.y=ov[5]; q1.z=ov[6]; q1.w=ov[7];
    q2.x=ov[8]; q2.y=ov[9]; q2.z=ov[10]; q2.w=ov[11];
    q3.x=ov[12]; q3.y=ov[13]; q3.z=ov[14]; q3.w=ov[15];
    o4[0]=q0; o4[1]=q1; o4[2]=q2; o4[3]=q3;
  }
}

// ---------------- conv3 + relu + pool:  p2 (512,6,18,3,32) -> p3 (512,3,9,3,64)
__global__ __launch_bounds__(256) void conv3_kernel(
    const float* __restrict__ p2, const float* __restrict__ wt,
    const float* __restrict__ bias, float* __restrict__ p3) {
  int t = blockIdx.x * 256 + threadIdx.x;            // 512*3*9 = 13824
  int ph = t % 9; int r = t / 9; int pd = r % 3; int b = r / 3;
  int ocb = blockIdx.y * 8;
  float best[24];                                    // [oc8][w3]
  #pragma unroll
  for (int i = 0; i < 24; ++i) best[i] = -1e30f;
  #pragma unroll 1
  for (int dd = 0; dd < 2; ++dd) {
    #pragma unroll 1
    for (int dh = 0; dh < 2; ++dh) {
      float acc[24];
      #pragma unroll
      for (int i = 0; i < 24; ++i) acc[i] = 0.f;
      int d0 = 2*pd + dd, h0 = 2*ph + dh;
      #pragma unroll 1
      for (int kd = 0; kd < 3; ++kd) {
        int d = d0 + kd - 1;
        bool okd = (unsigned)d < 6u;
        int dc = okd ? d : 0;
        #pragma unroll 1
        for (int kh = 0; kh < 3; ++kh) {
          int h = h0 + kh - 1;
          bool ok = okd && ((unsigned)h < 18u);
          int hc = ((unsigned)h < 18u) ? h : 0;
          const float* ip = p2 + ((size_t)(b*6 + dc)*18 + hc) * 96;
          const float* wb = wt + (kd*3 + kh)*3*2048 + ocb;
          #pragma unroll
          for (int wc = 0; wc < 3; ++wc) {
            const float4* q = (const float4*)(ip + wc*32);
            float in32[32];
            #pragma unroll
            for (int v = 0; v < 8; ++v) {
              float4 vv = q[v];
              in32[v*4+0]=vv.x; in32[v*4+1]=vv.y; in32[v*4+2]=vv.z; in32[v*4+3]=vv.w;
            }
            #pragma unroll
            for (int ii = 0; ii < 32; ++ii) in32[ii] = ok ? in32[ii] : 0.f;
            #pragma unroll
            for (int ic = 0; ic < 32; ++ic) {
              float xv = in32[ic];
              #pragma unroll
              for (int kw = 0; kw < 3; ++kw) {
                int w = wc + 1 - kw;
                if (w >= 0 && w < 3) {
                  const float* wr = wb + kw*2048 + ic*64;
                  #pragma unroll
                  for (int oc = 0; oc < 8; ++oc)
                    acc[oc*3+w] += xv * wr[oc];
                }
              }
            }
          }
        }
      }
      #pragma unroll
      for (int i = 0; i < 24; ++i) best[i] = fmaxf(best[i], acc[i]);
    }
  }
  float* op = p3 + ((size_t)(b*3 + pd)*9 + ph) * 192 + ocb;
  #pragma unroll
  for (int w = 0; w < 3; ++w) {
    float4 q0, q1;
    q0.x = fmaxf(best[0*3+w] + bias[ocb+0], 0.f);
    q0.y = fmaxf(best[1*3+w] + bias[ocb+1], 0.f);
    q0.z = fmaxf(best[2*3+w] + bias[ocb+2], 0.f);
    q0.w = fmaxf(best[3*3+w] + bias[ocb+3], 0.f);
    q1.x = fmaxf(best[4*3+w] + bias[ocb+4], 0.f);
    q1.y = fmaxf(best[5*3+w] + bias[ocb+5], 0.f);
    q1.z = fmaxf(best[6*3+w] + bias[ocb+6], 0.f);
    q1.w = fmaxf(best[7*3+w] + bias[ocb+7], 0.f);
    float4* o4 = (float4*)(op + w*64);
    o4[0] = q0; o4[1] = q1;
  }
}

// ---------------- mean over 81 positions ----------------
__global__ __launch_bounds__(256) void mean_kernel(const float* __restrict__ p3,
                                                   float* __restrict__ me) {
  int i = blockIdx.x * 256 + threadIdx.x;            // 512*64
  int c = i & 63; int b = i >> 6;
  const float* p = p3 + (size_t)b * 5184 + c;
  float s = 0.f;
  #pragma unroll 1
  for (int q = 0; q < 81; ++q) s += p[q*64];
  me[i] = s * (1.f / 81.f);
}

// ---------------- initial projections: h0, h2_0, ih_const ----------------
__global__ __launch_bounds__(256) void init_kernel(
    const float* __restrict__ me, const float* __restrict__ wiht,
    const float* __restrict__ b_init_h, const float* __restrict__ wih1t,
    const float* __restrict__ bih1, const float* __restrict__ bhh1,
    const float* __restrict__ wi2t, const float* __restrict__ b_init_h2,
    float* __restrict__ hout, float* __restrict__ h2out, float* __restrict__ ihcout) {
  __shared__ float sme[64];
  __shared__ float shl[256];
  int b = blockIdx.x, t = threadIdx.x;
  if (t < 64) sme[t] = me[b*64 + t];
  __syncthreads();
  float a = b_init_h[t];
  float cc = bih1[t] + bhh1[t];
  #pragma unroll 1
  for (int k = 0; k < 64; ++k) {
    float m = sme[k];
    a  += m * wiht[k*256 + t];
    cc += m * wih1t[k*256 + t];
  }
  hout[b*256 + t] = a; ihcout[b*256 + t] = cc; shl[t] = a;
  __syncthreads();
  float a2 = b_init_h2[t];
  #pragma unroll 1
  for (int k = 0; k < 256; ++k) a2 += shl[k] * wi2t[k*256 + t];
  h2out[b*256 + t] = a2;
}

// ---------------- 23-step 2-layer tanh RNN, 4 batch rows / block ----------------
__global__ __launch_bounds__(256) void rnn_kernel(
    const float* __restrict__ hin, const float* __restrict__ h2in,
    const float* __restrict__ ihc,
    const unsigned int* __restrict__ w1u, const unsigned int* __restrict__ w2u,
    const unsigned int* __restrict__ w3u,
    const float* __restrict__ bih2, const float* __restrict__ bhh2,
    const float* __restrict__ w_fc, const float* __restrict__ b_fc,
    float* __restrict__ preds) {
  __shared__ float sh[4][256], sh2[4][256];
  __shared__ float sred[4][4];
  int t = threadIdx.x; int bb = blockIdx.x * 4;
  int lane = t & 63, wid = t >> 6;
  float ihr[4];
  #pragma unroll
  for (int r = 0; r < 4; ++r) {
    sh[r][t]  = hin[(bb+r)*256 + t];
    sh2[r][t] = h2in[(bb+r)*256 + t];
    ihr[r]    = ihc[(bb+r)*256 + t];
  }
  float bias2 = bih2[t] + bhh2[t];
  float wfc = w_fc[t];
  float bfc = b_fc[0];
  __syncthreads();
  #pragma unroll 1
  for (int step = 0; step < 23; ++step) {
    float a[4] = {ihr[0], ihr[1], ihr[2], ihr[3]};
    #pragma unroll 2
    for (int k = 0; k < 256; k += 4) {
      int k2 = k >> 1;
      unsigned int ua = w1u[k2*256 + t];
      unsigned int ub = w1u[(k2+1)*256 + t];
      float w0 = __uint_as_float(ua << 16), w1 = __uint_as_float(ua & 0xffff0000u);
      float w2 = __uint_as_float(ub << 16), w3 = __uint_as_float(ub & 0xffff0000u);
      #pragma unroll
      for (int r = 0; r < 4; ++r) {
        float4 hv = *(const float4*)&sh[r][k];
        a[r] += hv.x*w0 + hv.y*w1 + hv.z*w2 + hv.w*w3;
      }
    }
    float hn[4];
    #pragma unroll
    for (int r = 0; r < 4; ++r) hn[r] = tanhf(a[r]);
    __syncthreads();
    #pragma unroll
    for (int r = 0; r < 4; ++r) sh[r][t] = hn[r];
    __syncthreads();
    float c[4] = {bias2, bias2, bias2, bias2};
    #pragma unroll 2
    for (int k = 0; k < 256; k += 4) {
      int k2 = k >> 1;
      unsigned int ua = w2u[k2*256 + t], ub = w2u[(k2+1)*256 + t];
      unsigned int va = w3u[k2*256 + t], vb = w3u[(k2+1)*256 + t];
      float i0 = __uint_as_float(ua << 16), i1 = __uint_as_float(ua & 0xffff0000u);
      float i2 = __uint_as_float(ub << 16), i3 = __uint_as_float(ub & 0xffff0000u);
      float g0 = __uint_as_float(va << 16), g1 = __uint_as_float(va & 0xffff0000u);
      float g2 = __uint_as_float(vb << 16), g3 = __uint_as_float(vb & 0xffff0000u);
      #pragma unroll
      for (int r = 0; r < 4; ++r) {
        float4 xv = *(const float4*)&sh[r][k];
        float4 yv = *(const float4*)&sh2[r][k];
        c[r] += xv.x*i0 + xv.y*i1 + xv.z*i2 + xv.w*i3
              + yv.x*g0 + yv.y*g1 + yv.z*g2 + yv.w*g3;
      }
    }
    float h2n[4];
    #pragma unroll
    for (int r = 0; r < 4; ++r) h2n[r] = tanhf(c[r]);
    __syncthreads();
    #pragma unroll
    for (int r = 0; r < 4; ++r) sh2[r][t] = h2n[r];
    #pragma unroll
    for (int r = 0; r < 4; ++r) {
      float v = h2n[r] * wfc;
      #pragma unroll
      for (int off = 32; off > 0; off >>= 1) v += __shfl_down(v, off, 64);
      if (lane == 0) sred[wid][r] = v;
    }
    __syncthreads();
    if (t < 4) {
      float s = sred[0][t] + sred[1][t] + sred[2][t] + sred[3][t] + bfc;
      preds[(size_t)(bb + t)*23 + step] = s;
    }
  }
}

// ---------------- lin1 + tanh + lin2 (2 batch rows / block) ----------------
__global__ __launch_bounds__(256) void lin_kernel(
    const float* __restrict__ p3, const unsigned int* __restrict__ wl1u,
    const float* __restrict__ b_lin1, const float* __restrict__ w_lin2,
    const float* __restrict__ b_lin2, float* __restrict__ outc) {
  __shared__ float sflat[2][5184];
  __shared__ float st1[2][256];
  int t = threadIdx.x; int bb = blockIdx.x * 2;
  #pragma unroll
  for (int r = 0; r < 2; ++r)
    for (int i = t; i < 5184; i += 256)
      sflat[r][i] = p3[(size_t)(bb + r)*5184 + i];
  __syncthreads();
  float a0 = b_lin1[t], a1 = a0;
  #pragma unroll 2
  for (int k2 = 0; k2 < 2592; ++k2) {
    unsigned int u = wl1u[k2*256 + t];
    float w0 = __uint_as_float(u << 16), w1 = __uint_as_float(u & 0xffff0000u);
    float2 f0 = *(const float2*)&sflat[0][2*k2];
    float2 f1 = *(const float2*)&sflat[1][2*k2];
    a0 += f0.x*w0 + f0.y*w1;
    a1 += f1.x*w0 + f1.y*w1;
  }
  st1[0][t] = tanhf(a0);
  st1[1][t] = tanhf(a1);
  __syncthreads();
  if (t < 24) {
    int r = t / 12, j = t % 12;
    float s = b_lin2[j];
    #pragma unroll 1
    for (int k = 0; k < 256; ++k) s += st1[r][k] * w_lin2[j*256 + k];
    outc[(size_t)(bb + r)*12 + j] = s;
  }
}

// ---------------- launch ----------------
extern "C" void kernel_launch(void* const* d_in, const int* in_sizes, int n_in,
                              void* d_out, int out_size, void* d_ws, size_t ws_size,
                              hipStream_t stream) {
  const float* x         = (const float*)d_in[0];
  const float* w1        = (const float*)d_in[1];
  const float* b1        = (const float*)d_in[2];
  const float* w2        = (const float*)d_in[3];
  const float* b2        = (const float*)d_in[4];
  const float* w3        = (const float*)d_in[5];
  const float* b3        = (const float*)d_in[6];
  const float* wih1      = (const float*)d_in[7];
  const float* whh1      = (const float*)d_in[8];
  const float* bih1      = (const float*)d_in[9];
  const float* bhh1      = (const float*)d_in[10];
  const float* wih2      = (const float*)d_in[11];
  const float* whh2      = (const float*)d_in[12];
  const float* bih2      = (const float*)d_in[13];
  const float* bhh2      = (const float*)d_in[14];
  const float* w_init_h  = (const float*)d_in[15];
  const float* b_init_h  = (const float*)d_in[16];
  const float* w_init_h2 = (const float*)d_in[17];
  const float* b_init_h2 = (const float*)d_in[18];
  const float* w_fc      = (const float*)d_in[19];
  const float* b_fc      = (const float*)d_in[20];
  const float* w_lin1    = (const float*)d_in[21];
  const float* b_lin1    = (const float*)d_in[22];
  const float* w_lin2    = (const float*)d_in[23];
  const float* b_lin2    = (const float*)d_in[24];
  float* ws  = (float*)d_ws;
  float* out = (float*)d_out;

  prep_kernel<<<6617, 256, 0, stream>>>(w1, w2, w3, w_init_h, wih1, w_init_h2,
                                        whh1, wih2, whh2, w_lin1, ws);
  conv1_kernel<<<864, 256, 0, stream>>>(x, ws + OFF_WT1, b1, ws + OFF_P1);
  conv2_kernel<<<dim3(216, 2), 256, 0, stream>>>(ws + OFF_P1, ws + OFF_WT2, b2, ws + OFF_P2);
  conv3_kernel<<<dim3(54, 8), 256, 0, stream>>>(ws + OFF_P2, ws + OFF_WT3, b3, ws + OFF_P3);
  mean_kernel<<<128, 256, 0, stream>>>(ws + OFF_P3, ws + OFF_ME);
  init_kernel<<<512, 256, 0, stream>>>(ws + OFF_ME, ws + OFF_WIHT, b_init_h, ws + OFF_WIH1T,
                                       bih1, bhh1, ws + OFF_WI2T, b_init_h2,
                                       ws + OFF_H, ws + OFF_H2, ws + OFF_IHC);
  rnn_kernel<<<128, 256, 0, stream>>>(ws + OFF_H, ws + OFF_H2, ws + OFF_IHC,
                                      (const unsigned int*)(ws + OFF_WHH1P),
                                      (const unsigned int*)(ws + OFF_WIH2P),
                                      (const unsigned int*)(ws + OFF_WHH2P),
                                      bih2, bhh2, w_fc, b_fc, out);
  lin_kernel<<<256, 256, 0, stream>>>(ws + OFF_P3, (const unsigned int*)(ws + OFF_WL1P),
                                      b_lin1, w_lin2, b_lin2, out + 11776);
}

// Round 2
// 1230.302 us; speedup vs baseline: 3.3649x; 3.3649x over previous
//
#include <hip/hip_runtime.h>
#include <hip/hip_bf16.h>

typedef __attribute__((ext_vector_type(8))) short short8;
typedef __attribute__((ext_vector_type(4))) float floatx4;

// ---------------- workspace layout (float offsets) ----------------
#define OFF_B1P   0        // conv1 B frags [7][64][8] bf16        = 1792 f
#define OFF_B2P   1792     // conv2 B frags [2][14][64][8] bf16    = 7168 f
#define OFF_B3P   8960     // conv3 B frags [4][27][64][8] bf16    = 27648 f
#define OFF_WIHT  36608    // w_init_h^T  (64,256)
#define OFF_WIH1T 52992    // wih1^T      (64,256)
#define OFF_WI2T  69376    // w_init_h2^T (256,256)
#define OFF_WHH1P 134912   // whh1 bf16 packed [k2][t][2]
#define OFF_WIH2P 167680
#define OFF_WHH2P 200448
#define OFF_WL1P  233216   // w_lin1 bf16 packed [k2][t][2]
#define OFF_ME    896768   // mean_enc (512,64)
#define OFF_H     929536   // h0  (512,256)
#define OFF_H2    1060608  // h2_0(512,256)
#define OFF_IHC   1191680  // ih_const (512,256)
#define OFF_P1    1322752  // p1 bf16 [512][1296][16]  (10616832 bf16)
#define OFF_P3    6631168  // p3 fp32 [512][81][64] == flat

static __device__ inline short f2bf(float f) {
  union { __hip_bfloat16 h; short s; } u;
  u.h = __float2bfloat16(f);
  return u.s;
}

// ---------------- prep: weight frag packs + RNN/linear packs ----------------
__global__ __launch_bounds__(256) void prep_kernel(
    const float* __restrict__ w1, const float* __restrict__ w2, const float* __restrict__ w3,
    const float* __restrict__ w_init_h, const float* __restrict__ wih1,
    const float* __restrict__ w_init_h2, const float* __restrict__ whh1,
    const float* __restrict__ wih2, const float* __restrict__ whh2,
    const float* __restrict__ w_lin1, float* __restrict__ ws) {
  int i = blockIdx.x * 256 + threadIdx.x;
  // conv1 B: k = tap*8 + icp (K=224, 7 chunks), value w1[oc, icp, tap]
  if (i < 3584) {
    int j = i & 7, l = (i >> 3) & 63, c = i >> 9;
    int k = c*32 + ((l >> 4) << 3) + j;
    int tap = k >> 3, icp = k & 7, oc = l & 15;
    float v = (tap < 27 && icp < 6) ? w1[(oc*6 + icp)*27 + tap] : 0.f;
    ((__hip_bfloat16*)(ws + OFF_B1P))[i] = __float2bfloat16(v);
    return;
  }
  i -= 3584;
  // conv2 B: k = tap*16 + ic (K=448, 14 chunks), layout [nt][c][l][j]
  if (i < 14336) {
    int j = i & 7, l = (i >> 3) & 63, cc = i >> 9;
    int c = cc % 14, nt = cc / 14;
    int k = c*32 + ((l >> 4) << 3) + j;
    int tap = k >> 4, ic = k & 15, oc = nt*16 + (l & 15);
    float v = (tap < 27) ? w2[(oc*16 + ic)*27 + tap] : 0.f;
    ((__hip_bfloat16*)(ws + OFF_B2P))[i] = __float2bfloat16(v);
    return;
  }
  i -= 14336;
  // conv3 B: k = tap*32 + ic (K=864, 27 chunks), layout [nt][c][l][j]
  if (i < 55296) {
    int j = i & 7, l = (i >> 3) & 63, cc = i >> 9;
    int c = cc % 27, nt = cc / 27;
    int k = c*32 + ((l >> 4) << 3) + j;
    int ic = k & 31, oc = nt*16 + (l & 15);
    ((__hip_bfloat16*)(ws + OFF_B3P))[i] = __float2bfloat16(w3[(oc*32 + ic)*27 + c]);
    return;
  }
  i -= 55296;
  if (i < 16384) { int t = i & 255, k = i >> 8; ws[OFF_WIHT + i]  = w_init_h[t*64 + k];  return; }
  i -= 16384;
  if (i < 16384) { int t = i & 255, k = i >> 8; ws[OFF_WIH1T + i] = wih1[t*64 + k];      return; }
  i -= 16384;
  if (i < 65536) { int t = i & 255, k = i >> 8; ws[OFF_WI2T + i]  = w_init_h2[t*256 + k]; return; }
  i -= 65536;
  if (i < 65536) {
    int j = i & 1, t = (i >> 1) & 255, k2 = i >> 9;
    ((__hip_bfloat16*)(ws + OFF_WHH1P))[i] = __float2bfloat16(whh1[t*256 + 2*k2 + j]);
    return;
  }
  i -= 65536;
  if (i < 65536) {
    int j = i & 1, t = (i >> 1) & 255, k2 = i >> 9;
    ((__hip_bfloat16*)(ws + OFF_WIH2P))[i] = __float2bfloat16(wih2[t*256 + 2*k2 + j]);
    return;
  }
  i -= 65536;
  if (i < 65536) {
    int j = i & 1, t = (i >> 1) & 255, k2 = i >> 9;
    ((__hip_bfloat16*)(ws + OFF_WHH2P))[i] = __float2bfloat16(whh2[t*256 + 2*k2 + j]);
    return;
  }
  i -= 65536;
  if (i < 1327104) {
    int j = i & 1, t = (i >> 1) & 255, k2 = i >> 9;
    ((__hip_bfloat16*)(ws + OFF_WL1P))[i] = __float2bfloat16(w_lin1[t*5184 + 2*k2 + j]);
    return;
  }
}

// ---------------- conv1 MFMA: x (512,6,24,72,3) fp32 -> p1 bf16 [b][1296][16]
// block = (b, dhalf). M-order: m = P*4 + dh*2 + dd, P = (pdl*36+ph)*3+w.
__global__ __launch_bounds__(256) void conv1_mfma(
    const float* __restrict__ x, const short* __restrict__ b1p,
    const float* __restrict__ bias, short* __restrict__ p1) {
  __shared__ __align__(16) short slab[13 * 216 * 8];  // [dslot][h*3+w][ic8] 44928 B
  int tid = threadIdx.x;
  int b = blockIdx.x >> 1, dhalf = blockIdx.x & 1;
  int dbase = dhalf * 11;
  for (int i = tid; i < 11232; i += 256) ((unsigned*)slab)[i] = 0u;
  __syncthreads();
  for (int i = tid; i < 6 * 13 * 216; i += 256) {
    int ic = i / 2808, r = i % 2808;
    int dslot = r / 216, pos = r % 216;
    float v = x[((size_t)(b*6 + ic)*24 + dbase + dslot)*216 + pos];
    slab[(dslot*216 + pos)*8 + ic] = f2bf(v);
  }
  int lane = tid & 63, wid = tid >> 6;
  int qd = lane >> 4, col = lane & 15;
  short8 bf[7];
  #pragma unroll
  for (int c = 0; c < 7; ++c) bf[c] = *(const short8*)(b1p + (c*64 + lane)*8);
  int kdm1[7], khm1[7], kwm1[7]; bool tv[7];
  #pragma unroll
  for (int c = 0; c < 7; ++c) {
    int tap = c*4 + qd;
    tv[c] = tap < 27;
    int tt = tv[c] ? tap : 0;
    kwm1[c] = tt % 3 - 1; khm1[c] = (tt/3) % 3 - 1; kdm1[c] = tt/9 - 1;
  }
  float bv = bias[col];
  __syncthreads();
  for (int tile = wid; tile < 162; tile += 4) {
    int m = tile*16 + (lane & 15);
    int dd = m & 1, dh = (m >> 1) & 1;
    int P = m >> 2;
    int w = P % 3, t2 = P / 3;
    int ph = t2 % 36, pdl = t2 / 36;
    int ds0 = 2*(dhalf*6 + pdl) + dd - dbase;  // slot-space (kd=1 base)
    int h0 = 2*ph + dh;
    floatx4 acc = {0.f, 0.f, 0.f, 0.f};
    #pragma unroll
    for (int c = 0; c < 7; ++c) {
      int dslot = ds0 + kdm1[c];
      int hh = h0 + khm1[c];
      int wi = w + kwm1[c];
      bool valid = tv[c] && ((unsigned)dslot < 13u) && ((unsigned)hh < 72u) && ((unsigned)wi < 3u);
      int a2 = valid ? ((dslot*216 + hh*3 + wi) * 8) : 0;
      short8 af = *(const short8*)(slab + a2);
      short8 z = {0,0,0,0,0,0,0,0};
      af = valid ? af : z;
      acc = __builtin_amdgcn_mfma_f32_16x16x32_bf16(af, bf[c], acc, 0, 0, 0);
    }
    float v = fmaxf(fmaxf(acc[0], acc[1]), fmaxf(acc[2], acc[3]));
    v = fmaxf(v + bv, 0.f);
    int Pout = dhalf*648 + tile*4 + qd;
    p1[((size_t)b*1296 + Pout)*16 + col] = f2bf(v);
  }
}

// ---------------- fused conv2+conv3 MFMA per batch: p1 bf16 -> p3 fp32 [b][81][64]
__global__ __launch_bounds__(256) void conv23_mfma(
    const short* __restrict__ p1, const short* __restrict__ b2p,
    const short* __restrict__ b3p,
    const float* __restrict__ bias2, const float* __restrict__ bias3,
    float* __restrict__ p3) {
  __shared__ __align__(16) short p1s[20736];  // [P1296][ic16] 41472 B
  __shared__ __align__(16) short p2s[10368];  // [P324][ic32]  20736 B
  int tid = threadIdx.x;
  int b = blockIdx.x;
  int lane = tid & 63, wid = tid >> 6;
  int qd = lane >> 4, col = lane & 15;
  const short* p1b = p1 + (size_t)b * 20736;
  for (int i = tid; i < 2592; i += 256)
    *(short8*)(p1s + i*8) = *(const short8*)(p1b + i*8);

  // ---- conv2: wave -> ntile = wid&1, tiles strided by 2 ----
  int nt2 = wid & 1;
  short8 bf2[14];
  #pragma unroll
  for (int c = 0; c < 14; ++c)
    bf2[c] = *(const short8*)(b2p + ((nt2*14 + c)*64 + lane)*8);
  int kdm1[14], khm1[14], kwm1[14]; bool tv2[14];
  #pragma unroll
  for (int c = 0; c < 14; ++c) {
    int tap = c*2 + (qd >> 1);
    tv2[c] = tap < 27;
    int tt = tv2[c] ? tap : 0;
    kwm1[c] = tt % 3 - 1; khm1[c] = (tt/3) % 3 - 1; kdm1[c] = tt/9 - 1;
  }
  int ic02 = (qd & 1) * 8;
  float bv2 = bias2[nt2*16 + col];
  __syncthreads();
  for (int tile = (wid >> 1); tile < 81; tile += 2) {
    int m = tile*16 + (lane & 15);
    int dd = m & 1, dh = (m >> 1) & 1;
    int P = m >> 2;
    int w = P % 3, t2 = P / 3;
    int ph = t2 % 18, pd = t2 / 18;
    int d0 = 2*pd + dd, h0 = 2*ph + dh;
    floatx4 acc = {0.f, 0.f, 0.f, 0.f};
    #pragma unroll
    for (int c = 0; c < 14; ++c) {
      int d = d0 + kdm1[c], h = h0 + khm1[c], wi = w + kwm1[c];
      bool valid = tv2[c] && ((unsigned)d < 12u) && ((unsigned)h < 36u) && ((unsigned)wi < 3u);
      int a2 = valid ? (((d*36 + h)*3 + wi)*16 + ic02) : 0;
      short8 af = *(const short8*)(p1s + a2);
      short8 z = {0,0,0,0,0,0,0,0};
      af = valid ? af : z;
      acc = __builtin_amdgcn_mfma_f32_16x16x32_bf16(af, bf2[c], acc, 0, 0, 0);
    }
    float v = fmaxf(fmaxf(acc[0], acc[1]), fmaxf(acc[2], acc[3]));
    v = fmaxf(v + bv2, 0.f);
    int Pout = tile*4 + qd;
    p2s[Pout*32 + nt2*16 + col] = f2bf(v);
  }
  __syncthreads();

  // ---- conv3: wave -> ntile = wid, all 21 tiles (last partial) ----
  short8 bf3[27];
  #pragma unroll
  for (int c = 0; c < 27; ++c)
    bf3[c] = *(const short8*)(b3p + ((wid*27 + c)*64 + lane)*8);
  float bv3 = bias3[wid*16 + col];
  int ic03 = qd * 8;
  for (int tile = 0; tile < 21; ++tile) {
    int m = tile*16 + (lane & 15);
    bool vm = m < 324;
    int dd = m & 1, dh = (m >> 1) & 1;
    int P = m >> 2;
    int w = P % 3, t2 = P / 3;
    int ph = t2 % 9, pd = t2 / 9;
    int d0 = 2*pd + dd, h0 = 2*ph + dh;
    floatx4 acc = {0.f, 0.f, 0.f, 0.f};
    #pragma unroll
    for (int c = 0; c < 27; ++c) {
      const int kw = c % 3, kh = (c / 3) % 3, kd = c / 9;
      int d = d0 + kd - 1, h = h0 + kh - 1, wi = w + kw - 1;
      bool valid = vm && ((unsigned)d < 6u) && ((unsigned)h < 18u) && ((unsigned)wi < 3u);
      int a2 = valid ? (((d*18 + h)*3 + wi)*32 + ic03) : 0;
      short8 af = *(const short8*)(p2s + a2);
      short8 z = {0,0,0,0,0,0,0,0};
      af = valid ? af : z;
      acc = __builtin_amdgcn_mfma_f32_16x16x32_bf16(af, bf3[c], acc, 0, 0, 0);
    }
    int Pout = tile*4 + qd;
    if (Pout < 81) {
      float v = fmaxf(fmaxf(acc[0], acc[1]), fmaxf(acc[2], acc[3]));
      v = fmaxf(v + bv3, 0.f);
      p3[((size_t)b*81 + Pout)*64 + wid*16 + col] = v;
    }
  }
}

// ---------------- mean over 81 positions ----------------
__global__ __launch_bounds__(256) void mean_kernel(const float* __restrict__ p3,
                                                   float* __restrict__ me) {
  int i = blockIdx.x * 256 + threadIdx.x;
  int c = i & 63, b = i >> 6;
  const float* p = p3 + (size_t)b * 5184 + c;
  float s = 0.f;
  #pragma unroll 1
  for (int q = 0; q < 81; ++q) s += p[q*64];
  me[i] = s * (1.f / 81.f);
}

// ---------------- initial projections: h0, h2_0, ih_const ----------------
__global__ __launch_bounds__(256) void init_kernel(
    const float* __restrict__ me, const float* __restrict__ wiht,
    const float* __restrict__ b_init_h, const float* __restrict__ wih1t,
    const float* __restrict__ bih1, const float* __restrict__ bhh1,
    const float* __restrict__ wi2t, const float* __restrict__ b_init_h2,
    float* __restrict__ hout, float* __restrict__ h2out, float* __restrict__ ihcout) {
  __shared__ float sme[64];
  __shared__ float shl[256];
  int b = blockIdx.x, t = threadIdx.x;
  if (t < 64) sme[t] = me[b*64 + t];
  __syncthreads();
  float a = b_init_h[t];
  float cc = bih1[t] + bhh1[t];
  #pragma unroll 1
  for (int k = 0; k < 64; ++k) {
    float m = sme[k];
    a  += m * wiht[k*256 + t];
    cc += m * wih1t[k*256 + t];
  }
  hout[b*256 + t] = a; ihcout[b*256 + t] = cc; shl[t] = a;
  __syncthreads();
  float a2 = b_init_h2[t];
  #pragma unroll 1
  for (int k = 0; k < 256; ++k) a2 += shl[k] * wi2t[k*256 + t];
  h2out[b*256 + t] = a2;
}

// ---------------- 23-step 2-layer tanh RNN, 4 batch rows / block ----------------
__global__ __launch_bounds__(256) void rnn_kernel(
    const float* __restrict__ hin, const float* __restrict__ h2in,
    const float* __restrict__ ihc,
    const unsigned int* __restrict__ w1u, const unsigned int* __restrict__ w2u,
    const unsigned int* __restrict__ w3u,
    const float* __restrict__ bih2, const float* __restrict__ bhh2,
    const float* __restrict__ w_fc, const float* __restrict__ b_fc,
    float* __restrict__ preds) {
  __shared__ float sh[4][256], sh2[4][256];
  __shared__ float sred[4][4];
  int t = threadIdx.x; int bb = blockIdx.x * 4;
  int lane = t & 63, wid = t >> 6;
  float ihr[4];
  #pragma unroll
  for (int r = 0; r < 4; ++r) {
    sh[r][t]  = hin[(bb+r)*256 + t];
    sh2[r][t] = h2in[(bb+r)*256 + t];
    ihr[r]    = ihc[(bb+r)*256 + t];
  }
  float bias2 = bih2[t] + bhh2[t];
  float wfc = w_fc[t];
  float bfc = b_fc[0];
  __syncthreads();
  #pragma unroll 1
  for (int step = 0; step < 23; ++step) {
    float a[4] = {ihr[0], ihr[1], ihr[2], ihr[3]};
    #pragma unroll 2
    for (int k = 0; k < 256; k += 4) {
      int k2 = k >> 1;
      unsigned int ua = w1u[k2*256 + t];
      unsigned int ub = w1u[(k2+1)*256 + t];
      float w0 = __uint_as_float(ua << 16), w1 = __uint_as_float(ua & 0xffff0000u);
      float w2 = __uint_as_float(ub << 16), w3 = __uint_as_float(ub & 0xffff0000u);
      #pragma unroll
      for (int r = 0; r < 4; ++r) {
        float4 hv = *(const float4*)&sh[r][k];
        a[r] += hv.x*w0 + hv.y*w1 + hv.z*w2 + hv.w*w3;
      }
    }
    float hn[4];
    #pragma unroll
    for (int r = 0; r < 4; ++r) hn[r] = tanhf(a[r]);
    __syncthreads();
    #pragma unroll
    for (int r = 0; r < 4; ++r) sh[r][t] = hn[r];
    __syncthreads();
    float c[4] = {bias2, bias2, bias2, bias2};
    #pragma unroll 2
    for (int k = 0; k < 256; k += 4) {
      int k2 = k >> 1;
      unsigned int ua = w2u[k2*256 + t], ub = w2u[(k2+1)*256 + t];
      unsigned int va = w3u[k2*256 + t], vb = w3u[(k2+1)*256 + t];
      float i0 = __uint_as_float(ua << 16), i1 = __uint_as_float(ua & 0xffff0000u);
      float i2 = __uint_as_float(ub << 16), i3 = __uint_as_float(ub & 0xffff0000u);
      float g0 = __uint_as_float(va << 16), g1 = __uint_as_float(va & 0xffff0000u);
      float g2 = __uint_as_float(vb << 16), g3 = __uint_as_float(vb & 0xffff0000u);
      #pragma unroll
      for (int r = 0; r < 4; ++r) {
        float4 xv = *(const float4*)&sh[r][k];
        float4 yv = *(const float4*)&sh2[r][k];
        c[r] += xv.x*i0 + xv.y*i1 + xv.z*i2 + xv.w*i3
              + yv.x*g0 + yv.y*g1 + yv.z*g2 + yv.w*g3;
      }
    }
    float h2n[4];
    #pragma unroll
    for (int r = 0; r < 4; ++r) h2n[r] = tanhf(c[r]);
    __syncthreads();
    #pragma unroll
    for (int r = 0; r < 4; ++r) sh2[r][t] = h2n[r];
    #pragma unroll
    for (int r = 0; r < 4; ++r) {
      float v = h2n[r] * wfc;
      #pragma unroll
      for (int off = 32; off > 0; off >>= 1) v += __shfl_down(v, off, 64);
      if (lane == 0) sred[wid][r] = v;
    }
    __syncthreads();
    if (t < 4) {
      float s = sred[0][t] + sred[1][t] + sred[2][t] + sred[3][t] + bfc;
      preds[(size_t)(bb + t)*23 + step] = s;
    }
  }
}

// ---------------- lin1 + tanh + lin2 (2 batch rows / block) ----------------
__global__ __launch_bounds__(256) void lin_kernel(
    const float* __restrict__ p3, const unsigned int* __restrict__ wl1u,
    const float* __restrict__ b_lin1, const float* __restrict__ w_lin2,
    const float* __restrict__ b_lin2, float* __restrict__ outc) {
  __shared__ float sflat[2][5184];
  __shared__ float st1[2][256];
  int t = threadIdx.x; int bb = blockIdx.x * 2;
  #pragma unroll
  for (int r = 0; r < 2; ++r)
    for (int i = t; i < 5184; i += 256)
      sflat[r][i] = p3[(size_t)(bb + r)*5184 + i];
  __syncthreads();
  float a0 = b_lin1[t], a1 = a0;
  #pragma unroll 2
  for (int k2 = 0; k2 < 2592; ++k2) {
    unsigned int u = wl1u[k2*256 + t];
    float w0 = __uint_as_float(u << 16), w1 = __uint_as_float(u & 0xffff0000u);
    float2 f0 = *(const float2*)&sflat[0][2*k2];
    float2 f1 = *(const float2*)&sflat[1][2*k2];
    a0 += f0.x*w0 + f0.y*w1;
    a1 += f1.x*w0 + f1.y*w1;
  }
  st1[0][t] = tanhf(a0);
  st1[1][t] = tanhf(a1);
  __syncthreads();
  if (t < 24) {
    int r = t / 12, j = t % 12;
    float s = b_lin2[j];
    #pragma unroll 1
    for (int k = 0; k < 256; ++k) s += st1[r][k] * w_lin2[j*256 + k];
    outc[(size_t)(bb + r)*12 + j] = s;
  }
}

// ---------------- launch ----------------
extern "C" void kernel_launch(void* const* d_in, const int* in_sizes, int n_in,
                              void* d_out, int out_size, void* d_ws, size_t ws_size,
                              hipStream_t stream) {
  const float* x         = (const float*)d_in[0];
  const float* w1        = (const float*)d_in[1];
  const float* b1        = (const float*)d_in[2];
  const float* w2        = (const float*)d_in[3];
  const float* b2        = (const float*)d_in[4];
  const float* w3        = (const float*)d_in[5];
  const float* b3        = (const float*)d_in[6];
  const float* wih1      = (const float*)d_in[7];
  const float* whh1      = (const float*)d_in[8];
  const float* bih1      = (const float*)d_in[9];
  const float* bhh1      = (const float*)d_in[10];
  const float* wih2      = (const float*)d_in[11];
  const float* whh2      = (const float*)d_in[12];
  const float* bih2      = (const float*)d_in[13];
  const float* bhh2      = (const float*)d_in[14];
  const float* w_init_h  = (const float*)d_in[15];
  const float* b_init_h  = (const float*)d_in[16];
  const float* w_init_h2 = (const float*)d_in[17];
  const float* b_init_h2 = (const float*)d_in[18];
  const float* w_fc      = (const float*)d_in[19];
  const float* b_fc      = (const float*)d_in[20];
  const float* w_lin1    = (const float*)d_in[21];
  const float* b_lin1    = (const float*)d_in[22];
  const float* w_lin2    = (const float*)d_in[23];
  const float* b_lin2    = (const float*)d_in[24];
  float* ws  = (float*)d_ws;
  float* out = (float*)d_out;

  prep_kernel<<<6622, 256, 0, stream>>>(w1, w2, w3, w_init_h, wih1, w_init_h2,
                                        whh1, wih2, whh2, w_lin1, ws);
  conv1_mfma<<<1024, 256, 0, stream>>>(x, (const short*)(ws + OFF_B1P), b1,
                                       (short*)(ws + OFF_P1));
  conv23_mfma<<<512, 256, 0, stream>>>((const short*)(ws + OFF_P1),
                                       (const short*)(ws + OFF_B2P),
                                       (const short*)(ws + OFF_B3P),
                                       b2, b3, ws + OFF_P3);
  mean_kernel<<<128, 256, 0, stream>>>(ws + OFF_P3, ws + OFF_ME);
  init_kernel<<<512, 256, 0, stream>>>(ws + OFF_ME, ws + OFF_WIHT, b_init_h, ws + OFF_WIH1T,
                                       bih1, bhh1, ws + OFF_WI2T, b_init_h2,
                                       ws + OFF_H, ws + OFF_H2, ws + OFF_IHC);
  rnn_kernel<<<128, 256, 0, stream>>>(ws + OFF_H, ws + OFF_H2, ws + OFF_IHC,
                                      (const unsigned int*)(ws + OFF_WHH1P),
                                      (const unsigned int*)(ws + OFF_WIH2P),
                                      (const unsigned int*)(ws + OFF_WHH2P),
                                      bih2, bhh2, w_fc, b_fc, out);
  lin_kernel<<<256, 256, 0, stream>>>(ws + OFF_P3, (const unsigned int*)(ws + OFF_WL1P),
                                      b_lin1, w_lin2, b_lin2, out + 11776);
}

// Round 3
// 902.894 us; speedup vs baseline: 4.5850x; 1.3626x over previous
//
#include <hip/hip_runtime.h>
#include <hip/hip_bf16.h>

typedef __attribute__((ext_vector_type(8))) short short8;
typedef __attribute__((ext_vector_type(4))) float floatx4;

// ---------------- workspace layout (float offsets) ----------------
#define OFF_B1P   0        // conv1 B frags [7][64][8] bf16        = 1792 f
#define OFF_B2P   1792     // conv2 B frags [2][14][64][8] bf16    = 7168 f
#define OFF_B3P   8960     // conv3 B frags [4][27][64][8] bf16    = 27648 f
#define OFF_WIHT  36608    // w_init_h^T  (64,256)
#define OFF_WIH1T 52992    // wih1^T      (64,256)
#define OFF_WI2T  69376    // w_init_h2^T (256,256)
#define OFF_WHH1B 134912   // whh1 bf16 row-major [t][k] (65536 bf16)
#define OFF_WIH2B 167680   // wih2 bf16 row-major
#define OFF_WHH2B 200448   // whh2 bf16 row-major
#define OFF_WL1P  233216   // w_lin1 bf16 packed [k2][t][2]
#define OFF_ME    896768   // mean_enc (512,64)
#define OFF_H     929536   // h0  (512,256)
#define OFF_H2    1060608  // h2_0(512,256)
#define OFF_IHC   1191680  // ih_const (512,256)
#define OFF_P1    1322752  // p1 bf16 [512][1296][16]  (10616832 bf16)
#define OFF_P3    6631168  // p3 fp32 [512][81][64] == flat

static __device__ inline short f2bf(float f) {
  union { __hip_bfloat16 h; short s; } u;
  u.h = __float2bfloat16(f);
  return u.s;
}
static __device__ inline float bf2f(short s) {
  union { unsigned u; float f; } v;
  v.u = ((unsigned)(unsigned short)s) << 16;
  return v.f;
}

// ---------------- prep: weight frag packs + RNN/linear packs ----------------
__global__ __launch_bounds__(256) void prep_kernel(
    const float* __restrict__ w1, const float* __restrict__ w2, const float* __restrict__ w3,
    const float* __restrict__ w_init_h, const float* __restrict__ wih1,
    const float* __restrict__ w_init_h2, const float* __restrict__ whh1,
    const float* __restrict__ wih2, const float* __restrict__ whh2,
    const float* __restrict__ w_lin1, float* __restrict__ ws) {
  int i = blockIdx.x * 256 + threadIdx.x;
  // conv1 B: k = tap*8 + icp (K=224, 7 chunks), value w1[oc, icp, tap]
  if (i < 3584) {
    int j = i & 7, l = (i >> 3) & 63, c = i >> 9;
    int k = c*32 + ((l >> 4) << 3) + j;
    int tap = k >> 3, icp = k & 7, oc = l & 15;
    float v = (tap < 27 && icp < 6) ? w1[(oc*6 + icp)*27 + tap] : 0.f;
    ((__hip_bfloat16*)(ws + OFF_B1P))[i] = __float2bfloat16(v);
    return;
  }
  i -= 3584;
  // conv2 B: k = tap*16 + ic (K=448, 14 chunks), layout [nt][c][l][j]
  if (i < 14336) {
    int j = i & 7, l = (i >> 3) & 63, cc = i >> 9;
    int c = cc % 14, nt = cc / 14;
    int k = c*32 + ((l >> 4) << 3) + j;
    int tap = k >> 4, ic = k & 15, oc = nt*16 + (l & 15);
    float v = (tap < 27) ? w2[(oc*16 + ic)*27 + tap] : 0.f;
    ((__hip_bfloat16*)(ws + OFF_B2P))[i] = __float2bfloat16(v);
    return;
  }
  i -= 14336;
  // conv3 B: k = tap*32 + ic (K=864, 27 chunks), layout [nt][c][l][j]
  if (i < 55296) {
    int j = i & 7, l = (i >> 3) & 63, cc = i >> 9;
    int c = cc % 27, nt = cc / 27;
    int k = c*32 + ((l >> 4) << 3) + j;
    int ic = k & 31, oc = nt*16 + (l & 15);
    ((__hip_bfloat16*)(ws + OFF_B3P))[i] = __float2bfloat16(w3[(oc*32 + ic)*27 + c]);
    return;
  }
  i -= 55296;
  if (i < 16384) { int t = i & 255, k = i >> 8; ws[OFF_WIHT + i]  = w_init_h[t*64 + k];  return; }
  i -= 16384;
  if (i < 16384) { int t = i & 255, k = i >> 8; ws[OFF_WIH1T + i] = wih1[t*64 + k];      return; }
  i -= 16384;
  if (i < 65536) { int t = i & 255, k = i >> 8; ws[OFF_WI2T + i]  = w_init_h2[t*256 + k]; return; }
  i -= 65536;
  if (i < 65536) { ((__hip_bfloat16*)(ws + OFF_WHH1B))[i] = __float2bfloat16(whh1[i]); return; }
  i -= 65536;
  if (i < 65536) { ((__hip_bfloat16*)(ws + OFF_WIH2B))[i] = __float2bfloat16(wih2[i]); return; }
  i -= 65536;
  if (i < 65536) { ((__hip_bfloat16*)(ws + OFF_WHH2B))[i] = __float2bfloat16(whh2[i]); return; }
  i -= 65536;
  if (i < 1327104) {
    int j = i & 1, t = (i >> 1) & 255, k2 = i >> 9;
    ((__hip_bfloat16*)(ws + OFF_WL1P))[i] = __float2bfloat16(w_lin1[t*5184 + 2*k2 + j]);
    return;
  }
}

// ---------------- conv1 MFMA: x (512,6,24,72,3) fp32 -> p1 bf16 [b][1296][16]
__global__ __launch_bounds__(256) void conv1_mfma(
    const float* __restrict__ x, const short* __restrict__ b1p,
    const float* __restrict__ bias, short* __restrict__ p1) {
  __shared__ __align__(16) short slab[13 * 216 * 8];  // [dslot][h*3+w][ic8] 44928 B
  int tid = threadIdx.x;
  int b = blockIdx.x >> 1, dhalf = blockIdx.x & 1;
  int dbase = dhalf * 11;
  for (int i = tid; i < 11232; i += 256) ((unsigned*)slab)[i] = 0u;
  __syncthreads();
  for (int i = tid; i < 6 * 13 * 216; i += 256) {
    int ic = i / 2808, r = i % 2808;
    int dslot = r / 216, pos = r % 216;
    float v = x[((size_t)(b*6 + ic)*24 + dbase + dslot)*216 + pos];
    slab[(dslot*216 + pos)*8 + ic] = f2bf(v);
  }
  int lane = tid & 63, wid = tid >> 6;
  int qd = lane >> 4, col = lane & 15;
  short8 bf[7];
  #pragma unroll
  for (int c = 0; c < 7; ++c) bf[c] = *(const short8*)(b1p + (c*64 + lane)*8);
  int kdm1[7], khm1[7], kwm1[7]; bool tv[7];
  #pragma unroll
  for (int c = 0; c < 7; ++c) {
    int tap = c*4 + qd;
    tv[c] = tap < 27;
    int tt = tv[c] ? tap : 0;
    kwm1[c] = tt % 3 - 1; khm1[c] = (tt/3) % 3 - 1; kdm1[c] = tt/9 - 1;
  }
  float bv = bias[col];
  __syncthreads();
  for (int tile = wid; tile < 162; tile += 4) {
    int m = tile*16 + (lane & 15);
    int dd = m & 1, dh = (m >> 1) & 1;
    int P = m >> 2;
    int w = P % 3, t2 = P / 3;
    int ph = t2 % 36, pdl = t2 / 36;
    int ds0 = 2*(dhalf*6 + pdl) + dd - dbase;
    int h0 = 2*ph + dh;
    floatx4 acc = {0.f, 0.f, 0.f, 0.f};
    #pragma unroll
    for (int c = 0; c < 7; ++c) {
      int dslot = ds0 + kdm1[c];
      int hh = h0 + khm1[c];
      int wi = w + kwm1[c];
      bool valid = tv[c] && ((unsigned)dslot < 13u) && ((unsigned)hh < 72u) && ((unsigned)wi < 3u);
      int a2 = valid ? ((dslot*216 + hh*3 + wi) * 8) : 0;
      short8 af = *(const short8*)(slab + a2);
      short8 z = {0,0,0,0,0,0,0,0};
      af = valid ? af : z;
      acc = __builtin_amdgcn_mfma_f32_16x16x32_bf16(af, bf[c], acc, 0, 0, 0);
    }
    float v = fmaxf(fmaxf(acc[0], acc[1]), fmaxf(acc[2], acc[3]));
    v = fmaxf(v + bv, 0.f);
    int Pout = dhalf*648 + tile*4 + qd;
    p1[((size_t)b*1296 + Pout)*16 + col] = f2bf(v);
  }
}

// ---------------- fused conv2+conv3 MFMA per batch: p1 bf16 -> p3 fp32 [b][81][64]
__global__ __launch_bounds__(256) void conv23_mfma(
    const short* __restrict__ p1, const short* __restrict__ b2p,
    const short* __restrict__ b3p,
    const float* __restrict__ bias2, const float* __restrict__ bias3,
    float* __restrict__ p3) {
  __shared__ __align__(16) short p1s[20736];  // [P1296][ic16] 41472 B
  __shared__ __align__(16) short p2s[10368];  // [P324][ic32]  20736 B
  int tid = threadIdx.x;
  int b = blockIdx.x;
  int lane = tid & 63, wid = tid >> 6;
  int qd = lane >> 4, col = lane & 15;
  const short* p1b = p1 + (size_t)b * 20736;
  for (int i = tid; i < 2592; i += 256)
    *(short8*)(p1s + i*8) = *(const short8*)(p1b + i*8);

  int nt2 = wid & 1;
  short8 bf2[14];
  #pragma unroll
  for (int c = 0; c < 14; ++c)
    bf2[c] = *(const short8*)(b2p + ((nt2*14 + c)*64 + lane)*8);
  int kdm1[14], khm1[14], kwm1[14]; bool tv2[14];
  #pragma unroll
  for (int c = 0; c < 14; ++c) {
    int tap = c*2 + (qd >> 1);
    tv2[c] = tap < 27;
    int tt = tv2[c] ? tap : 0;
    kwm1[c] = tt % 3 - 1; khm1[c] = (tt/3) % 3 - 1; kdm1[c] = tt/9 - 1;
  }
  int ic02 = (qd & 1) * 8;
  float bv2 = bias2[nt2*16 + col];
  __syncthreads();
  for (int tile = (wid >> 1); tile < 81; tile += 2) {
    int m = tile*16 + (lane & 15);
    int dd = m & 1, dh = (m >> 1) & 1;
    int P = m >> 2;
    int w = P % 3, t2 = P / 3;
    int ph = t2 % 18, pd = t2 / 18;
    int d0 = 2*pd + dd, h0 = 2*ph + dh;
    floatx4 acc = {0.f, 0.f, 0.f, 0.f};
    #pragma unroll
    for (int c = 0; c < 14; ++c) {
      int d = d0 + kdm1[c], h = h0 + khm1[c], wi = w + kwm1[c];
      bool valid = tv2[c] && ((unsigned)d < 12u) && ((unsigned)h < 36u) && ((unsigned)wi < 3u);
      int a2 = valid ? (((d*36 + h)*3 + wi)*16 + ic02) : 0;
      short8 af = *(const short8*)(p1s + a2);
      short8 z = {0,0,0,0,0,0,0,0};
      af = valid ? af : z;
      acc = __builtin_amdgcn_mfma_f32_16x16x32_bf16(af, bf2[c], acc, 0, 0, 0);
    }
    float v = fmaxf(fmaxf(acc[0], acc[1]), fmaxf(acc[2], acc[3]));
    v = fmaxf(v + bv2, 0.f);
    int Pout = tile*4 + qd;
    p2s[Pout*32 + nt2*16 + col] = f2bf(v);
  }
  __syncthreads();

  short8 bf3[27];
  #pragma unroll
  for (int c = 0; c < 27; ++c)
    bf3[c] = *(const short8*)(b3p + ((wid*27 + c)*64 + lane)*8);
  float bv3 = bias3[wid*16 + col];
  int ic03 = qd * 8;
  for (int tile = 0; tile < 21; ++tile) {
    int m = tile*16 + (lane & 15);
    bool vm = m < 324;
    int dd = m & 1, dh = (m >> 1) & 1;
    int P = m >> 2;
    int w = P % 3, t2 = P / 3;
    int ph = t2 % 9, pd = t2 / 9;
    int d0 = 2*pd + dd, h0 = 2*ph + dh;
    floatx4 acc = {0.f, 0.f, 0.f, 0.f};
    #pragma unroll
    for (int c = 0; c < 27; ++c) {
      const int kw = c % 3, kh = (c / 3) % 3, kd = c / 9;
      int d = d0 + kd - 1, h = h0 + kh - 1, wi = w + kw - 1;
      bool valid = vm && ((unsigned)d < 6u) && ((unsigned)h < 18u) && ((unsigned)wi < 3u);
      int a2 = valid ? (((d*18 + h)*3 + wi)*32 + ic03) : 0;
      short8 af = *(const short8*)(p2s + a2);
      short8 z = {0,0,0,0,0,0,0,0};
      af = valid ? af : z;
      acc = __builtin_amdgcn_mfma_f32_16x16x32_bf16(af, bf3[c], acc, 0, 0, 0);
    }
    int Pout = tile*4 + qd;
    if (Pout < 81) {
      float v = fmaxf(fmaxf(acc[0], acc[1]), fmaxf(acc[2], acc[3]));
      v = fmaxf(v + bv3, 0.f);
      p3[((size_t)b*81 + Pout)*64 + wid*16 + col] = v;
    }
  }
}

// ---------------- mean over 81 positions ----------------
__global__ __launch_bounds__(256) void mean_kernel(const float* __restrict__ p3,
                                                   float* __restrict__ me) {
  int i = blockIdx.x * 256 + threadIdx.x;
  int c = i & 63, b = i >> 6;
  const float* p = p3 + (size_t)b * 5184 + c;
  float s = 0.f;
  #pragma unroll 1
  for (int q = 0; q < 81; ++q) s += p[q*64];
  me[i] = s * (1.f / 81.f);
}

// ---------------- initial projections: h0, h2_0, ih_const ----------------
__global__ __launch_bounds__(256) void init_kernel(
    const float* __restrict__ me, const float* __restrict__ wiht,
    const float* __restrict__ b_init_h, const float* __restrict__ wih1t,
    const float* __restrict__ bih1, const float* __restrict__ bhh1,
    const float* __restrict__ wi2t, const float* __restrict__ b_init_h2,
    float* __restrict__ hout, float* __restrict__ h2out, float* __restrict__ ihcout) {
  __shared__ float sme[64];
  __shared__ float shl[256];
  int b = blockIdx.x, t = threadIdx.x;
  if (t < 64) sme[t] = me[b*64 + t];
  __syncthreads();
  float a = b_init_h[t];
  float cc = bih1[t] + bhh1[t];
  #pragma unroll 1
  for (int k = 0; k < 64; ++k) {
    float m = sme[k];
    a  += m * wiht[k*256 + t];
    cc += m * wih1t[k*256 + t];
  }
  hout[b*256 + t] = a; ihcout[b*256 + t] = cc; shl[t] = a;
  __syncthreads();
  float a2 = b_init_h2[t];
  #pragma unroll 1
  for (int k = 0; k < 256; ++k) a2 += shl[k] * wi2t[k*256 + t];
  h2out[b*256 + t] = a2;
}

// ---------------- RNN: register-resident MFMA, 32 blocks x 512 thr, M=16 rows
// waves 0-3: whh1 N=64 slices; waves 4-7: whh2 N=64 slices; all: wih2 N=32 slices.
__global__ __launch_bounds__(512) void rnn2_kernel(
    const float* __restrict__ hin, const float* __restrict__ h2in,
    const float* __restrict__ ihc,
    const short* __restrict__ whh1b, const short* __restrict__ wih2b,
    const short* __restrict__ whh2b,
    const float* __restrict__ bih2, const float* __restrict__ bhh2,
    const float* __restrict__ w_fc, const float* __restrict__ b_fc,
    float* __restrict__ preds) {
  __shared__ __align__(16) short hbuf[2][16][264];   // bf16 [m][k] padded
  __shared__ __align__(16) short h2buf[2][16][264];
  __shared__ __align__(16) short p2b[16][264];       // bf16 P2 staging
  __shared__ float ihcL[16][260];                    // fp32 ihc [m][n]
  __shared__ float predp[8][16];
  int tid = threadIdx.x;
  int bb = blockIdx.x * 16;
  int wid = tid >> 6, lane = tid & 63;
  int quad = lane >> 4, col = lane & 15;

  // weight fragments (held in VGPRs for all 23 steps)
  short8 wf[4][8];   // whh1 (waves 0-3) or whh2 (waves 4-7), N=64 slice
  const short* wsel = (wid < 4) ? whh1b : whh2b;
  int nb = (wid & 3) * 64;
  #pragma unroll
  for (int t = 0; t < 4; ++t)
    #pragma unroll
    for (int c = 0; c < 8; ++c)
      wf[t][c] = *(const short8*)(wsel + (nb + t*16 + col)*256 + c*32 + quad*8);
  short8 w2f[2][8];  // wih2, N=32 slice
  int nb2 = wid * 32;
  #pragma unroll
  for (int t = 0; t < 2; ++t)
    #pragma unroll
    for (int c = 0; c < 8; ++c)
      w2f[t][c] = *(const short8*)(wih2b + (nb2 + t*16 + col)*256 + c*32 + quad*8);
  float b2v[2], wfcv[2];
  #pragma unroll
  for (int t = 0; t < 2; ++t) {
    int n = nb2 + t*16 + col;
    b2v[t] = bih2[n] + bhh2[n];
    wfcv[t] = w_fc[n];
  }
  float bfc = b_fc[0];

  // initial state + ihc into LDS
  for (int i = tid; i < 4096; i += 512) {
    int m = i >> 8, k = i & 255;
    hbuf[0][m][k]  = f2bf(hin[(bb + m)*256 + k]);
    h2buf[0][m][k] = f2bf(h2in[(bb + m)*256 + k]);
    ihcL[m][k]     = ihc[(bb + m)*256 + k];
  }
  __syncthreads();

  for (int step = 0; step < 23; ++step) {
    int cur = step & 1, nxt = cur ^ 1;
    // ---- phase 1: GEMM1 (waves 0-3) || GEMM2b (waves 4-7) ----
    floatx4 acc[4];
    if (wid < 4) {
      #pragma unroll
      for (int t = 0; t < 4; ++t)
        #pragma unroll
        for (int r = 0; r < 4; ++r)
          acc[t][r] = ihcL[quad*4 + r][nb + t*16 + col];
    } else {
      #pragma unroll
      for (int t = 0; t < 4; ++t) {
        floatx4 z = {0.f, 0.f, 0.f, 0.f};
        acc[t] = z;
      }
    }
    const short (*src)[264] = (wid < 4) ? hbuf[cur] : h2buf[cur];
    #pragma unroll
    for (int c = 0; c < 8; ++c) {
      short8 a = *(const short8*)&src[col][c*32 + quad*8];
      #pragma unroll
      for (int t = 0; t < 4; ++t)
        acc[t] = __builtin_amdgcn_mfma_f32_16x16x32_bf16(a, wf[t][c], acc[t], 0, 0, 0);
    }
    if (wid < 4) {
      #pragma unroll
      for (int t = 0; t < 4; ++t)
        #pragma unroll
        for (int r = 0; r < 4; ++r)
          hbuf[nxt][quad*4 + r][nb + t*16 + col] = f2bf(tanhf(acc[t][r]));
    } else {
      #pragma unroll
      for (int t = 0; t < 4; ++t)
        #pragma unroll
        for (int r = 0; r < 4; ++r)
          p2b[quad*4 + r][nb + t*16 + col] = f2bf(acc[t][r]);
    }
    __syncthreads();
    // ---- phase 2: GEMM2a + combine (all 8 waves) ----
    floatx4 q0 = {0.f,0.f,0.f,0.f}, q1 = {0.f,0.f,0.f,0.f};
    #pragma unroll
    for (int c = 0; c < 8; ++c) {
      short8 a = *(const short8*)&hbuf[nxt][col][c*32 + quad*8];
      q0 = __builtin_amdgcn_mfma_f32_16x16x32_bf16(a, w2f[0][c], q0, 0, 0, 0);
      q1 = __builtin_amdgcn_mfma_f32_16x16x32_bf16(a, w2f[1][c], q1, 0, 0, 0);
    }
    float pr[4];
    #pragma unroll
    for (int r = 0; r < 4; ++r) {
      float v0 = q0[r] + bf2f(p2b[quad*4 + r][nb2 + col]) + b2v[0];
      float v1 = q1[r] + bf2f(p2b[quad*4 + r][nb2 + 16 + col]) + b2v[1];
      float t0 = tanhf(v0), t1 = tanhf(v1);
      h2buf[nxt][quad*4 + r][nb2 + col] = f2bf(t0);
      h2buf[nxt][quad*4 + r][nb2 + 16 + col] = f2bf(t1);
      pr[r] = t0*wfcv[0] + t1*wfcv[1];
    }
    #pragma unroll
    for (int r = 0; r < 4; ++r) {
      #pragma unroll
      for (int off = 1; off < 16; off <<= 1)
        pr[r] += __shfl_xor(pr[r], off, 64);
    }
    if (col == 0) {
      #pragma unroll
      for (int r = 0; r < 4; ++r) predp[wid][quad*4 + r] = pr[r];
    }
    __syncthreads();
    if (tid < 16) {
      float s = bfc;
      #pragma unroll
      for (int w = 0; w < 8; ++w) s += predp[w][tid];
      preds[(size_t)(bb + tid)*23 + step] = s;
    }
  }
}

// ---------------- lin1 + tanh + lin2 (2 batch rows / block) ----------------
__global__ __launch_bounds__(256) void lin_kernel(
    const float* __restrict__ p3, const unsigned int* __restrict__ wl1u,
    const float* __restrict__ b_lin1, const float* __restrict__ w_lin2,
    const float* __restrict__ b_lin2, float* __restrict__ outc) {
  __shared__ float sflat[2][5184];
  __shared__ float st1[2][256];
  int t = threadIdx.x; int bb = blockIdx.x * 2;
  #pragma unroll
  for (int r = 0; r < 2; ++r)
    for (int i = t; i < 5184; i += 256)
      sflat[r][i] = p3[(size_t)(bb + r)*5184 + i];
  __syncthreads();
  float a0 = b_lin1[t], a1 = a0;
  #pragma unroll 2
  for (int k2 = 0; k2 < 2592; ++k2) {
    unsigned int u = wl1u[k2*256 + t];
    float w0 = __uint_as_float(u << 16), w1 = __uint_as_float(u & 0xffff0000u);
    float2 f0 = *(const float2*)&sflat[0][2*k2];
    float2 f1 = *(const float2*)&sflat[1][2*k2];
    a0 += f0.x*w0 + f0.y*w1;
    a1 += f1.x*w0 + f1.y*w1;
  }
  st1[0][t] = tanhf(a0);
  st1[1][t] = tanhf(a1);
  __syncthreads();
  if (t < 24) {
    int r = t / 12, j = t % 12;
    float s = b_lin2[j];
    #pragma unroll 1
    for (int k = 0; k < 256; ++k) s += st1[r][k] * w_lin2[j*256 + k];
    outc[(size_t)(bb + r)*12 + j] = s;
  }
}

// ---------------- launch ----------------
extern "C" void kernel_launch(void* const* d_in, const int* in_sizes, int n_in,
                              void* d_out, int out_size, void* d_ws, size_t ws_size,
                              hipStream_t stream) {
  const float* x         = (const float*)d_in[0];
  const float* w1        = (const float*)d_in[1];
  const float* b1        = (const float*)d_in[2];
  const float* w2        = (const float*)d_in[3];
  const float* b2        = (const float*)d_in[4];
  const float* w3        = (const float*)d_in[5];
  const float* b3        = (const float*)d_in[6];
  const float* wih1      = (const float*)d_in[7];
  const float* whh1      = (const float*)d_in[8];
  const float* bih1      = (const float*)d_in[9];
  const float* bhh1      = (const float*)d_in[10];
  const float* wih2      = (const float*)d_in[11];
  const float* whh2      = (const float*)d_in[12];
  const float* bih2      = (const float*)d_in[13];
  const float* bhh2      = (const float*)d_in[14];
  const float* w_init_h  = (const float*)d_in[15];
  const float* b_init_h  = (const float*)d_in[16];
  const float* w_init_h2 = (const float*)d_in[17];
  const float* b_init_h2 = (const float*)d_in[18];
  const float* w_fc      = (const float*)d_in[19];
  const float* b_fc      = (const float*)d_in[20];
  const float* w_lin1    = (const float*)d_in[21];
  const float* b_lin1    = (const float*)d_in[22];
  const float* w_lin2    = (const float*)d_in[23];
  const float* b_lin2    = (const float*)d_in[24];
  float* ws  = (float*)d_ws;
  float* out = (float*)d_out;

  prep_kernel<<<6622, 256, 0, stream>>>(w1, w2, w3, w_init_h, wih1, w_init_h2,
                                        whh1, wih2, whh2, w_lin1, ws);
  conv1_mfma<<<1024, 256, 0, stream>>>(x, (const short*)(ws + OFF_B1P), b1,
                                       (short*)(ws + OFF_P1));
  conv23_mfma<<<512, 256, 0, stream>>>((const short*)(ws + OFF_P1),
                                       (const short*)(ws + OFF_B2P),
                                       (const short*)(ws + OFF_B3P),
                                       b2, b3, ws + OFF_P3);
  mean_kernel<<<128, 256, 0, stream>>>(ws + OFF_P3, ws + OFF_ME);
  init_kernel<<<512, 256, 0, stream>>>(ws + OFF_ME, ws + OFF_WIHT, b_init_h, ws + OFF_WIH1T,
                                       bih1, bhh1, ws + OFF_WI2T, b_init_h2,
                                       ws + OFF_H, ws + OFF_H2, ws + OFF_IHC);
  rnn2_kernel<<<32, 512, 0, stream>>>(ws + OFF_H, ws + OFF_H2, ws + OFF_IHC,
                                      (const short*)(ws + OFF_WHH1B),
                                      (const short*)(ws + OFF_WIH2B),
                                      (const short*)(ws + OFF_WHH2B),
                                      bih2, bhh2, w_fc, b_fc, out);
  lin_kernel<<<256, 256, 0, stream>>>(ws + OFF_P3, (const unsigned int*)(ws + OFF_WL1P),
                                      b_lin1, w_lin2, b_lin2, out + 11776);
}

// Round 4
// 592.936 us; speedup vs baseline: 6.9818x; 1.5228x over previous
//
#include <hip/hip_runtime.h>
#include <hip/hip_bf16.h>

typedef __attribute__((ext_vector_type(8))) short short8;
typedef __attribute__((ext_vector_type(4))) float floatx4;

// ---------------- workspace layout (float offsets) ----------------
#define OFF_B1P   0        // conv1 B frags [7][64][8] bf16
#define OFF_B2P   1792     // conv2 B frags [2][14][64][8] bf16
#define OFF_B3P   8960     // conv3 B frags [4][27][64][8] bf16
#define OFF_WIHT  36608    // w_init_h^T  (64,256)
#define OFF_WIH1T 52992    // wih1^T      (64,256)
#define OFF_WI2T  69376    // w_init_h2^T (256,256)
#define OFF_WHH1B 134912   // whh1 bf16 row-major [t][k]
#define OFF_WIH2B 167680   // wih2 bf16 row-major
#define OFF_WHH2B 200448   // whh2 bf16 row-major
#define OFF_WL1P  233216   // w_lin1 MFMA frags [nt16][c162][lane64][j8] bf16
#define OFF_ME    896768   // mean_enc (512,64)
#define OFF_H     929536   // h0  (512,256)
#define OFF_H2    1060608  // h2_0(512,256)
#define OFF_IHC   1191680  // ih_const (512,256)
#define OFF_P1    1322752  // p1 bf16 [512][1296][16]
#define OFF_P3    6631168  // p3 fp32 [512][81][64] == flat
#define OFF_P3BF  9285376  // p3 bf16 copy [512][5184]
#define OFF_T1    10612480 // lin1 pre-tanh acc (512,256) fp32

static __device__ inline short f2bf(float f) {
  union { __hip_bfloat16 h; short s; } u;
  u.h = __float2bfloat16(f);
  return u.s;
}
static __device__ inline float bf2f(short s) {
  union { unsigned u; float f; } v;
  v.u = ((unsigned)(unsigned short)s) << 16;
  return v.f;
}

// ---------------- prep: weight frag packs + RNN/linear packs ----------------
__global__ __launch_bounds__(256) void prep_kernel(
    const float* __restrict__ w1, const float* __restrict__ w2, const float* __restrict__ w3,
    const float* __restrict__ w_init_h, const float* __restrict__ wih1,
    const float* __restrict__ w_init_h2, const float* __restrict__ whh1,
    const float* __restrict__ wih2, const float* __restrict__ whh2,
    const float* __restrict__ w_lin1, float* __restrict__ ws) {
  int i = blockIdx.x * 256 + threadIdx.x;
  // conv1 B: k = tap*8 + icp (K=224, 7 chunks)
  if (i < 3584) {
    int j = i & 7, l = (i >> 3) & 63, c = i >> 9;
    int k = c*32 + ((l >> 4) << 3) + j;
    int tap = k >> 3, icp = k & 7, oc = l & 15;
    float v = (tap < 27 && icp < 6) ? w1[(oc*6 + icp)*27 + tap] : 0.f;
    ((__hip_bfloat16*)(ws + OFF_B1P))[i] = __float2bfloat16(v);
    return;
  }
  i -= 3584;
  // conv2 B: k = tap*16 + ic (K=448, 14 chunks)
  if (i < 14336) {
    int j = i & 7, l = (i >> 3) & 63, cc = i >> 9;
    int c = cc % 14, nt = cc / 14;
    int k = c*32 + ((l >> 4) << 3) + j;
    int tap = k >> 4, ic = k & 15, oc = nt*16 + (l & 15);
    float v = (tap < 27) ? w2[(oc*16 + ic)*27 + tap] : 0.f;
    ((__hip_bfloat16*)(ws + OFF_B2P))[i] = __float2bfloat16(v);
    return;
  }
  i -= 14336;
  // conv3 B: k = tap*32 + ic (K=864, 27 chunks)
  if (i < 55296) {
    int j = i & 7, l = (i >> 3) & 63, cc = i >> 9;
    int c = cc % 27, nt = cc / 27;
    int k = c*32 + ((l >> 4) << 3) + j;
    int ic = k & 31, oc = nt*16 + (l & 15);
    ((__hip_bfloat16*)(ws + OFF_B3P))[i] = __float2bfloat16(w3[(oc*32 + ic)*27 + c]);
    return;
  }
  i -= 55296;
  if (i < 16384) { int t = i & 255, k = i >> 8; ws[OFF_WIHT + i]  = w_init_h[t*64 + k];  return; }
  i -= 16384;
  if (i < 16384) { int t = i & 255, k = i >> 8; ws[OFF_WIH1T + i] = wih1[t*64 + k];      return; }
  i -= 16384;
  if (i < 65536) { int t = i & 255, k = i >> 8; ws[OFF_WI2T + i]  = w_init_h2[t*256 + k]; return; }
  i -= 65536;
  if (i < 65536) { ((__hip_bfloat16*)(ws + OFF_WHH1B))[i] = __float2bfloat16(whh1[i]); return; }
  i -= 65536;
  if (i < 65536) { ((__hip_bfloat16*)(ws + OFF_WIH2B))[i] = __float2bfloat16(wih2[i]); return; }
  i -= 65536;
  if (i < 65536) { ((__hip_bfloat16*)(ws + OFF_WHH2B))[i] = __float2bfloat16(whh2[i]); return; }
  i -= 65536;
  // w_lin1 MFMA B-frags: [nt][c][lane][j], n = nt*16+(l&15), k = c*32+quad*8+j
  if (i < 1327104) {
    int j = i & 7, l = (i >> 3) & 63, cc = i >> 9;
    int c = cc % 162, nt = cc / 162;
    int k = c*32 + ((l >> 4) << 3) + j;
    int n = nt*16 + (l & 15);
    ((__hip_bfloat16*)(ws + OFF_WL1P))[i] = __float2bfloat16(w_lin1[n*5184 + k]);
    return;
  }
}

// ---------------- conv1 MFMA: x (512,6,24,72,3) fp32 -> p1 bf16 [b][1296][16]
__global__ __launch_bounds__(256) void conv1_mfma(
    const float* __restrict__ x, const short* __restrict__ b1p,
    const float* __restrict__ bias, short* __restrict__ p1) {
  __shared__ __align__(16) short slab[13 * 216 * 8];
  int tid = threadIdx.x;
  int b = blockIdx.x >> 1, dhalf = blockIdx.x & 1;
  int dbase = dhalf * 11;
  for (int i = tid; i < 11232; i += 256) ((unsigned*)slab)[i] = 0u;
  __syncthreads();
  for (int i = tid; i < 6 * 13 * 216; i += 256) {
    int ic = i / 2808, r = i % 2808;
    int dslot = r / 216, pos = r % 216;
    float v = x[((size_t)(b*6 + ic)*24 + dbase + dslot)*216 + pos];
    slab[(dslot*216 + pos)*8 + ic] = f2bf(v);
  }
  int lane = tid & 63, wid = tid >> 6;
  int qd = lane >> 4, col = lane & 15;
  short8 bf[7];
  #pragma unroll
  for (int c = 0; c < 7; ++c) bf[c] = *(const short8*)(b1p + (c*64 + lane)*8);
  int kdm1[7], khm1[7], kwm1[7]; bool tv[7];
  #pragma unroll
  for (int c = 0; c < 7; ++c) {
    int tap = c*4 + qd;
    tv[c] = tap < 27;
    int tt = tv[c] ? tap : 0;
    kwm1[c] = tt % 3 - 1; khm1[c] = (tt/3) % 3 - 1; kdm1[c] = tt/9 - 1;
  }
  float bv = bias[col];
  __syncthreads();
  for (int tile = wid; tile < 162; tile += 4) {
    int m = tile*16 + (lane & 15);
    int dd = m & 1, dh = (m >> 1) & 1;
    int P = m >> 2;
    int w = P % 3, t2 = P / 3;
    int ph = t2 % 36, pdl = t2 / 36;
    int ds0 = 2*(dhalf*6 + pdl) + dd - dbase;
    int h0 = 2*ph + dh;
    floatx4 acc = {0.f, 0.f, 0.f, 0.f};
    #pragma unroll
    for (int c = 0; c < 7; ++c) {
      int dslot = ds0 + kdm1[c];
      int hh = h0 + khm1[c];
      int wi = w + kwm1[c];
      bool valid = tv[c] && ((unsigned)dslot < 13u) && ((unsigned)hh < 72u) && ((unsigned)wi < 3u);
      int a2 = valid ? ((dslot*216 + hh*3 + wi) * 8) : 0;
      short8 af = *(const short8*)(slab + a2);
      short8 z = {0,0,0,0,0,0,0,0};
      af = valid ? af : z;
      acc = __builtin_amdgcn_mfma_f32_16x16x32_bf16(af, bf[c], acc, 0, 0, 0);
    }
    float v = fmaxf(fmaxf(acc[0], acc[1]), fmaxf(acc[2], acc[3]));
    v = fmaxf(v + bv, 0.f);
    int Pout = dhalf*648 + tile*4 + qd;
    p1[((size_t)b*1296 + Pout)*16 + col] = f2bf(v);
  }
}

// ---------------- fused conv2+conv3 MFMA per batch: p1 bf16 -> p3 fp32 + bf16
__global__ __launch_bounds__(256) void conv23_mfma(
    const short* __restrict__ p1, const short* __restrict__ b2p,
    const short* __restrict__ b3p,
    const float* __restrict__ bias2, const float* __restrict__ bias3,
    float* __restrict__ p3, short* __restrict__ p3bf) {
  __shared__ __align__(16) short p1s[20736];
  __shared__ __align__(16) short p2s[10368];
  int tid = threadIdx.x;
  int b = blockIdx.x;
  int lane = tid & 63, wid = tid >> 6;
  int qd = lane >> 4, col = lane & 15;
  const short* p1b = p1 + (size_t)b * 20736;
  for (int i = tid; i < 2592; i += 256)
    *(short8*)(p1s + i*8) = *(const short8*)(p1b + i*8);

  int nt2 = wid & 1;
  short8 bf2[14];
  #pragma unroll
  for (int c = 0; c < 14; ++c)
    bf2[c] = *(const short8*)(b2p + ((nt2*14 + c)*64 + lane)*8);
  int kdm1[14], khm1[14], kwm1[14]; bool tv2[14];
  #pragma unroll
  for (int c = 0; c < 14; ++c) {
    int tap = c*2 + (qd >> 1);
    tv2[c] = tap < 27;
    int tt = tv2[c] ? tap : 0;
    kwm1[c] = tt % 3 - 1; khm1[c] = (tt/3) % 3 - 1; kdm1[c] = tt/9 - 1;
  }
  int ic02 = (qd & 1) * 8;
  float bv2 = bias2[nt2*16 + col];
  __syncthreads();
  for (int tile = (wid >> 1); tile < 81; tile += 2) {
    int m = tile*16 + (lane & 15);
    int dd = m & 1, dh = (m >> 1) & 1;
    int P = m >> 2;
    int w = P % 3, t2 = P / 3;
    int ph = t2 % 18, pd = t2 / 18;
    int d0 = 2*pd + dd, h0 = 2*ph + dh;
    floatx4 acc = {0.f, 0.f, 0.f, 0.f};
    #pragma unroll
    for (int c = 0; c < 14; ++c) {
      int d = d0 + kdm1[c], h = h0 + khm1[c], wi = w + kwm1[c];
      bool valid = tv2[c] && ((unsigned)d < 12u) && ((unsigned)h < 36u) && ((unsigned)wi < 3u);
      int a2 = valid ? (((d*36 + h)*3 + wi)*16 + ic02) : 0;
      short8 af = *(const short8*)(p1s + a2);
      short8 z = {0,0,0,0,0,0,0,0};
      af = valid ? af : z;
      acc = __builtin_amdgcn_mfma_f32_16x16x32_bf16(af, bf2[c], acc, 0, 0, 0);
    }
    float v = fmaxf(fmaxf(acc[0], acc[1]), fmaxf(acc[2], acc[3]));
    v = fmaxf(v + bv2, 0.f);
    int Pout = tile*4 + qd;
    p2s[Pout*32 + nt2*16 + col] = f2bf(v);
  }
  __syncthreads();

  short8 bf3[27];
  #pragma unroll
  for (int c = 0; c < 27; ++c)
    bf3[c] = *(const short8*)(b3p + ((wid*27 + c)*64 + lane)*8);
  float bv3 = bias3[wid*16 + col];
  int ic03 = qd * 8;
  for (int tile = 0; tile < 21; ++tile) {
    int m = tile*16 + (lane & 15);
    bool vm = m < 324;
    int dd = m & 1, dh = (m >> 1) & 1;
    int P = m >> 2;
    int w = P % 3, t2 = P / 3;
    int ph = t2 % 9, pd = t2 / 9;
    int d0 = 2*pd + dd, h0 = 2*ph + dh;
    floatx4 acc = {0.f, 0.f, 0.f, 0.f};
    #pragma unroll
    for (int c = 0; c < 27; ++c) {
      const int kw = c % 3, kh = (c / 3) % 3, kd = c / 9;
      int d = d0 + kd - 1, h = h0 + kh - 1, wi = w + kw - 1;
      bool valid = vm && ((unsigned)d < 6u) && ((unsigned)h < 18u) && ((unsigned)wi < 3u);
      int a2 = valid ? (((d*18 + h)*3 + wi)*32 + ic03) : 0;
      short8 af = *(const short8*)(p2s + a2);
      short8 z = {0,0,0,0,0,0,0,0};
      af = valid ? af : z;
      acc = __builtin_amdgcn_mfma_f32_16x16x32_bf16(af, bf3[c], acc, 0, 0, 0);
    }
    int Pout = tile*4 + qd;
    if (Pout < 81) {
      float v = fmaxf(fmaxf(acc[0], acc[1]), fmaxf(acc[2], acc[3]));
      v = fmaxf(v + bv3, 0.f);
      size_t oi = ((size_t)b*81 + Pout)*64 + wid*16 + col;
      p3[oi] = v;
      p3bf[oi] = f2bf(v);
    }
  }
}

// ---------------- mean over 81 positions ----------------
__global__ __launch_bounds__(256) void mean_kernel(const float* __restrict__ p3,
                                                   float* __restrict__ me) {
  int i = blockIdx.x * 256 + threadIdx.x;
  int c = i & 63, b = i >> 6;
  const float* p = p3 + (size_t)b * 5184 + c;
  float s = 0.f;
  #pragma unroll 1
  for (int q = 0; q < 81; ++q) s += p[q*64];
  me[i] = s * (1.f / 81.f);
}

// ---------------- initial projections: h0, h2_0, ih_const ----------------
__global__ __launch_bounds__(256) void init_kernel(
    const float* __restrict__ me, const float* __restrict__ wiht,
    const float* __restrict__ b_init_h, const float* __restrict__ wih1t,
    const float* __restrict__ bih1, const float* __restrict__ bhh1,
    const float* __restrict__ wi2t, const float* __restrict__ b_init_h2,
    float* __restrict__ hout, float* __restrict__ h2out, float* __restrict__ ihcout) {
  __shared__ float sme[64];
  __shared__ float shl[256];
  int b = blockIdx.x, t = threadIdx.x;
  if (t < 64) sme[t] = me[b*64 + t];
  __syncthreads();
  float a = b_init_h[t];
  float cc = bih1[t] + bhh1[t];
  #pragma unroll 1
  for (int k = 0; k < 64; ++k) {
    float m = sme[k];
    a  += m * wiht[k*256 + t];
    cc += m * wih1t[k*256 + t];
  }
  hout[b*256 + t] = a; ihcout[b*256 + t] = cc; shl[t] = a;
  __syncthreads();
  float a2 = b_init_h2[t];
  #pragma unroll 1
  for (int k = 0; k < 256; ++k) a2 += shl[k] * wi2t[k*256 + t];
  h2out[b*256 + t] = a2;
}

// ---------------- RNN: register-resident MFMA, 32 blocks x 512 thr, M=16 rows
__global__ __launch_bounds__(512) void rnn2_kernel(
    const float* __restrict__ hin, const float* __restrict__ h2in,
    const float* __restrict__ ihc,
    const short* __restrict__ whh1b, const short* __restrict__ wih2b,
    const short* __restrict__ whh2b,
    const float* __restrict__ bih2, const float* __restrict__ bhh2,
    const float* __restrict__ w_fc, const float* __restrict__ b_fc,
    float* __restrict__ preds) {
  __shared__ __align__(16) short hbuf[2][16][264];
  __shared__ __align__(16) short h2buf[2][16][264];
  __shared__ __align__(16) short p2b[16][264];
  __shared__ float ihcL[16][260];
  __shared__ float predp[8][16];
  int tid = threadIdx.x;
  int bb = blockIdx.x * 16;
  int wid = tid >> 6, lane = tid & 63;
  int quad = lane >> 4, col = lane & 15;

  short8 wf[4][8];
  const short* wsel = (wid < 4) ? whh1b : whh2b;
  int nb = (wid & 3) * 64;
  #pragma unroll
  for (int t = 0; t < 4; ++t)
    #pragma unroll
    for (int c = 0; c < 8; ++c)
      wf[t][c] = *(const short8*)(wsel + (nb + t*16 + col)*256 + c*32 + quad*8);
  short8 w2f[2][8];
  int nb2 = wid * 32;
  #pragma unroll
  for (int t = 0; t < 2; ++t)
    #pragma unroll
    for (int c = 0; c < 8; ++c)
      w2f[t][c] = *(const short8*)(wih2b + (nb2 + t*16 + col)*256 + c*32 + quad*8);
  float b2v[2], wfcv[2];
  #pragma unroll
  for (int t = 0; t < 2; ++t) {
    int n = nb2 + t*16 + col;
    b2v[t] = bih2[n] + bhh2[n];
    wfcv[t] = w_fc[n];
  }
  float bfc = b_fc[0];

  for (int i = tid; i < 4096; i += 512) {
    int m = i >> 8, k = i & 255;
    hbuf[0][m][k]  = f2bf(hin[(bb + m)*256 + k]);
    h2buf[0][m][k] = f2bf(h2in[(bb + m)*256 + k]);
    ihcL[m][k]     = ihc[(bb + m)*256 + k];
  }
  __syncthreads();

  for (int step = 0; step < 23; ++step) {
    int cur = step & 1, nxt = cur ^ 1;
    floatx4 acc[4];
    if (wid < 4) {
      #pragma unroll
      for (int t = 0; t < 4; ++t)
        #pragma unroll
        for (int r = 0; r < 4; ++r)
          acc[t][r] = ihcL[quad*4 + r][nb + t*16 + col];
    } else {
      #pragma unroll
      for (int t = 0; t < 4; ++t) {
        floatx4 z = {0.f, 0.f, 0.f, 0.f};
        acc[t] = z;
      }
    }
    const short (*src)[264] = (wid < 4) ? hbuf[cur] : h2buf[cur];
    #pragma unroll
    for (int c = 0; c < 8; ++c) {
      short8 a = *(const short8*)&src[col][c*32 + quad*8];
      #pragma unroll
      for (int t = 0; t < 4; ++t)
        acc[t] = __builtin_amdgcn_mfma_f32_16x16x32_bf16(a, wf[t][c], acc[t], 0, 0, 0);
    }
    if (wid < 4) {
      #pragma unroll
      for (int t = 0; t < 4; ++t)
        #pragma unroll
        for (int r = 0; r < 4; ++r)
          hbuf[nxt][quad*4 + r][nb + t*16 + col] = f2bf(tanhf(acc[t][r]));
    } else {
      #pragma unroll
      for (int t = 0; t < 4; ++t)
        #pragma unroll
        for (int r = 0; r < 4; ++r)
          p2b[quad*4 + r][nb + t*16 + col] = f2bf(acc[t][r]);
    }
    __syncthreads();
    floatx4 q0 = {0.f,0.f,0.f,0.f}, q1 = {0.f,0.f,0.f,0.f};
    #pragma unroll
    for (int c = 0; c < 8; ++c) {
      short8 a = *(const short8*)&hbuf[nxt][col][c*32 + quad*8];
      q0 = __builtin_amdgcn_mfma_f32_16x16x32_bf16(a, w2f[0][c], q0, 0, 0, 0);
      q1 = __builtin_amdgcn_mfma_f32_16x16x32_bf16(a, w2f[1][c], q1, 0, 0, 0);
    }
    float pr[4];
    #pragma unroll
    for (int r = 0; r < 4; ++r) {
      float v0 = q0[r] + bf2f(p2b[quad*4 + r][nb2 + col]) + b2v[0];
      float v1 = q1[r] + bf2f(p2b[quad*4 + r][nb2 + 16 + col]) + b2v[1];
      float t0 = tanhf(v0), t1 = tanhf(v1);
      h2buf[nxt][quad*4 + r][nb2 + col] = f2bf(t0);
      h2buf[nxt][quad*4 + r][nb2 + 16 + col] = f2bf(t1);
      pr[r] = t0*wfcv[0] + t1*wfcv[1];
    }
    #pragma unroll
    for (int r = 0; r < 4; ++r) {
      #pragma unroll
      for (int off = 1; off < 16; off <<= 1)
        pr[r] += __shfl_xor(pr[r], off, 64);
    }
    if (col == 0) {
      #pragma unroll
      for (int r = 0; r < 4; ++r) predp[wid][quad*4 + r] = pr[r];
    }
    __syncthreads();
    if (tid < 16) {
      float s = bfc;
      #pragma unroll
      for (int w = 0; w < 8; ++w) s += predp[w][tid];
      preds[(size_t)(bb + tid)*23 + step] = s;
    }
  }
}

// ---------------- lin1 MFMA GEMM: (512x5184) x (5184x256) -> t1 fp32 ----------------
// grid (8 M-blocks of 64, 4 N-blocks of 64); wave = 16M x 64N, full K.
__global__ __launch_bounds__(256) void lin_gemm(
    const short* __restrict__ p3bf, const short* __restrict__ wl1p,
    const float* __restrict__ b_lin1, float* __restrict__ t1) {
  int tid = threadIdx.x;
  int lane = tid & 63, wid = tid >> 6;
  int quad = lane >> 4, col = lane & 15;
  int mt = blockIdx.x, ntb = blockIdx.y;
  int m0 = mt*64 + wid*16;
  floatx4 acc[4];
  #pragma unroll
  for (int t = 0; t < 4; ++t) {
    float bv = b_lin1[ntb*64 + t*16 + col];
    #pragma unroll
    for (int r = 0; r < 4; ++r) acc[t][r] = bv;
  }
  const short* arow = p3bf + (size_t)(m0 + col)*5184 + quad*8;
  const short* bbase = wl1p + ((size_t)(ntb*4)*162)*512 + lane*8;
  #pragma unroll 2
  for (int c = 0; c < 162; ++c) {
    short8 a = *(const short8*)(arow + c*32);
    #pragma unroll
    for (int t = 0; t < 4; ++t) {
      short8 b = *(const short8*)(bbase + (size_t)(t*162 + c)*512);
      acc[t] = __builtin_amdgcn_mfma_f32_16x16x32_bf16(a, b, acc[t], 0, 0, 0);
    }
  }
  #pragma unroll
  for (int t = 0; t < 4; ++t)
    #pragma unroll
    for (int r = 0; r < 4; ++r)
      t1[(size_t)(m0 + quad*4 + r)*256 + ntb*64 + t*16 + col] = acc[t][r];
}

// ---------------- lin epilogue: tanh + (256 -> 12) ----------------
__global__ __launch_bounds__(256) void lin_fin(
    const float* __restrict__ t1, const float* __restrict__ w_lin2,
    const float* __restrict__ b_lin2, float* __restrict__ outc) {
  __shared__ float st[16][257];
  int tid = threadIdx.x;
  int bb = blockIdx.x * 16;
  for (int i = tid; i < 4096; i += 256) {
    int m = i >> 8, k = i & 255;
    st[m][k] = tanhf(t1[(size_t)(bb + m)*256 + k]);
  }
  __syncthreads();
  if (tid < 192) {
    int r = tid / 12, j = tid % 12;
    float s = b_lin2[j];
    #pragma unroll 1
    for (int k = 0; k < 256; ++k) s += st[r][k] * w_lin2[j*256 + k];
    outc[(size_t)(bb + r)*12 + j] = s;
  }
}

// ---------------- launch ----------------
extern "C" void kernel_launch(void* const* d_in, const int* in_sizes, int n_in,
                              void* d_out, int out_size, void* d_ws, size_t ws_size,
                              hipStream_t stream) {
  const float* x         = (const float*)d_in[0];
  const float* w1        = (const float*)d_in[1];
  const float* b1        = (const float*)d_in[2];
  const float* w2        = (const float*)d_in[3];
  const float* b2        = (const float*)d_in[4];
  const float* w3        = (const float*)d_in[5];
  const float* b3        = (const float*)d_in[6];
  const float* wih1      = (const float*)d_in[7];
  const float* whh1      = (const float*)d_in[8];
  const float* bih1      = (const float*)d_in[9];
  const float* bhh1      = (const float*)d_in[10];
  const float* wih2      = (const float*)d_in[11];
  const float* whh2      = (const float*)d_in[12];
  const float* bih2      = (const float*)d_in[13];
  const float* bhh2      = (const float*)d_in[14];
  const float* w_init_h  = (const float*)d_in[15];
  const float* b_init_h  = (const float*)d_in[16];
  const float* w_init_h2 = (const float*)d_in[17];
  const float* b_init_h2 = (const float*)d_in[18];
  const float* w_fc      = (const float*)d_in[19];
  const float* b_fc      = (const float*)d_in[20];
  const float* w_lin1    = (const float*)d_in[21];
  const float* b_lin1    = (const float*)d_in[22];
  const float* w_lin2    = (const float*)d_in[23];
  const float* b_lin2    = (const float*)d_in[24];
  float* ws  = (float*)d_ws;
  float* out = (float*)d_out;

  prep_kernel<<<6622, 256, 0, stream>>>(w1, w2, w3, w_init_h, wih1, w_init_h2,
                                        whh1, wih2, whh2, w_lin1, ws);
  conv1_mfma<<<1024, 256, 0, stream>>>(x, (const short*)(ws + OFF_B1P), b1,
                                       (short*)(ws + OFF_P1));
  conv23_mfma<<<512, 256, 0, stream>>>((const short*)(ws + OFF_P1),
                                       (const short*)(ws + OFF_B2P),
                                       (const short*)(ws + OFF_B3P),
                                       b2, b3, ws + OFF_P3, (short*)(ws + OFF_P3BF));
  mean_kernel<<<128, 256, 0, stream>>>(ws + OFF_P3, ws + OFF_ME);
  init_kernel<<<512, 256, 0, stream>>>(ws + OFF_ME, ws + OFF_WIHT, b_init_h, ws + OFF_WIH1T,
                                       bih1, bhh1, ws + OFF_WI2T, b_init_h2,
                                       ws + OFF_H, ws + OFF_H2, ws + OFF_IHC);
  rnn2_kernel<<<32, 512, 0, stream>>>(ws + OFF_H, ws + OFF_H2, ws + OFF_IHC,
                                      (const short*)(ws + OFF_WHH1B),
                                      (const short*)(ws + OFF_WIH2B),
                                      (const short*)(ws + OFF_WHH2B),
                                      bih2, bhh2, w_fc, b_fc, out);
  lin_gemm<<<dim3(8, 4), 256, 0, stream>>>((const short*)(ws + OFF_P3BF),
                                           (const short*)(ws + OFF_WL1P),
                                           b_lin1, ws + OFF_T1);
  lin_fin<<<32, 256, 0, stream>>>(ws + OFF_T1, w_lin2, b_lin2, out + 11776);
}

// Round 5
// 449.067 us; speedup vs baseline: 9.2186x; 1.3204x over previous
//
#include <hip/hip_runtime.h>
#include <hip/hip_bf16.h>

typedef __attribute__((ext_vector_type(8))) short short8;
typedef __attribute__((ext_vector_type(4))) float floatx4;

// ---------------- workspace layout (float offsets) ----------------
#define OFF_B1P   0        // conv1 B frags [7][64][8] bf16
#define OFF_B2P   1792     // conv2 B frags [2][14][64][8] bf16
#define OFF_B3P   8960     // conv3 B frags [4][27][64][8] bf16
#define OFF_WIHT  36608    // w_init_h^T  (64,256)
#define OFF_WIH1T 52992    // wih1^T      (64,256)
#define OFF_WI2T  69376    // w_init_h2^T (256,256)
#define OFF_WHH1B 134912   // whh1 bf16 row-major [t][k]
#define OFF_WIH2B 167680   // wih2 bf16 row-major
#define OFF_WHH2B 200448   // whh2 bf16 row-major
#define OFF_WL1P  233216   // w_lin1 MFMA frags [nt16][c162][lane64][j8] bf16
#define OFF_ME    896768   // mean_enc (512,64)
#define OFF_H     929536   // h0  (512,256)
#define OFF_H2    1060608  // h2_0(512,256)
#define OFF_IHC   1191680  // ih_const (512,256)
#define OFF_P1    1322752  // p1 bf16 [512][1296][16]
#define OFF_P3    6631168  // p3 fp32 [512][81][64] == flat
#define OFF_P3BF  9285376  // p3 bf16 copy [512][5184]
#define OFF_T1    10612480 // lin1 pre-tanh acc (512,256) fp32

static __device__ inline short f2bf(float f) {
  union { __hip_bfloat16 h; short s; } u;
  u.h = __float2bfloat16(f);
  return u.s;
}
static __device__ inline float bf2f(short s) {
  union { unsigned u; float f; } v;
  v.u = ((unsigned)(unsigned short)s) << 16;
  return v.f;
}
// fast tanh: v_exp_f32 + v_rcp_f32, rel err ~1e-6 (<< bf16 noise)
static __device__ inline float fast_tanh(float x) {
  x = fminf(fmaxf(x, -12.f), 12.f);
  float e = __expf(2.f * x);
  return (e - 1.f) * __builtin_amdgcn_rcpf(e + 1.f);
}

// ---------------- prep: weight frag packs + RNN/linear packs ----------------
__global__ __launch_bounds__(256) void prep_kernel(
    const float* __restrict__ w1, const float* __restrict__ w2, const float* __restrict__ w3,
    const float* __restrict__ w_init_h, const float* __restrict__ wih1,
    const float* __restrict__ w_init_h2, const float* __restrict__ whh1,
    const float* __restrict__ wih2, const float* __restrict__ whh2,
    const float* __restrict__ w_lin1, float* __restrict__ ws) {
  int i = blockIdx.x * 256 + threadIdx.x;
  // conv1 B: k = tap*8 + icp (K=224, 7 chunks)
  if (i < 3584) {
    int j = i & 7, l = (i >> 3) & 63, c = i >> 9;
    int k = c*32 + ((l >> 4) << 3) + j;
    int tap = k >> 3, icp = k & 7, oc = l & 15;
    float v = (tap < 27 && icp < 6) ? w1[(oc*6 + icp)*27 + tap] : 0.f;
    ((__hip_bfloat16*)(ws + OFF_B1P))[i] = __float2bfloat16(v);
    return;
  }
  i -= 3584;
  // conv2 B: k = tap*16 + ic (K=448, 14 chunks)
  if (i < 14336) {
    int j = i & 7, l = (i >> 3) & 63, cc = i >> 9;
    int c = cc % 14, nt = cc / 14;
    int k = c*32 + ((l >> 4) << 3) + j;
    int tap = k >> 4, ic = k & 15, oc = nt*16 + (l & 15);
    float v = (tap < 27) ? w2[(oc*16 + ic)*27 + tap] : 0.f;
    ((__hip_bfloat16*)(ws + OFF_B2P))[i] = __float2bfloat16(v);
    return;
  }
  i -= 14336;
  // conv3 B: k = tap*32 + ic (K=864, 27 chunks)
  if (i < 55296) {
    int j = i & 7, l = (i >> 3) & 63, cc = i >> 9;
    int c = cc % 27, nt = cc / 27;
    int k = c*32 + ((l >> 4) << 3) + j;
    int ic = k & 31, oc = nt*16 + (l & 15);
    ((__hip_bfloat16*)(ws + OFF_B3P))[i] = __float2bfloat16(w3[(oc*32 + ic)*27 + c]);
    return;
  }
  i -= 55296;
  if (i < 16384) { int t = i & 255, k = i >> 8; ws[OFF_WIHT + i]  = w_init_h[t*64 + k];  return; }
  i -= 16384;
  if (i < 16384) { int t = i & 255, k = i >> 8; ws[OFF_WIH1T + i] = wih1[t*64 + k];      return; }
  i -= 16384;
  if (i < 65536) { int t = i & 255, k = i >> 8; ws[OFF_WI2T + i]  = w_init_h2[t*256 + k]; return; }
  i -= 65536;
  if (i < 65536) { ((__hip_bfloat16*)(ws + OFF_WHH1B))[i] = __float2bfloat16(whh1[i]); return; }
  i -= 65536;
  if (i < 65536) { ((__hip_bfloat16*)(ws + OFF_WIH2B))[i] = __float2bfloat16(wih2[i]); return; }
  i -= 65536;
  if (i < 65536) { ((__hip_bfloat16*)(ws + OFF_WHH2B))[i] = __float2bfloat16(whh2[i]); return; }
  i -= 65536;
  // w_lin1 MFMA B-frags: [nt][c][lane][j]
  if (i < 1327104) {
    int j = i & 7, l = (i >> 3) & 63, cc = i >> 9;
    int c = cc % 162, nt = cc / 162;
    int k = c*32 + ((l >> 4) << 3) + j;
    int n = nt*16 + (l & 15);
    ((__hip_bfloat16*)(ws + OFF_WL1P))[i] = __float2bfloat16(w_lin1[n*5184 + k]);
    return;
  }
}

// ---------------- conv1 MFMA, halo slab: x (512,6,24,72,3) -> p1 bf16 [b][1296][16]
// 4 blocks per batch row; slab [dslot8][h+1:74][w+1:5][ic8] zero-padded halo.
__global__ __launch_bounds__(256) void conv1_mfma(
    const float* __restrict__ x, const short* __restrict__ b1p,
    const float* __restrict__ bias, short* __restrict__ p1) {
  __shared__ __align__(16) short slab[8 * 74 * 5 * 8];   // 23680 shorts = 47360 B
  int tid = threadIdx.x;
  int b = blockIdx.x >> 2, q = blockIdx.x & 3;
  for (int i = tid; i < 11840; i += 256) ((unsigned*)slab)[i] = 0u;
  __syncthreads();
  // stage: 8 dslots x 6 ic x 54 float4
  for (int i = tid; i < 2592; i += 256) {
    int dslot = i / 324;
    int r = i - dslot*324;
    int ic = r / 54;
    int f4 = r - ic*54;
    int d = 6*q - 1 + dslot;
    if ((unsigned)d < 24u) {
      float4 v = *(const float4*)(x + ((size_t)(b*6 + ic)*24 + d)*216 + f4*4);
      int pos = f4*4;
      int h0 = pos / 3, w0 = pos - h0*3;
      int hh = h0 + 1, ww = w0 + 1;
      float vv[4] = {v.x, v.y, v.z, v.w};
      #pragma unroll
      for (int e = 0; e < 4; ++e) {
        slab[((dslot*74 + hh)*5 + ww)*8 + ic] = f2bf(vv[e]);
        ++ww; if (ww == 4) { ww = 1; ++hh; }
      }
    }
  }
  int lane = tid & 63, wid = tid >> 6;
  int quad = lane >> 4, col = lane & 15;
  short8 bf[7];
  #pragma unroll
  for (int c = 0; c < 7; ++c) bf[c] = *(const short8*)(b1p + (c*64 + lane)*8);
  int tapoff[7];
  #pragma unroll
  for (int c = 0; c < 7; ++c) {
    int tap = c*4 + quad;
    int tt = tap < 27 ? tap : 26;       // tap>=27 has zero B-frag; clamp addr only
    int kd = tt/9, rr = tt - kd*9, kh = rr/3, kw = rr - kh*3;
    tapoff[c] = ((kd*74 + kh)*5 + kw)*8;
  }
  float bv = bias[col];
  __syncthreads();
  for (int tile = wid; tile < 81; tile += 4) {
    int m = tile*16 + col;
    int dd = m & 1, dh = (m >> 1) & 1;
    int P = m >> 2;
    int t2 = P/3; int w = P - t2*3;
    int pdl = t2/36; int ph = t2 - pdl*36;
    int base = (((2*pdl + dd)*74 + 2*ph + dh)*5 + w)*8;
    floatx4 acc = {0.f, 0.f, 0.f, 0.f};
    #pragma unroll
    for (int c = 0; c < 7; ++c) {
      short8 af = *(const short8*)(slab + base + tapoff[c]);
      acc = __builtin_amdgcn_mfma_f32_16x16x32_bf16(af, bf[c], acc, 0, 0, 0);
    }
    float v = fmaxf(fmaxf(acc[0], acc[1]), fmaxf(acc[2], acc[3]));
    v = fmaxf(v + bv, 0.f);
    int Pout = q*324 + tile*4 + quad;
    p1[((size_t)b*1296 + Pout)*16 + col] = f2bf(v);
  }
}

// ---------------- fused conv2+conv3 MFMA per batch + mean fusion ----------------
__global__ __launch_bounds__(256) void conv23_mfma(
    const short* __restrict__ p1, const short* __restrict__ b2p,
    const short* __restrict__ b3p,
    const float* __restrict__ bias2, const float* __restrict__ bias3,
    float* __restrict__ p3, short* __restrict__ p3bf, float* __restrict__ me) {
  __shared__ __align__(16) short p1s[20736];
  __shared__ __align__(16) short p2s[10368];
  __shared__ float smean[4][16];
  int tid = threadIdx.x;
  int b = blockIdx.x;
  int lane = tid & 63, wid = tid >> 6;
  int qd = lane >> 4, col = lane & 15;
  const short* p1b = p1 + (size_t)b * 20736;
  for (int i = tid; i < 2592; i += 256)
    *(short8*)(p1s + i*8) = *(const short8*)(p1b + i*8);

  int nt2 = wid & 1;
  short8 bf2[14];
  #pragma unroll
  for (int c = 0; c < 14; ++c)
    bf2[c] = *(const short8*)(b2p + ((nt2*14 + c)*64 + lane)*8);
  int kdm1[14], khm1[14], kwm1[14]; bool tv2[14];
  #pragma unroll
  for (int c = 0; c < 14; ++c) {
    int tap = c*2 + (qd >> 1);
    tv2[c] = tap < 27;
    int tt = tv2[c] ? tap : 0;
    kwm1[c] = tt % 3 - 1; khm1[c] = (tt/3) % 3 - 1; kdm1[c] = tt/9 - 1;
  }
  int ic02 = (qd & 1) * 8;
  float bv2 = bias2[nt2*16 + col];
  __syncthreads();
  for (int tile = (wid >> 1); tile < 81; tile += 2) {
    int m = tile*16 + (lane & 15);
    int dd = m & 1, dh = (m >> 1) & 1;
    int P = m >> 2;
    int w = P % 3, t2 = P / 3;
    int ph = t2 % 18, pd = t2 / 18;
    int d0 = 2*pd + dd, h0 = 2*ph + dh;
    floatx4 acc = {0.f, 0.f, 0.f, 0.f};
    #pragma unroll
    for (int c = 0; c < 14; ++c) {
      int d = d0 + kdm1[c], h = h0 + khm1[c], wi = w + kwm1[c];
      bool valid = tv2[c] && ((unsigned)d < 12u) && ((unsigned)h < 36u) && ((unsigned)wi < 3u);
      int a2 = valid ? (((d*36 + h)*3 + wi)*16 + ic02) : 0;
      short8 af = *(const short8*)(p1s + a2);
      short8 z = {0,0,0,0,0,0,0,0};
      af = valid ? af : z;
      acc = __builtin_amdgcn_mfma_f32_16x16x32_bf16(af, bf2[c], acc, 0, 0, 0);
    }
    float v = fmaxf(fmaxf(acc[0], acc[1]), fmaxf(acc[2], acc[3]));
    v = fmaxf(v + bv2, 0.f);
    int Pout = tile*4 + qd;
    p2s[Pout*32 + nt2*16 + col] = f2bf(v);
  }
  __syncthreads();

  short8 bf3[27];
  #pragma unroll
  for (int c = 0; c < 27; ++c)
    bf3[c] = *(const short8*)(b3p + ((wid*27 + c)*64 + lane)*8);
  float bv3 = bias3[wid*16 + col];
  int ic03 = qd * 8;
  float msum = 0.f;
  for (int tile = 0; tile < 21; ++tile) {
    int m = tile*16 + (lane & 15);
    bool vm = m < 324;
    int dd = m & 1, dh = (m >> 1) & 1;
    int P = m >> 2;
    int w = P % 3, t2 = P / 3;
    int ph = t2 % 9, pd = t2 / 9;
    int d0 = 2*pd + dd, h0 = 2*ph + dh;
    floatx4 acc = {0.f, 0.f, 0.f, 0.f};
    #pragma unroll
    for (int c = 0; c < 27; ++c) {
      const int kw = c % 3, kh = (c / 3) % 3, kd = c / 9;
      int d = d0 + kd - 1, h = h0 + kh - 1, wi = w + kw - 1;
      bool valid = vm && ((unsigned)d < 6u) && ((unsigned)h < 18u) && ((unsigned)wi < 3u);
      int a2 = valid ? (((d*18 + h)*3 + wi)*32 + ic03) : 0;
      short8 af = *(const short8*)(p2s + a2);
      short8 z = {0,0,0,0,0,0,0,0};
      af = valid ? af : z;
      acc = __builtin_amdgcn_mfma_f32_16x16x32_bf16(af, bf3[c], acc, 0, 0, 0);
    }
    int Pout = tile*4 + qd;
    if (Pout < 81) {
      float v = fmaxf(fmaxf(acc[0], acc[1]), fmaxf(acc[2], acc[3]));
      v = fmaxf(v + bv3, 0.f);
      size_t oi = ((size_t)b*81 + Pout)*64 + wid*16 + col;
      p3[oi] = v;
      p3bf[oi] = f2bf(v);
      msum += v;
    }
  }
  // mean over the 81 positions: reduce over quads (each wave covers all Pout for its 16 ch)
  msum += __shfl_xor(msum, 16, 64);
  msum += __shfl_xor(msum, 32, 64);
  if (lane < 16) smean[wid][lane] = msum;
  __syncthreads();
  if (tid < 64) me[b*64 + tid] = smean[tid >> 4][tid & 15] * (1.f / 81.f);
}

// ---------------- initial projections: 64 blocks x 8 rows ----------------
__global__ __launch_bounds__(256) void init_kernel(
    const float* __restrict__ me, const float* __restrict__ wiht,
    const float* __restrict__ b_init_h, const float* __restrict__ wih1t,
    const float* __restrict__ bih1, const float* __restrict__ bhh1,
    const float* __restrict__ wi2t, const float* __restrict__ b_init_h2,
    float* __restrict__ hout, float* __restrict__ h2out, float* __restrict__ ihcout) {
  __shared__ float sme[8][64];
  __shared__ float shl[8][256];
  int t = threadIdx.x; int bb = blockIdx.x * 8;
  for (int i = t; i < 512; i += 256) {
    int m = i >> 6, c = i & 63;
    sme[m][c] = me[(bb + m)*64 + c];
  }
  __syncthreads();
  float a[8], cc[8];
  float ba = b_init_h[t], bc = bih1[t] + bhh1[t];
  #pragma unroll
  for (int r = 0; r < 8; ++r) { a[r] = ba; cc[r] = bc; }
  #pragma unroll 2
  for (int k = 0; k < 64; ++k) {
    float w1v = wiht[k*256 + t], w2v = wih1t[k*256 + t];
    #pragma unroll
    for (int r = 0; r < 8; ++r) {
      float m = sme[r][k];
      a[r]  += m * w1v;
      cc[r] += m * w2v;
    }
  }
  #pragma unroll
  for (int r = 0; r < 8; ++r) {
    hout[(size_t)(bb + r)*256 + t] = a[r];
    ihcout[(size_t)(bb + r)*256 + t] = cc[r];
    shl[r][t] = a[r];
  }
  __syncthreads();
  float a2[8];
  float b2 = b_init_h2[t];
  #pragma unroll
  for (int r = 0; r < 8; ++r) a2[r] = b2;
  #pragma unroll 2
  for (int k = 0; k < 256; ++k) {
    float wv = wi2t[k*256 + t];
    #pragma unroll
    for (int r = 0; r < 8; ++r) a2[r] += shl[r][k] * wv;
  }
  #pragma unroll
  for (int r = 0; r < 8; ++r) h2out[(size_t)(bb + r)*256 + t] = a2[r];
}

// ---------------- RNN: register-resident MFMA, 32 blocks x 512 thr, M=16 rows
__global__ __launch_bounds__(512) void rnn2_kernel(
    const float* __restrict__ hin, const float* __restrict__ h2in,
    const float* __restrict__ ihc,
    const short* __restrict__ whh1b, const short* __restrict__ wih2b,
    const short* __restrict__ whh2b,
    const float* __restrict__ bih2, const float* __restrict__ bhh2,
    const float* __restrict__ w_fc, const float* __restrict__ b_fc,
    float* __restrict__ preds) {
  __shared__ __align__(16) short hbuf[2][16][264];
  __shared__ __align__(16) short h2buf[2][16][264];
  __shared__ __align__(16) short p2b[16][264];
  __shared__ float ihcL[16][260];
  __shared__ float predp[8][16];
  int tid = threadIdx.x;
  int bb = blockIdx.x * 16;
  int wid = tid >> 6, lane = tid & 63;
  int quad = lane >> 4, col = lane & 15;

  short8 wf[4][8];
  const short* wsel = (wid < 4) ? whh1b : whh2b;
  int nb = (wid & 3) * 64;
  #pragma unroll
  for (int t = 0; t < 4; ++t)
    #pragma unroll
    for (int c = 0; c < 8; ++c)
      wf[t][c] = *(const short8*)(wsel + (nb + t*16 + col)*256 + c*32 + quad*8);
  short8 w2f[2][8];
  int nb2 = wid * 32;
  #pragma unroll
  for (int t = 0; t < 2; ++t)
    #pragma unroll
    for (int c = 0; c < 8; ++c)
      w2f[t][c] = *(const short8*)(wih2b + (nb2 + t*16 + col)*256 + c*32 + quad*8);
  float b2v[2], wfcv[2];
  #pragma unroll
  for (int t = 0; t < 2; ++t) {
    int n = nb2 + t*16 + col;
    b2v[t] = bih2[n] + bhh2[n];
    wfcv[t] = w_fc[n];
  }
  float bfc = b_fc[0];

  for (int i = tid; i < 4096; i += 512) {
    int m = i >> 8, k = i & 255;
    hbuf[0][m][k]  = f2bf(hin[(bb + m)*256 + k]);
    h2buf[0][m][k] = f2bf(h2in[(bb + m)*256 + k]);
    ihcL[m][k]     = ihc[(bb + m)*256 + k];
  }
  __syncthreads();

  for (int step = 0; step < 23; ++step) {
    int cur = step & 1, nxt = cur ^ 1;
    floatx4 acc[4];
    if (wid < 4) {
      #pragma unroll
      for (int t = 0; t < 4; ++t)
        #pragma unroll
        for (int r = 0; r < 4; ++r)
          acc[t][r] = ihcL[quad*4 + r][nb + t*16 + col];
    } else {
      #pragma unroll
      for (int t = 0; t < 4; ++t) {
        floatx4 z = {0.f, 0.f, 0.f, 0.f};
        acc[t] = z;
      }
    }
    const short (*src)[264] = (wid < 4) ? hbuf[cur] : h2buf[cur];
    #pragma unroll
    for (int c = 0; c < 8; ++c) {
      short8 a = *(const short8*)&src[col][c*32 + quad*8];
      #pragma unroll
      for (int t = 0; t < 4; ++t)
        acc[t] = __builtin_amdgcn_mfma_f32_16x16x32_bf16(a, wf[t][c], acc[t], 0, 0, 0);
    }
    if (wid < 4) {
      #pragma unroll
      for (int t = 0; t < 4; ++t)
        #pragma unroll
        for (int r = 0; r < 4; ++r)
          hbuf[nxt][quad*4 + r][nb + t*16 + col] = f2bf(fast_tanh(acc[t][r]));
    } else {
      #pragma unroll
      for (int t = 0; t < 4; ++t)
        #pragma unroll
        for (int r = 0; r < 4; ++r)
          p2b[quad*4 + r][nb + t*16 + col] = f2bf(acc[t][r]);
    }
    __syncthreads();
    floatx4 q0 = {0.f,0.f,0.f,0.f}, q1 = {0.f,0.f,0.f,0.f};
    #pragma unroll
    for (int c = 0; c < 8; ++c) {
      short8 a = *(const short8*)&hbuf[nxt][col][c*32 + quad*8];
      q0 = __builtin_amdgcn_mfma_f32_16x16x32_bf16(a, w2f[0][c], q0, 0, 0, 0);
      q1 = __builtin_amdgcn_mfma_f32_16x16x32_bf16(a, w2f[1][c], q1, 0, 0, 0);
    }
    float pr[4];
    #pragma unroll
    for (int r = 0; r < 4; ++r) {
      float v0 = q0[r] + bf2f(p2b[quad*4 + r][nb2 + col]) + b2v[0];
      float v1 = q1[r] + bf2f(p2b[quad*4 + r][nb2 + 16 + col]) + b2v[1];
      float t0 = fast_tanh(v0), t1 = fast_tanh(v1);
      h2buf[nxt][quad*4 + r][nb2 + col] = f2bf(t0);
      h2buf[nxt][quad*4 + r][nb2 + 16 + col] = f2bf(t1);
      pr[r] = t0*wfcv[0] + t1*wfcv[1];
    }
    #pragma unroll
    for (int r = 0; r < 4; ++r) {
      #pragma unroll
      for (int off = 1; off < 16; off <<= 1)
        pr[r] += __shfl_xor(pr[r], off, 64);
    }
    if (col == 0) {
      #pragma unroll
      for (int r = 0; r < 4; ++r) predp[wid][quad*4 + r] = pr[r];
    }
    __syncthreads();
    if (tid < 16) {
      float s = bfc;
      #pragma unroll
      for (int w = 0; w < 8; ++w) s += predp[w][tid];
      preds[(size_t)(bb + tid)*23 + step] = s;
    }
  }
}

// ---------------- lin1 MFMA GEMM: (512x5184) x (5184x256) -> t1 fp32 ----------------
__global__ __launch_bounds__(256) void lin_gemm(
    const short* __restrict__ p3bf, const short* __restrict__ wl1p,
    const float* __restrict__ b_lin1, float* __restrict__ t1) {
  int tid = threadIdx.x;
  int lane = tid & 63, wid = tid >> 6;
  int quad = lane >> 4, col = lane & 15;
  int mt = blockIdx.x, ntb = blockIdx.y;
  int m0 = mt*64 + wid*16;
  floatx4 acc[4];
  #pragma unroll
  for (int t = 0; t < 4; ++t) {
    float bv = b_lin1[ntb*64 + t*16 + col];
    #pragma unroll
    for (int r = 0; r < 4; ++r) acc[t][r] = bv;
  }
  const short* arow = p3bf + (size_t)(m0 + col)*5184 + quad*8;
  const short* bbase = wl1p + ((size_t)(ntb*4)*162)*512 + lane*8;
  #pragma unroll 2
  for (int c = 0; c < 162; ++c) {
    short8 a = *(const short8*)(arow + c*32);
    #pragma unroll
    for (int t = 0; t < 4; ++t) {
      short8 b = *(const short8*)(bbase + (size_t)(t*162 + c)*512);
      acc[t] = __builtin_amdgcn_mfma_f32_16x16x32_bf16(a, b, acc[t], 0, 0, 0);
    }
  }
  #pragma unroll
  for (int t = 0; t < 4; ++t)
    #pragma unroll
    for (int r = 0; r < 4; ++r)
      t1[(size_t)(m0 + quad*4 + r)*256 + ntb*64 + t*16 + col] = acc[t][r];
}

// ---------------- lin epilogue: tanh + (256 -> 12) ----------------
__global__ __launch_bounds__(256) void lin_fin(
    const float* __restrict__ t1, const float* __restrict__ w_lin2,
    const float* __restrict__ b_lin2, float* __restrict__ outc) {
  __shared__ float st[16][257];
  int tid = threadIdx.x;
  int bb = blockIdx.x * 16;
  for (int i = tid; i < 4096; i += 256) {
    int m = i >> 8, k = i & 255;
    st[m][k] = fast_tanh(t1[(size_t)(bb + m)*256 + k]);
  }
  __syncthreads();
  if (tid < 192) {
    int r = tid / 12, j = tid % 12;
    float s = b_lin2[j];
    #pragma unroll 1
    for (int k = 0; k < 256; ++k) s += st[r][k] * w_lin2[j*256 + k];
    outc[(size_t)(bb + r)*12 + j] = s;
  }
}

// ---------------- launch ----------------
extern "C" void kernel_launch(void* const* d_in, const int* in_sizes, int n_in,
                              void* d_out, int out_size, void* d_ws, size_t ws_size,
                              hipStream_t stream) {
  const float* x         = (const float*)d_in[0];
  const float* w1        = (const float*)d_in[1];
  const float* b1        = (const float*)d_in[2];
  const float* w2        = (const float*)d_in[3];
  const float* b2        = (const float*)d_in[4];
  const float* w3        = (const float*)d_in[5];
  const float* b3        = (const float*)d_in[6];
  const float* wih1      = (const float*)d_in[7];
  const float* whh1      = (const float*)d_in[8];
  const float* bih1      = (const float*)d_in[9];
  const float* bhh1      = (const float*)d_in[10];
  const float* wih2      = (const float*)d_in[11];
  const float* whh2      = (const float*)d_in[12];
  const float* bih2      = (const float*)d_in[13];
  const float* bhh2      = (const float*)d_in[14];
  const float* w_init_h  = (const float*)d_in[15];
  const float* b_init_h  = (const float*)d_in[16];
  const float* w_init_h2 = (const float*)d_in[17];
  const float* b_init_h2 = (const float*)d_in[18];
  const float* w_fc      = (const float*)d_in[19];
  const float* b_fc      = (const float*)d_in[20];
  const float* w_lin1    = (const float*)d_in[21];
  const float* b_lin1    = (const float*)d_in[22];
  const float* w_lin2    = (const float*)d_in[23];
  const float* b_lin2    = (const float*)d_in[24];
  float* ws  = (float*)d_ws;
  float* out = (float*)d_out;

  prep_kernel<<<6622, 256, 0, stream>>>(w1, w2, w3, w_init_h, wih1, w_init_h2,
                                        whh1, wih2, whh2, w_lin1, ws);
  conv1_mfma<<<2048, 256, 0, stream>>>(x, (const short*)(ws + OFF_B1P), b1,
                                       (short*)(ws + OFF_P1));
  conv23_mfma<<<512, 256, 0, stream>>>((const short*)(ws + OFF_P1),
                                       (const short*)(ws + OFF_B2P),
                                       (const short*)(ws + OFF_B3P),
                                       b2, b3, ws + OFF_P3, (short*)(ws + OFF_P3BF),
                                       ws + OFF_ME);
  init_kernel<<<64, 256, 0, stream>>>(ws + OFF_ME, ws + OFF_WIHT, b_init_h, ws + OFF_WIH1T,
                                      bih1, bhh1, ws + OFF_WI2T, b_init_h2,
                                      ws + OFF_H, ws + OFF_H2, ws + OFF_IHC);
  rnn2_kernel<<<32, 512, 0, stream>>>(ws + OFF_H, ws + OFF_H2, ws + OFF_IHC,
                                      (const short*)(ws + OFF_WHH1B),
                                      (const short*)(ws + OFF_WIH2B),
                                      (const short*)(ws + OFF_WHH2B),
                                      bih2, bhh2, w_fc, b_fc, out);
  lin_gemm<<<dim3(8, 4), 256, 0, stream>>>((const short*)(ws + OFF_P3BF),
                                           (const short*)(ws + OFF_WL1P),
                                           b_lin1, ws + OFF_T1);
  lin_fin<<<32, 256, 0, stream>>>(ws + OFF_T1, w_lin2, b_lin2, out + 11776);
}

// Round 6
// 370.692 us; speedup vs baseline: 11.1677x; 1.2114x over previous
//
#include <hip/hip_runtime.h>
#include <hip/hip_bf16.h>

typedef __attribute__((ext_vector_type(8))) short short8;
typedef __attribute__((ext_vector_type(4))) float floatx4;

// ---------------- workspace layout (float offsets) ----------------
#define OFF_B1P   0        // conv1 B frags [7][64][8] bf16
#define OFF_B2P   1792     // conv2 B frags [2][14][64][8] bf16
#define OFF_B3P   8960     // conv3 B frags [4][27][64][8] bf16
#define OFF_WIHT  36608    // w_init_h^T  (64,256)
#define OFF_WIH1T 52992    // wih1^T      (64,256)
#define OFF_WI2T  69376    // w_init_h2^T (256,256)
#define OFF_WHH1B 134912   // whh1 bf16 row-major [t][k]
#define OFF_WIH2B 167680   // wih2 bf16 row-major
#define OFF_WHH2B 200448   // whh2 bf16 row-major
#define OFF_WL1P  233216   // w_lin1 MFMA frags [nt16][c162][lane64][j8] bf16
#define OFF_ME    896768   // mean_enc (512,64)
#define OFF_H     929536   // h0  (512,256)
#define OFF_H2    1060608  // h2_0(512,256)
#define OFF_IHC   1191680  // ih_const (512,256)
#define OFF_P1    1322752  // p1 bf16 [512][1296][16]
#define OFF_P2    6631168  // p2 bf16 [512][324][32]
#define OFF_P3BF  9285376  // p3 bf16 [512][5184]
#define OFF_T1    1322752  // lin1 partials 4x(512,256) fp32 (over dead p1)

// conv2 slab strides (shorts): picked so A-read lanes spread 2-per-bank-window
#define S2_H 88            // 5*16 + 8 pad
#define S2_D 1760          // 20*88
// conv3 half-slab strides (shorts)
#define S3_H 88            // 5*16 + 8 pad
#define S3_D 1760          // 20*88
#define S3_HALF 14080      // 8*1760

static __device__ inline short f2bf(float f) {
  union { __hip_bfloat16 h; short s; } u;
  u.h = __float2bfloat16(f);
  return u.s;
}
static __device__ inline float bf2f(short s) {
  union { unsigned u; float f; } v;
  v.u = ((unsigned)(unsigned short)s) << 16;
  return v.f;
}
static __device__ inline float fast_tanh(float x) {
  x = fminf(fmaxf(x, -12.f), 12.f);
  float e = __expf(2.f * x);
  return (e - 1.f) * __builtin_amdgcn_rcpf(e + 1.f);
}

// ---------------- prep: weight frag packs + RNN/linear packs ----------------
__global__ __launch_bounds__(256) void prep_kernel(
    const float* __restrict__ w1, const float* __restrict__ w2, const float* __restrict__ w3,
    const float* __restrict__ w_init_h, const float* __restrict__ wih1,
    const float* __restrict__ w_init_h2, const float* __restrict__ whh1,
    const float* __restrict__ wih2, const float* __restrict__ whh2,
    const float* __restrict__ w_lin1, float* __restrict__ ws) {
  int i = blockIdx.x * 256 + threadIdx.x;
  if (i < 3584) {
    int j = i & 7, l = (i >> 3) & 63, c = i >> 9;
    int k = c*32 + ((l >> 4) << 3) + j;
    int tap = k >> 3, icp = k & 7, oc = l & 15;
    float v = (tap < 27 && icp < 6) ? w1[(oc*6 + icp)*27 + tap] : 0.f;
    ((__hip_bfloat16*)(ws + OFF_B1P))[i] = __float2bfloat16(v);
    return;
  }
  i -= 3584;
  if (i < 14336) {
    int j = i & 7, l = (i >> 3) & 63, cc = i >> 9;
    int c = cc % 14, nt = cc / 14;
    int k = c*32 + ((l >> 4) << 3) + j;
    int tap = k >> 4, ic = k & 15, oc = nt*16 + (l & 15);
    float v = (tap < 27) ? w2[(oc*16 + ic)*27 + tap] : 0.f;
    ((__hip_bfloat16*)(ws + OFF_B2P))[i] = __float2bfloat16(v);
    return;
  }
  i -= 14336;
  if (i < 55296) {
    int j = i & 7, l = (i >> 3) & 63, cc = i >> 9;
    int c = cc % 27, nt = cc / 27;
    int k = c*32 + ((l >> 4) << 3) + j;
    int ic = k & 31, oc = nt*16 + (l & 15);
    ((__hip_bfloat16*)(ws + OFF_B3P))[i] = __float2bfloat16(w3[(oc*32 + ic)*27 + c]);
    return;
  }
  i -= 55296;
  if (i < 16384) { int t = i & 255, k = i >> 8; ws[OFF_WIHT + i]  = w_init_h[t*64 + k];  return; }
  i -= 16384;
  if (i < 16384) { int t = i & 255, k = i >> 8; ws[OFF_WIH1T + i] = wih1[t*64 + k];      return; }
  i -= 16384;
  if (i < 65536) { int t = i & 255, k = i >> 8; ws[OFF_WI2T + i]  = w_init_h2[t*256 + k]; return; }
  i -= 65536;
  if (i < 65536) { ((__hip_bfloat16*)(ws + OFF_WHH1B))[i] = __float2bfloat16(whh1[i]); return; }
  i -= 65536;
  if (i < 65536) { ((__hip_bfloat16*)(ws + OFF_WIH2B))[i] = __float2bfloat16(wih2[i]); return; }
  i -= 65536;
  if (i < 65536) { ((__hip_bfloat16*)(ws + OFF_WHH2B))[i] = __float2bfloat16(whh2[i]); return; }
  i -= 65536;
  if (i < 1327104) {
    int j = i & 7, l = (i >> 3) & 63, cc = i >> 9;
    int c = cc % 162, nt = cc / 162;
    int k = c*32 + ((l >> 4) << 3) + j;
    int n = nt*16 + (l & 15);
    ((__hip_bfloat16*)(ws + OFF_WL1P))[i] = __float2bfloat16(w_lin1[n*5184 + k]);
    return;
  }
}

// ---------------- conv1 MFMA, halo slab: x (512,6,24,72,3) -> p1 bf16 [b][1296][16]
__global__ __launch_bounds__(256) void conv1_mfma(
    const float* __restrict__ x, const short* __restrict__ b1p,
    const float* __restrict__ bias, short* __restrict__ p1) {
  __shared__ __align__(16) short slab[8 * 74 * 5 * 8];
  int tid = threadIdx.x;
  int b = blockIdx.x >> 2, q = blockIdx.x & 3;
  for (int i = tid; i < 11840; i += 256) ((unsigned*)slab)[i] = 0u;
  __syncthreads();
  for (int i = tid; i < 2592; i += 256) {
    int dslot = i / 324;
    int r = i - dslot*324;
    int ic = r / 54;
    int f4 = r - ic*54;
    int d = 6*q - 1 + dslot;
    if ((unsigned)d < 24u) {
      float4 v = *(const float4*)(x + ((size_t)(b*6 + ic)*24 + d)*216 + f4*4);
      int pos = f4*4;
      int h0 = pos / 3, w0 = pos - h0*3;
      int hh = h0 + 1, ww = w0 + 1;
      float vv[4] = {v.x, v.y, v.z, v.w};
      #pragma unroll
      for (int e = 0; e < 4; ++e) {
        slab[((dslot*74 + hh)*5 + ww)*8 + ic] = f2bf(vv[e]);
        ++ww; if (ww == 4) { ww = 1; ++hh; }
      }
    }
  }
  int lane = tid & 63, wid = tid >> 6;
  int quad = lane >> 4, col = lane & 15;
  short8 bf[7];
  #pragma unroll
  for (int c = 0; c < 7; ++c) bf[c] = *(const short8*)(b1p + (c*64 + lane)*8);
  int tapoff[7];
  #pragma unroll
  for (int c = 0; c < 7; ++c) {
    int tap = c*4 + quad;
    int tt = tap < 27 ? tap : 26;
    int kd = tt/9, rr = tt - kd*9, kh = rr/3, kw = rr - kh*3;
    tapoff[c] = ((kd*74 + kh)*5 + kw)*8;
  }
  float bv = bias[col];
  __syncthreads();
  for (int tile = wid; tile < 81; tile += 4) {
    int m = tile*16 + col;
    int dd = m & 1, dh = (m >> 1) & 1;
    int P = m >> 2;
    int t2 = P/3; int w = P - t2*3;
    int pdl = t2/36; int ph = t2 - pdl*36;
    int base = (((2*pdl + dd)*74 + 2*ph + dh)*5 + w)*8;
    floatx4 acc = {0.f, 0.f, 0.f, 0.f};
    #pragma unroll
    for (int c = 0; c < 7; ++c) {
      short8 af = *(const short8*)(slab + base + tapoff[c]);
      acc = __builtin_amdgcn_mfma_f32_16x16x32_bf16(af, bf[c], acc, 0, 0, 0);
    }
    float v = fmaxf(fmaxf(acc[0], acc[1]), fmaxf(acc[2], acc[3]));
    v = fmaxf(v + bv, 0.f);
    int Pout = q*324 + tile*4 + quad;
    p1[((size_t)b*1296 + Pout)*16 + col] = f2bf(v);
  }
}

// ---------------- conv2 MFMA, halo slab: p1 -> p2 bf16 [b][324][32] ----------------
// 1024 blocks = 512 b x 2 h-halves. slab [d14][h20][w5 (+pad)][ic16].
__global__ __launch_bounds__(256) void conv2_mfma(
    const short* __restrict__ p1, const short* __restrict__ b2p,
    const float* __restrict__ bias2, short* __restrict__ p2g) {
  __shared__ __align__(16) short slab[14 * S2_D];   // 24640 sh = 49280 B
  int tid = threadIdx.x;
  int b = blockIdx.x >> 1, qh = blockIdx.x & 1;
  short8 z8 = {0,0,0,0,0,0,0,0};
  for (int i = tid; i < 3080; i += 256) *(short8*)(slab + i*8) = z8;
  __syncthreads();
  // stage rows: d in [0,12), hr in [0,20) -> hg = 18*qh - 1 + hr; 6 x short8 per row
  for (int i = tid; i < 1440; i += 256) {
    int c8 = i % 6; int r = i / 6; int hr = r % 20; int d = r / 20;
    int hg = 18*qh - 1 + hr;
    if ((unsigned)hg < 36u) {
      short8 v = *(const short8*)(p1 + ((size_t)b*1296 + (d*36 + hg)*3)*16 + c8*8);
      *(short8*)(slab + (d+1)*S2_D + hr*S2_H + 16 + c8*8) = v;
    }
  }
  int lane = tid & 63, wid = tid >> 6;
  int quad = lane >> 4, col = lane & 15;
  short8 bf[2][14];
  #pragma unroll
  for (int nt = 0; nt < 2; ++nt)
    #pragma unroll
    for (int c = 0; c < 14; ++c)
      bf[nt][c] = *(const short8*)(b2p + ((nt*14 + c)*64 + lane)*8);
  int tq = quad >> 1, icoff = (quad & 1) * 8;
  int tapoff[14];
  #pragma unroll
  for (int c = 0; c < 14; ++c) {
    int tap = 2*c + tq; if (tap > 26) tap = 26;   // tap 27 has zero B-frag
    int kd = tap/9, rr = tap - kd*9, kh = rr/3, kw = rr - kh*3;
    tapoff[c] = kd*S2_D + kh*S2_H + kw*16 + icoff;
  }
  float bv0 = bias2[col], bv1 = bias2[16 + col];
  __syncthreads();
  for (int tile = wid; tile < 41; tile += 4) {
    int m = tile*16 + col; if (m > 647) m = 647;
    int dd = m & 1, dh = (m >> 1) & 1;
    int P = m >> 2;
    int t = P/3; int w = P - t*3;
    int pd = t/9; int phl = t - pd*9;
    int base = (2*pd + dd)*S2_D + (2*phl + dh)*S2_H + w*16;
    floatx4 a0 = {0.f,0.f,0.f,0.f}, a1 = {0.f,0.f,0.f,0.f};
    #pragma unroll
    for (int c = 0; c < 14; ++c) {
      short8 a = *(const short8*)(slab + base + tapoff[c]);
      a0 = __builtin_amdgcn_mfma_f32_16x16x32_bf16(a, bf[0][c], a0, 0, 0, 0);
      a1 = __builtin_amdgcn_mfma_f32_16x16x32_bf16(a, bf[1][c], a1, 0, 0, 0);
    }
    int P2l = tile*4 + quad;
    if (P2l < 162) {
      float v0 = fmaxf(fmaxf(fmaxf(a0[0],a0[1]), fmaxf(a0[2],a0[3])) + bv0, 0.f);
      float v1 = fmaxf(fmaxf(fmaxf(a1[0],a1[1]), fmaxf(a1[2],a1[3])) + bv1, 0.f);
      int t2 = P2l/3; int w2 = P2l - t2*3;
      int pd2 = t2/9; int ph2 = t2 - pd2*9;
      size_t off = ((size_t)b*324 + (pd2*18 + 9*qh + ph2)*3 + w2)*32;
      p2g[off + col] = f2bf(v0);
      p2g[off + 16 + col] = f2bf(v1);
    }
  }
}

// ---------------- conv3 MFMA, dual ic-half halo slabs: p2 -> p3bf + mean ----------------
__global__ __launch_bounds__(256) void conv3_mfma(
    const short* __restrict__ p2g, const short* __restrict__ b3p,
    const float* __restrict__ bias3,
    short* __restrict__ p3bf, float* __restrict__ me) {
  __shared__ __align__(16) short slab[2 * S3_HALF];  // 56320 B
  __shared__ float smean[4][32];
  int tid = threadIdx.x;
  int b = blockIdx.x;
  short8 z8 = {0,0,0,0,0,0,0,0};
  for (int i = tid; i < 3520; i += 256) *(short8*)(slab + i*8) = z8;
  __syncthreads();
  // stage: 324 cells x (2 halves) x (2 short8)
  for (int i = tid; i < 1296; i += 256) {
    int c8 = i & 1;
    int hv = (i >> 1) & 1;
    int cell = i >> 2;
    int t = cell/3; int w = cell - t*3;
    int d = t/18; int h = t - d*18;
    short8 v = *(const short8*)(p2g + ((size_t)b*324 + cell)*32 + hv*16 + c8*8);
    *(short8*)(slab + hv*S3_HALF + (d+1)*S3_D + (h+1)*S3_H + (w+1)*16 + c8*8) = v;
  }
  int lane = tid & 63, wid = tid >> 6;
  int quad = lane >> 4, col = lane & 15;
  int ntp = (wid & 1) * 2;          // nt pair base: 0 or 2
  int tsel = wid >> 1;              // tile parity
  short8 bf[2][27];
  #pragma unroll
  for (int u = 0; u < 2; ++u)
    #pragma unroll
    for (int c = 0; c < 27; ++c)
      bf[u][c] = *(const short8*)(b3p + (((ntp+u)*27 + c)*64 + lane)*8);
  const short* sb = slab + (quad >> 1)*S3_HALF + (quad & 1)*8;
  float bva = bias3[ntp*16 + col], bvb = bias3[(ntp+1)*16 + col];
  float ms0 = 0.f, ms1 = 0.f;
  __syncthreads();
  for (int tile = tsel; tile < 21; tile += 2) {
    int m = tile*16 + col; if (m > 323) m = 323;
    int dd = m & 1, dh = (m >> 1) & 1;
    int P = m >> 2;
    int t = P/3; int w = P - t*3;
    int pd = t/9; int ph = t - pd*9;
    const short* ap = sb + (2*pd + dd)*S3_D + (2*ph + dh)*S3_H + w*16;
    floatx4 a0 = {0.f,0.f,0.f,0.f}, a1 = {0.f,0.f,0.f,0.f};
    #pragma unroll
    for (int c = 0; c < 27; ++c) {
      const int kd = c/9, rr = c - kd*9, kh = rr/3, kw = rr - kh*3;
      short8 a = *(const short8*)(ap + kd*S3_D + kh*S3_H + kw*16);
      a0 = __builtin_amdgcn_mfma_f32_16x16x32_bf16(a, bf[0][c], a0, 0, 0, 0);
      a1 = __builtin_amdgcn_mfma_f32_16x16x32_bf16(a, bf[1][c], a1, 0, 0, 0);
    }
    int Pout = tile*4 + quad;
    if (Pout < 81) {
      float v0 = fmaxf(fmaxf(fmaxf(a0[0],a0[1]), fmaxf(a0[2],a0[3])) + bva, 0.f);
      float v1 = fmaxf(fmaxf(fmaxf(a1[0],a1[1]), fmaxf(a1[2],a1[3])) + bvb, 0.f);
      size_t oi = ((size_t)b*81 + Pout)*64 + ntp*16 + col;
      p3bf[oi] = f2bf(v0);
      p3bf[oi + 16] = f2bf(v1);
      ms0 += v0; ms1 += v1;
    }
  }
  // reduce over quads (different Pout), then combine tile parities across waves
  ms0 += __shfl_xor(ms0, 16, 64); ms0 += __shfl_xor(ms0, 32, 64);
  ms1 += __shfl_xor(ms1, 16, 64); ms1 += __shfl_xor(ms1, 32, 64);
  if (lane < 16) { smean[wid][lane] = ms0; smean[wid][16 + lane] = ms1; }
  __syncthreads();
  if (tid < 64) {
    float s = (tid < 32) ? (smean[0][tid] + smean[2][tid])
                         : (smean[1][tid-32] + smean[3][tid-32]);
    me[b*64 + tid] = s * (1.f / 81.f);
  }
}

// ---------------- initial projections: 64 blocks x 8 rows ----------------
__global__ __launch_bounds__(256) void init_kernel(
    const float* __restrict__ me, const float* __restrict__ wiht,
    const float* __restrict__ b_init_h, const float* __restrict__ wih1t,
    const float* __restrict__ bih1, const float* __restrict__ bhh1,
    const float* __restrict__ wi2t, const float* __restrict__ b_init_h2,
    float* __restrict__ hout, float* __restrict__ h2out, float* __restrict__ ihcout) {
  __shared__ float sme[8][64];
  __shared__ float shl[8][256];
  int t = threadIdx.x; int bb = blockIdx.x * 8;
  for (int i = t; i < 512; i += 256) {
    int m = i >> 6, c = i & 63;
    sme[m][c] = me[(bb + m)*64 + c];
  }
  __syncthreads();
  float a[8], cc[8];
  float ba = b_init_h[t], bc = bih1[t] + bhh1[t];
  #pragma unroll
  for (int r = 0; r < 8; ++r) { a[r] = ba; cc[r] = bc; }
  #pragma unroll 2
  for (int k = 0; k < 64; ++k) {
    float w1v = wiht[k*256 + t], w2v = wih1t[k*256 + t];
    #pragma unroll
    for (int r = 0; r < 8; ++r) {
      float m = sme[r][k];
      a[r]  += m * w1v;
      cc[r] += m * w2v;
    }
  }
  #pragma unroll
  for (int r = 0; r < 8; ++r) {
    hout[(size_t)(bb + r)*256 + t] = a[r];
    ihcout[(size_t)(bb + r)*256 + t] = cc[r];
    shl[r][t] = a[r];
  }
  __syncthreads();
  float a2[8];
  float b2 = b_init_h2[t];
  #pragma unroll
  for (int r = 0; r < 8; ++r) a2[r] = b2;
  #pragma unroll 2
  for (int k = 0; k < 256; ++k) {
    float wv = wi2t[k*256 + t];
    #pragma unroll
    for (int r = 0; r < 8; ++r) a2[r] += shl[r][k] * wv;
  }
  #pragma unroll
  for (int r = 0; r < 8; ++r) h2out[(size_t)(bb + r)*256 + t] = a2[r];
}

// ---------------- RNN: register-resident MFMA, 32 blocks x 512 thr, M=16 rows
__global__ __launch_bounds__(512) void rnn2_kernel(
    const float* __restrict__ hin, const float* __restrict__ h2in,
    const float* __restrict__ ihc,
    const short* __restrict__ whh1b, const short* __restrict__ wih2b,
    const short* __restrict__ whh2b,
    const float* __restrict__ bih2, const float* __restrict__ bhh2,
    const float* __restrict__ w_fc, const float* __restrict__ b_fc,
    float* __restrict__ preds) {
  __shared__ __align__(16) short hbuf[2][16][264];
  __shared__ __align__(16) short h2buf[2][16][264];
  __shared__ __align__(16) short p2b[16][264];
  __shared__ float ihcL[16][260];
  __shared__ float predp[8][16];
  int tid = threadIdx.x;
  int bb = blockIdx.x * 16;
  int wid = tid >> 6, lane = tid & 63;
  int quad = lane >> 4, col = lane & 15;

  short8 wf[4][8];
  const short* wsel = (wid < 4) ? whh1b : whh2b;
  int nb = (wid & 3) * 64;
  #pragma unroll
  for (int t = 0; t < 4; ++t)
    #pragma unroll
    for (int c = 0; c < 8; ++c)
      wf[t][c] = *(const short8*)(wsel + (nb + t*16 + col)*256 + c*32 + quad*8);
  short8 w2f[2][8];
  int nb2 = wid * 32;
  #pragma unroll
  for (int t = 0; t < 2; ++t)
    #pragma unroll
    for (int c = 0; c < 8; ++c)
      w2f[t][c] = *(const short8*)(wih2b + (nb2 + t*16 + col)*256 + c*32 + quad*8);
  float b2v[2], wfcv[2];
  #pragma unroll
  for (int t = 0; t < 2; ++t) {
    int n = nb2 + t*16 + col;
    b2v[t] = bih2[n] + bhh2[n];
    wfcv[t] = w_fc[n];
  }
  float bfc = b_fc[0];

  for (int i = tid; i < 4096; i += 512) {
    int m = i >> 8, k = i & 255;
    hbuf[0][m][k]  = f2bf(hin[(bb + m)*256 + k]);
    h2buf[0][m][k] = f2bf(h2in[(bb + m)*256 + k]);
    ihcL[m][k]     = ihc[(bb + m)*256 + k];
  }
  __syncthreads();

  for (int step = 0; step < 23; ++step) {
    int cur = step & 1, nxt = cur ^ 1;
    floatx4 acc[4];
    if (wid < 4) {
      #pragma unroll
      for (int t = 0; t < 4; ++t)
        #pragma unroll
        for (int r = 0; r < 4; ++r)
          acc[t][r] = ihcL[quad*4 + r][nb + t*16 + col];
    } else {
      #pragma unroll
      for (int t = 0; t < 4; ++t) {
        floatx4 z = {0.f, 0.f, 0.f, 0.f};
        acc[t] = z;
      }
    }
    const short (*src)[264] = (wid < 4) ? hbuf[cur] : h2buf[cur];
    #pragma unroll
    for (int c = 0; c < 8; ++c) {
      short8 a = *(const short8*)&src[col][c*32 + quad*8];
      #pragma unroll
      for (int t = 0; t < 4; ++t)
        acc[t] = __builtin_amdgcn_mfma_f32_16x16x32_bf16(a, wf[t][c], acc[t], 0, 0, 0);
    }
    if (wid < 4) {
      #pragma unroll
      for (int t = 0; t < 4; ++t)
        #pragma unroll
        for (int r = 0; r < 4; ++r)
          hbuf[nxt][quad*4 + r][nb + t*16 + col] = f2bf(fast_tanh(acc[t][r]));
    } else {
      #pragma unroll
      for (int t = 0; t < 4; ++t)
        #pragma unroll
        for (int r = 0; r < 4; ++r)
          p2b[quad*4 + r][nb + t*16 + col] = f2bf(acc[t][r]);
    }
    __syncthreads();
    floatx4 q0 = {0.f,0.f,0.f,0.f}, q1 = {0.f,0.f,0.f,0.f};
    #pragma unroll
    for (int c = 0; c < 8; ++c) {
      short8 a = *(const short8*)&hbuf[nxt][col][c*32 + quad*8];
      q0 = __builtin_amdgcn_mfma_f32_16x16x32_bf16(a, w2f[0][c], q0, 0, 0, 0);
      q1 = __builtin_amdgcn_mfma_f32_16x16x32_bf16(a, w2f[1][c], q1, 0, 0, 0);
    }
    float pr[4];
    #pragma unroll
    for (int r = 0; r < 4; ++r) {
      float v0 = q0[r] + bf2f(p2b[quad*4 + r][nb2 + col]) + b2v[0];
      float v1 = q1[r] + bf2f(p2b[quad*4 + r][nb2 + 16 + col]) + b2v[1];
      float t0 = fast_tanh(v0), t1 = fast_tanh(v1);
      h2buf[nxt][quad*4 + r][nb2 + col] = f2bf(t0);
      h2buf[nxt][quad*4 + r][nb2 + 16 + col] = f2bf(t1);
      pr[r] = t0*wfcv[0] + t1*wfcv[1];
    }
    #pragma unroll
    for (int r = 0; r < 4; ++r) {
      #pragma unroll
      for (int off = 1; off < 16; off <<= 1)
        pr[r] += __shfl_xor(pr[r], off, 64);
    }
    if (col == 0) {
      #pragma unroll
      for (int r = 0; r < 4; ++r) predp[wid][quad*4 + r] = pr[r];
    }
    __syncthreads();
    if (tid < 16) {
      float s = bfc;
      #pragma unroll
      for (int w = 0; w < 8; ++w) s += predp[w][tid];
      preds[(size_t)(bb + tid)*23 + step] = s;
    }
  }
}

// ---------------- lin1 MFMA GEMM, split-K x4: (512x5184)x(5184x256) -> 4 partials
__global__ __launch_bounds__(256) void lin_gemm(
    const short* __restrict__ p3bf, const short* __restrict__ wl1p,
    const float* __restrict__ b_lin1, float* __restrict__ t1) {
  int tid = threadIdx.x;
  int lane = tid & 63, wid = tid >> 6;
  int quad = lane >> 4, col = lane & 15;
  int mt = blockIdx.x, ntb = blockIdx.y, kz = blockIdx.z;
  int c0 = kz*41; if (kz == 3) c0 = 122;
  int c1 = c0 + ((kz >= 2) ? 40 : 41);
  int m0 = mt*64 + wid*16;
  floatx4 acc[4];
  #pragma unroll
  for (int t = 0; t < 4; ++t) {
    float bv = (kz == 0) ? b_lin1[ntb*64 + t*16 + col] : 0.f;
    #pragma unroll
    for (int r = 0; r < 4; ++r) acc[t][r] = bv;
  }
  const short* arow = p3bf + (size_t)(m0 + col)*5184 + quad*8;
  const short* bbase = wl1p + ((size_t)(ntb*4)*162)*512 + lane*8;
  #pragma unroll 2
  for (int c = c0; c < c1; ++c) {
    short8 a = *(const short8*)(arow + c*32);
    #pragma unroll
    for (int t = 0; t < 4; ++t) {
      short8 b = *(const short8*)(bbase + (size_t)(t*162 + c)*512);
      acc[t] = __builtin_amdgcn_mfma_f32_16x16x32_bf16(a, b, acc[t], 0, 0, 0);
    }
  }
  float* to = t1 + (size_t)kz * 131072;
  #pragma unroll
  for (int t = 0; t < 4; ++t)
    #pragma unroll
    for (int r = 0; r < 4; ++r)
      to[(size_t)(m0 + quad*4 + r)*256 + ntb*64 + t*16 + col] = acc[t][r];
}

// ---------------- lin epilogue: sum partials + tanh + (256 -> 12) ----------------
__global__ __launch_bounds__(256) void lin_fin(
    const float* __restrict__ t1, const float* __restrict__ w_lin2,
    const float* __restrict__ b_lin2, float* __restrict__ outc) {
  __shared__ float st[16][257];
  int tid = threadIdx.x;
  int bb = blockIdx.x * 16;
  for (int i = tid; i < 4096; i += 256) {
    int m = i >> 8, k = i & 255;
    size_t i0 = (size_t)(bb + m)*256 + k;
    float s = t1[i0] + t1[i0 + 131072] + t1[i0 + 262144] + t1[i0 + 393216];
    st[m][k] = fast_tanh(s);
  }
  __syncthreads();
  if (tid < 192) {
    int r = tid / 12, j = tid % 12;
    float s = b_lin2[j];
    #pragma unroll 1
    for (int k = 0; k < 256; ++k) s += st[r][k] * w_lin2[j*256 + k];
    outc[(size_t)(bb + r)*12 + j] = s;
  }
}

// ---------------- launch ----------------
extern "C" void kernel_launch(void* const* d_in, const int* in_sizes, int n_in,
                              void* d_out, int out_size, void* d_ws, size_t ws_size,
                              hipStream_t stream) {
  const float* x         = (const float*)d_in[0];
  const float* w1        = (const float*)d_in[1];
  const float* b1        = (const float*)d_in[2];
  const float* w2        = (const float*)d_in[3];
  const float* b2        = (const float*)d_in[4];
  const float* w3        = (const float*)d_in[5];
  const float* b3        = (const float*)d_in[6];
  const float* wih1      = (const float*)d_in[7];
  const float* whh1      = (const float*)d_in[8];
  const float* bih1      = (const float*)d_in[9];
  const float* bhh1      = (const float*)d_in[10];
  const float* wih2      = (const float*)d_in[11];
  const float* whh2      = (const float*)d_in[12];
  const float* bih2      = (const float*)d_in[13];
  const float* bhh2      = (const float*)d_in[14];
  const float* w_init_h  = (const float*)d_in[15];
  const float* b_init_h  = (const float*)d_in[16];
  const float* w_init_h2 = (const float*)d_in[17];
  const float* b_init_h2 = (const float*)d_in[18];
  const float* w_fc      = (const float*)d_in[19];
  const float* b_fc      = (const float*)d_in[20];
  const float* w_lin1    = (const float*)d_in[21];
  const float* b_lin1    = (const float*)d_in[22];
  const float* w_lin2    = (const float*)d_in[23];
  const float* b_lin2    = (const float*)d_in[24];
  float* ws  = (float*)d_ws;
  float* out = (float*)d_out;

  prep_kernel<<<6622, 256, 0, stream>>>(w1, w2, w3, w_init_h, wih1, w_init_h2,
                                        whh1, wih2, whh2, w_lin1, ws);
  conv1_mfma<<<2048, 256, 0, stream>>>(x, (const short*)(ws + OFF_B1P), b1,
                                       (short*)(ws + OFF_P1));
  conv2_mfma<<<1024, 256, 0, stream>>>((const short*)(ws + OFF_P1),
                                       (const short*)(ws + OFF_B2P), b2,
                                       (short*)(ws + OFF_P2));
  conv3_mfma<<<512, 256, 0, stream>>>((const short*)(ws + OFF_P2),
                                      (const short*)(ws + OFF_B3P), b3,
                                      (short*)(ws + OFF_P3BF), ws + OFF_ME);
  init_kernel<<<64, 256, 0, stream>>>(ws + OFF_ME, ws + OFF_WIHT, b_init_h, ws + OFF_WIH1T,
                                      bih1, bhh1, ws + OFF_WI2T, b_init_h2,
                                      ws + OFF_H, ws + OFF_H2, ws + OFF_IHC);
  rnn2_kernel<<<32, 512, 0, stream>>>(ws + OFF_H, ws + OFF_H2, ws + OFF_IHC,
                                      (const short*)(ws + OFF_WHH1B),
                                      (const short*)(ws + OFF_WIH2B),
                                      (const short*)(ws + OFF_WHH2B),
                                      bih2, bhh2, w_fc, b_fc, out);
  lin_gemm<<<dim3(8, 4, 4), 256, 0, stream>>>((const short*)(ws + OFF_P3BF),
                                              (const short*)(ws + OFF_WL1P),
                                              b_lin1, ws + OFF_T1);
  lin_fin<<<32, 256, 0, stream>>>(ws + OFF_T1, w_lin2, b_lin2, out + 11776);
}

// Round 7
// 365.960 us; speedup vs baseline: 11.3121x; 1.0129x over previous
//
#include <hip/hip_runtime.h>
#include <hip/hip_bf16.h>

typedef __attribute__((ext_vector_type(8))) short short8;
typedef __attribute__((ext_vector_type(4))) float floatx4;

// ---------------- workspace layout (float offsets) ----------------
#define OFF_B1P   0        // conv1 B frags [7][64][8] bf16
#define OFF_B2P   1792     // conv2 B frags [2][14][64][8] bf16
#define OFF_B3P   8960     // conv3 B frags [4][27][64][8] bf16
#define OFF_WIHT  36608    // w_init_h^T  (64,256)
#define OFF_WIH1T 52992    // wih1^T      (64,256)
#define OFF_WI2T  69376    // w_init_h2^T (256,256)
#define OFF_WHH1B 134912   // whh1 bf16 row-major [t][k]
#define OFF_WIH2B 167680   // wih2 bf16 row-major
#define OFF_WHH2B 200448   // whh2 bf16 row-major
#define OFF_WL1P  233216   // w_lin1 MFMA frags [nt16][c162][lane64][j8] bf16
#define OFF_ME    896768   // mean_enc (512,64)
#define OFF_H     929536   // h0  (512,256)
#define OFF_H2    1060608  // h2_0(512,256)
#define OFF_IHC   1191680  // ih_const (512,256)
#define OFF_P1    1322752  // p1 bf16 [512][1296][16]
#define OFF_P2    6631168  // p2 bf16 [512][324][32]
#define OFF_P3BF  9285376  // p3 bf16 [512][5184]
#define OFF_T1    1322752  // lin1 partials 4x(512,256) fp32 (over dead p1)

#define S2_H 88
#define S2_D 1760
#define S3_H 88
#define S3_D 1760
#define S3_HALF 14080

static __device__ inline short f2bf(float f) {
  union { __hip_bfloat16 h; short s; } u;
  u.h = __float2bfloat16(f);
  return u.s;
}
// 5-instr tanh: 1 - 2/(e^{2x}+1); inf-safe both directions
static __device__ inline float fast_tanh(float x) {
  float e = __expf(2.f * x);
  return __builtin_fmaf(-2.f, __builtin_amdgcn_rcpf(e + 1.f), 1.f);
}

// ---------------- prep: weight frag packs + RNN packs (w_lin1 moved to conv1) ----
__global__ __launch_bounds__(256) void prep_kernel(
    const float* __restrict__ w1, const float* __restrict__ w2, const float* __restrict__ w3,
    const float* __restrict__ w_init_h, const float* __restrict__ wih1,
    const float* __restrict__ w_init_h2, const float* __restrict__ whh1,
    const float* __restrict__ wih2, const float* __restrict__ whh2,
    float* __restrict__ ws) {
  int i = blockIdx.x * 256 + threadIdx.x;
  if (i < 3584) {
    int j = i & 7, l = (i >> 3) & 63, c = i >> 9;
    int k = c*32 + ((l >> 4) << 3) + j;
    int tap = k >> 3, icp = k & 7, oc = l & 15;
    float v = (tap < 27 && icp < 6) ? w1[(oc*6 + icp)*27 + tap] : 0.f;
    ((__hip_bfloat16*)(ws + OFF_B1P))[i] = __float2bfloat16(v);
    return;
  }
  i -= 3584;
  if (i < 14336) {
    int j = i & 7, l = (i >> 3) & 63, cc = i >> 9;
    int c = cc % 14, nt = cc / 14;
    int k = c*32 + ((l >> 4) << 3) + j;
    int tap = k >> 4, ic = k & 15, oc = nt*16 + (l & 15);
    float v = (tap < 27) ? w2[(oc*16 + ic)*27 + tap] : 0.f;
    ((__hip_bfloat16*)(ws + OFF_B2P))[i] = __float2bfloat16(v);
    return;
  }
  i -= 14336;
  if (i < 55296) {
    int j = i & 7, l = (i >> 3) & 63, cc = i >> 9;
    int c = cc % 27, nt = cc / 27;
    int k = c*32 + ((l >> 4) << 3) + j;
    int ic = k & 31, oc = nt*16 + (l & 15);
    ((__hip_bfloat16*)(ws + OFF_B3P))[i] = __float2bfloat16(w3[(oc*32 + ic)*27 + c]);
    return;
  }
  i -= 55296;
  if (i < 16384) { int t = i & 255, k = i >> 8; ws[OFF_WIHT + i]  = w_init_h[t*64 + k];  return; }
  i -= 16384;
  if (i < 16384) { int t = i & 255, k = i >> 8; ws[OFF_WIH1T + i] = wih1[t*64 + k];      return; }
  i -= 16384;
  if (i < 65536) { int t = i & 255, k = i >> 8; ws[OFF_WI2T + i]  = w_init_h2[t*256 + k]; return; }
  i -= 65536;
  if (i < 65536) { ((__hip_bfloat16*)(ws + OFF_WHH1B))[i] = __float2bfloat16(whh1[i]); return; }
  i -= 65536;
  if (i < 65536) { ((__hip_bfloat16*)(ws + OFF_WIH2B))[i] = __float2bfloat16(wih2[i]); return; }
  i -= 65536;
  if (i < 65536) { ((__hip_bfloat16*)(ws + OFF_WHH2B))[i] = __float2bfloat16(whh2[i]); return; }
}

// ---------------- conv1 MFMA + w_lin1 pack tail blocks ----------------
__global__ __launch_bounds__(256) void conv1_mfma(
    const float* __restrict__ x, const short* __restrict__ b1p,
    const float* __restrict__ bias, short* __restrict__ p1,
    const float* __restrict__ w_lin1, short* __restrict__ wl1p) {
  __shared__ __align__(16) short slab[8 * 74 * 5 * 8];
  int tid = threadIdx.x;
  if (blockIdx.x >= 2048) {
    int i = (blockIdx.x - 2048)*256 + tid;        // < 1327104
    int j = i & 7, l = (i >> 3) & 63, cc = i >> 9;
    int c = cc % 162, nt = cc / 162;
    int k = c*32 + ((l >> 4) << 3) + j;
    int n = nt*16 + (l & 15);
    wl1p[i] = f2bf(w_lin1[n*5184 + k]);
    return;
  }
  int b = blockIdx.x >> 2, q = blockIdx.x & 3;
  for (int i = tid; i < 11840; i += 256) ((unsigned*)slab)[i] = 0u;
  __syncthreads();
  for (int i = tid; i < 2592; i += 256) {
    int dslot = i / 324;
    int r = i - dslot*324;
    int ic = r / 54;
    int f4 = r - ic*54;
    int d = 6*q - 1 + dslot;
    if ((unsigned)d < 24u) {
      float4 v = *(const float4*)(x + ((size_t)(b*6 + ic)*24 + d)*216 + f4*4);
      int pos = f4*4;
      int h0 = pos / 3, w0 = pos - h0*3;
      int hh = h0 + 1, ww = w0 + 1;
      float vv[4] = {v.x, v.y, v.z, v.w};
      #pragma unroll
      for (int e = 0; e < 4; ++e) {
        slab[((dslot*74 + hh)*5 + ww)*8 + ic] = f2bf(vv[e]);
        ++ww; if (ww == 4) { ww = 1; ++hh; }
      }
    }
  }
  int lane = tid & 63, wid = tid >> 6;
  int quad = lane >> 4, col = lane & 15;
  short8 bf[7];
  #pragma unroll
  for (int c = 0; c < 7; ++c) bf[c] = *(const short8*)(b1p + (c*64 + lane)*8);
  int tapoff[7];
  #pragma unroll
  for (int c = 0; c < 7; ++c) {
    int tap = c*4 + quad;
    int tt = tap < 27 ? tap : 26;
    int kd = tt/9, rr = tt - kd*9, kh = rr/3, kw = rr - kh*3;
    tapoff[c] = ((kd*74 + kh)*5 + kw)*8;
  }
  float bv = bias[col];
  __syncthreads();
  for (int tile = wid; tile < 81; tile += 4) {
    int m = tile*16 + col;
    int dd = m & 1, dh = (m >> 1) & 1;
    int P = m >> 2;
    int t2 = P/3; int w = P - t2*3;
    int pdl = t2/36; int ph = t2 - pdl*36;
    int base = (((2*pdl + dd)*74 + 2*ph + dh)*5 + w)*8;
    floatx4 acc = {0.f, 0.f, 0.f, 0.f};
    #pragma unroll
    for (int c = 0; c < 7; ++c) {
      short8 af = *(const short8*)(slab + base + tapoff[c]);
      acc = __builtin_amdgcn_mfma_f32_16x16x32_bf16(af, bf[c], acc, 0, 0, 0);
    }
    float v = fmaxf(fmaxf(acc[0], acc[1]), fmaxf(acc[2], acc[3]));
    v = fmaxf(v + bv, 0.f);
    int Pout = q*324 + tile*4 + quad;
    p1[((size_t)b*1296 + Pout)*16 + col] = f2bf(v);
  }
}

// ---------------- conv2 MFMA, halo slab: p1 -> p2 bf16 [b][324][32] ----------------
__global__ __launch_bounds__(256) void conv2_mfma(
    const short* __restrict__ p1, const short* __restrict__ b2p,
    const float* __restrict__ bias2, short* __restrict__ p2g) {
  __shared__ __align__(16) short slab[14 * S2_D];
  int tid = threadIdx.x;
  int b = blockIdx.x >> 1, qh = blockIdx.x & 1;
  short8 z8 = {0,0,0,0,0,0,0,0};
  for (int i = tid; i < 3080; i += 256) *(short8*)(slab + i*8) = z8;
  __syncthreads();
  for (int i = tid; i < 1440; i += 256) {
    int c8 = i % 6; int r = i / 6; int hr = r % 20; int d = r / 20;
    int hg = 18*qh - 1 + hr;
    if ((unsigned)hg < 36u) {
      short8 v = *(const short8*)(p1 + ((size_t)b*1296 + (d*36 + hg)*3)*16 + c8*8);
      *(short8*)(slab + (d+1)*S2_D + hr*S2_H + 16 + c8*8) = v;
    }
  }
  int lane = tid & 63, wid = tid >> 6;
  int quad = lane >> 4, col = lane & 15;
  short8 bf[2][14];
  #pragma unroll
  for (int nt = 0; nt < 2; ++nt)
    #pragma unroll
    for (int c = 0; c < 14; ++c)
      bf[nt][c] = *(const short8*)(b2p + ((nt*14 + c)*64 + lane)*8);
  int tq = quad >> 1, icoff = (quad & 1) * 8;
  int tapoff[14];
  #pragma unroll
  for (int c = 0; c < 14; ++c) {
    int tap = 2*c + tq; if (tap > 26) tap = 26;
    int kd = tap/9, rr = tap - kd*9, kh = rr/3, kw = rr - kh*3;
    tapoff[c] = kd*S2_D + kh*S2_H + kw*16 + icoff;
  }
  float bv0 = bias2[col], bv1 = bias2[16 + col];
  __syncthreads();
  for (int tile = wid; tile < 41; tile += 4) {
    int m = tile*16 + col; if (m > 647) m = 647;
    int dd = m & 1, dh = (m >> 1) & 1;
    int P = m >> 2;
    int t = P/3; int w = P - t*3;
    int pd = t/9; int phl = t - pd*9;
    int base = (2*pd + dd)*S2_D + (2*phl + dh)*S2_H + w*16;
    floatx4 a0 = {0.f,0.f,0.f,0.f}, a1 = {0.f,0.f,0.f,0.f};
    #pragma unroll
    for (int c = 0; c < 14; ++c) {
      short8 a = *(const short8*)(slab + base + tapoff[c]);
      a0 = __builtin_amdgcn_mfma_f32_16x16x32_bf16(a, bf[0][c], a0, 0, 0, 0);
      a1 = __builtin_amdgcn_mfma_f32_16x16x32_bf16(a, bf[1][c], a1, 0, 0, 0);
    }
    int P2l = tile*4 + quad;
    if (P2l < 162) {
      float v0 = fmaxf(fmaxf(fmaxf(a0[0],a0[1]), fmaxf(a0[2],a0[3])) + bv0, 0.f);
      float v1 = fmaxf(fmaxf(fmaxf(a1[0],a1[1]), fmaxf(a1[2],a1[3])) + bv1, 0.f);
      int t2 = P2l/3; int w2 = P2l - t2*3;
      int pd2 = t2/9; int ph2 = t2 - pd2*9;
      size_t off = ((size_t)b*324 + (pd2*18 + 9*qh + ph2)*3 + w2)*32;
      p2g[off + col] = f2bf(v0);
      p2g[off + 16 + col] = f2bf(v1);
    }
  }
}

// ---------------- conv3 MFMA, dual ic-half halo slabs: p2 -> p3bf + mean ----------------
__global__ __launch_bounds__(256) void conv3_mfma(
    const short* __restrict__ p2g, const short* __restrict__ b3p,
    const float* __restrict__ bias3,
    short* __restrict__ p3bf, float* __restrict__ me) {
  __shared__ __align__(16) short slab[2 * S3_HALF];
  __shared__ float smean[4][32];
  int tid = threadIdx.x;
  int b = blockIdx.x;
  short8 z8 = {0,0,0,0,0,0,0,0};
  for (int i = tid; i < 3520; i += 256) *(short8*)(slab + i*8) = z8;
  __syncthreads();
  for (int i = tid; i < 1296; i += 256) {
    int c8 = i & 1;
    int hv = (i >> 1) & 1;
    int cell = i >> 2;
    int t = cell/3; int w = cell - t*3;
    int d = t/18; int h = t - d*18;
    short8 v = *(const short8*)(p2g + ((size_t)b*324 + cell)*32 + hv*16 + c8*8);
    *(short8*)(slab + hv*S3_HALF + (d+1)*S3_D + (h+1)*S3_H + (w+1)*16 + c8*8) = v;
  }
  int lane = tid & 63, wid = tid >> 6;
  int quad = lane >> 4, col = lane & 15;
  int ntp = (wid & 1) * 2;
  int tsel = wid >> 1;
  short8 bf[2][27];
  #pragma unroll
  for (int u = 0; u < 2; ++u)
    #pragma unroll
    for (int c = 0; c < 27; ++c)
      bf[u][c] = *(const short8*)(b3p + (((ntp+u)*27 + c)*64 + lane)*8);
  const short* sb = slab + (quad >> 1)*S3_HALF + (quad & 1)*8;
  float bva = bias3[ntp*16 + col], bvb = bias3[(ntp+1)*16 + col];
  float ms0 = 0.f, ms1 = 0.f;
  __syncthreads();
  for (int tile = tsel; tile < 21; tile += 2) {
    int m = tile*16 + col; if (m > 323) m = 323;
    int dd = m & 1, dh = (m >> 1) & 1;
    int P = m >> 2;
    int t = P/3; int w = P - t*3;
    int pd = t/9; int ph = t - pd*9;
    const short* ap = sb + (2*pd + dd)*S3_D + (2*ph + dh)*S3_H + w*16;
    floatx4 a0 = {0.f,0.f,0.f,0.f}, a1 = {0.f,0.f,0.f,0.f};
    #pragma unroll
    for (int c = 0; c < 27; ++c) {
      const int kd = c/9, rr = c - kd*9, kh = rr/3, kw = rr - kh*3;
      short8 a = *(const short8*)(ap + kd*S3_D + kh*S3_H + kw*16);
      a0 = __builtin_amdgcn_mfma_f32_16x16x32_bf16(a, bf[0][c], a0, 0, 0, 0);
      a1 = __builtin_amdgcn_mfma_f32_16x16x32_bf16(a, bf[1][c], a1, 0, 0, 0);
    }
    int Pout = tile*4 + quad;
    if (Pout < 81) {
      float v0 = fmaxf(fmaxf(fmaxf(a0[0],a0[1]), fmaxf(a0[2],a0[3])) + bva, 0.f);
      float v1 = fmaxf(fmaxf(fmaxf(a1[0],a1[1]), fmaxf(a1[2],a1[3])) + bvb, 0.f);
      size_t oi = ((size_t)b*81 + Pout)*64 + ntp*16 + col;
      p3bf[oi] = f2bf(v0);
      p3bf[oi + 16] = f2bf(v1);
      ms0 += v0; ms1 += v1;
    }
  }
  ms0 += __shfl_xor(ms0, 16, 64); ms0 += __shfl_xor(ms0, 32, 64);
  ms1 += __shfl_xor(ms1, 16, 64); ms1 += __shfl_xor(ms1, 32, 64);
  if (lane < 16) { smean[wid][lane] = ms0; smean[wid][16 + lane] = ms1; }
  __syncthreads();
  if (tid < 64) {
    float s = (tid < 32) ? (smean[0][tid] + smean[2][tid])
                         : (smean[1][tid-32] + smean[3][tid-32]);
    me[b*64 + tid] = s * (1.f / 81.f);
  }
}

// ---------------- initial projections: 64 blocks x 8 rows ----------------
__global__ __launch_bounds__(256) void init_kernel(
    const float* __restrict__ me, const float* __restrict__ wiht,
    const float* __restrict__ b_init_h, const float* __restrict__ wih1t,
    const float* __restrict__ bih1, const float* __restrict__ bhh1,
    const float* __restrict__ wi2t, const float* __restrict__ b_init_h2,
    float* __restrict__ hout, float* __restrict__ h2out, float* __restrict__ ihcout) {
  __shared__ float sme[8][64];
  __shared__ float shl[8][256];
  int t = threadIdx.x; int bb = blockIdx.x * 8;
  for (int i = t; i < 512; i += 256) {
    int m = i >> 6, c = i & 63;
    sme[m][c] = me[(bb + m)*64 + c];
  }
  __syncthreads();
  float a[8], cc[8];
  float ba = b_init_h[t], bc = bih1[t] + bhh1[t];
  #pragma unroll
  for (int r = 0; r < 8; ++r) { a[r] = ba; cc[r] = bc; }
  #pragma unroll 2
  for (int k = 0; k < 64; ++k) {
    float w1v = wiht[k*256 + t], w2v = wih1t[k*256 + t];
    #pragma unroll
    for (int r = 0; r < 8; ++r) {
      float m = sme[r][k];
      a[r]  += m * w1v;
      cc[r] += m * w2v;
    }
  }
  #pragma unroll
  for (int r = 0; r < 8; ++r) {
    hout[(size_t)(bb + r)*256 + t] = a[r];
    ihcout[(size_t)(bb + r)*256 + t] = cc[r];
    shl[r][t] = a[r];
  }
  __syncthreads();
  float a2[8];
  float b2 = b_init_h2[t];
  #pragma unroll
  for (int r = 0; r < 8; ++r) a2[r] = b2;
  #pragma unroll 2
  for (int k = 0; k < 256; ++k) {
    float wv = wi2t[k*256 + t];
    #pragma unroll
    for (int r = 0; r < 8; ++r) a2[r] += shl[r][k] * wv;
  }
  #pragma unroll
  for (int r = 0; r < 8; ++r) h2out[(size_t)(bb + r)*256 + t] = a2[r];
}

// ---------------- fused tail: blocks 0-31 RNN (4 waves, all weights in regs),
//                  blocks 32-159 lin1 split-K GEMM (hidden under the RNN) ----------
__global__ __launch_bounds__(256, 1) void tail_kernel(
    const float* __restrict__ hin, const float* __restrict__ h2in,
    const float* __restrict__ ihc,
    const short* __restrict__ whh1b, const short* __restrict__ wih2b,
    const short* __restrict__ whh2b,
    const float* __restrict__ bih2, const float* __restrict__ bhh2,
    const float* __restrict__ w_fc, const float* __restrict__ b_fc,
    float* __restrict__ preds,
    const short* __restrict__ p3bf, const short* __restrict__ wl1p,
    const float* __restrict__ b_lin1, float* __restrict__ t1) {
  __shared__ __align__(16) short hbuf[2][16][264];
  __shared__ __align__(16) short h2buf[2][16][264];
  __shared__ float predsAll[23][4][16];
  int tid = threadIdx.x;
  int lane = tid & 63, wid = tid >> 6;
  int quad = lane >> 4, col = lane & 15;

  if (blockIdx.x >= 32) {
    // ---- lin arm: split-K x4 GEMM (512x5184)x(5184x256) ----
    int q = blockIdx.x - 32;
    int mt = q & 7, ntb = (q >> 3) & 3, kz = q >> 5;
    int c0 = kz*41; if (kz == 3) c0 = 122;
    int c1 = c0 + ((kz >= 2) ? 40 : 41);
    int m0 = mt*64 + wid*16;
    floatx4 acc[4];
    #pragma unroll
    for (int t = 0; t < 4; ++t) {
      float bv = (kz == 0) ? b_lin1[ntb*64 + t*16 + col] : 0.f;
      #pragma unroll
      for (int r = 0; r < 4; ++r) acc[t][r] = bv;
    }
    const short* arow = p3bf + (size_t)(m0 + col)*5184 + quad*8;
    const short* bbase = wl1p + ((size_t)(ntb*4)*162)*512 + lane*8;
    #pragma unroll 2
    for (int c = c0; c < c1; ++c) {
      short8 a = *(const short8*)(arow + c*32);
      #pragma unroll
      for (int t = 0; t < 4; ++t) {
        short8 b = *(const short8*)(bbase + (size_t)(t*162 + c)*512);
        acc[t] = __builtin_amdgcn_mfma_f32_16x16x32_bf16(a, b, acc[t], 0, 0, 0);
      }
    }
    float* to = t1 + (size_t)kz * 131072;
    #pragma unroll
    for (int t = 0; t < 4; ++t)
      #pragma unroll
      for (int r = 0; r < 4; ++r)
        to[(size_t)(m0 + quad*4 + r)*256 + ntb*64 + t*16 + col] = acc[t][r];
    return;
  }

  // ---- RNN arm ----
  int bb = blockIdx.x * 16;
  int nb = wid * 64;
  short8 w1f[4][8], w2af[4][8], w2bf[4][8];
  #pragma unroll
  for (int t = 0; t < 4; ++t)
    #pragma unroll
    for (int c = 0; c < 8; ++c) {
      int off = (nb + t*16 + col)*256 + c*32 + quad*8;
      w1f[t][c]  = *(const short8*)(whh1b + off);
      w2af[t][c] = *(const short8*)(wih2b + off);
      w2bf[t][c] = *(const short8*)(whh2b + off);
    }
  float b2v[4], wfcv[4];
  #pragma unroll
  for (int t = 0; t < 4; ++t) {
    int n = nb + t*16 + col;
    b2v[t] = bih2[n] + bhh2[n];
    wfcv[t] = w_fc[n];
  }
  float bfc = b_fc[0];
  float ihcr[4][4];
  #pragma unroll
  for (int t = 0; t < 4; ++t)
    #pragma unroll
    for (int r = 0; r < 4; ++r)
      ihcr[t][r] = ihc[(size_t)(bb + quad*4 + r)*256 + nb + t*16 + col];

  for (int i = tid; i < 4096; i += 256) {
    int m = i >> 8, k = i & 255;
    hbuf[0][m][k]  = f2bf(hin[(size_t)(bb + m)*256 + k]);
    h2buf[0][m][k] = f2bf(h2in[(size_t)(bb + m)*256 + k]);
  }
  __syncthreads();

  for (int s = 0; s < 23; ++s) {
    int cur = s & 1, nxt = cur ^ 1;
    // phase 1: h_new = tanh(ihc + h @ whh1), N=64 per wave
    floatx4 a1[4];
    #pragma unroll
    for (int t = 0; t < 4; ++t)
      #pragma unroll
      for (int r = 0; r < 4; ++r) a1[t][r] = ihcr[t][r];
    #pragma unroll
    for (int c = 0; c < 8; ++c) {
      short8 ah = *(const short8*)&hbuf[cur][col][c*32 + quad*8];
      #pragma unroll
      for (int t = 0; t < 4; ++t)
        a1[t] = __builtin_amdgcn_mfma_f32_16x16x32_bf16(ah, w1f[t][c], a1[t], 0, 0, 0);
    }
    #pragma unroll
    for (int t = 0; t < 4; ++t)
      #pragma unroll
      for (int r = 0; r < 4; ++r)
        hbuf[nxt][quad*4 + r][nb + t*16 + col] = f2bf(fast_tanh(a1[t][r]));
    __syncthreads();
    // phase 2: h2_new = tanh(h_new @ wih2 + h2 @ whh2 + b2); pred partial
    floatx4 a2[4], a3[4];
    #pragma unroll
    for (int t = 0; t < 4; ++t) {
      floatx4 z = {0.f,0.f,0.f,0.f};
      a2[t] = z; a3[t] = z;
    }
    #pragma unroll
    for (int c = 0; c < 8; ++c) {
      short8 ah = *(const short8*)&hbuf[nxt][col][c*32 + quad*8];
      short8 ag = *(const short8*)&h2buf[cur][col][c*32 + quad*8];
      #pragma unroll
      for (int t = 0; t < 4; ++t) {
        a2[t] = __builtin_amdgcn_mfma_f32_16x16x32_bf16(ah, w2af[t][c], a2[t], 0, 0, 0);
        a3[t] = __builtin_amdgcn_mfma_f32_16x16x32_bf16(ag, w2bf[t][c], a3[t], 0, 0, 0);
      }
    }
    float pr[4] = {0.f, 0.f, 0.f, 0.f};
    #pragma unroll
    for (int t = 0; t < 4; ++t)
      #pragma unroll
      for (int r = 0; r < 4; ++r) {
        float tv = fast_tanh(a2[t][r] + a3[t][r] + b2v[t]);
        h2buf[nxt][quad*4 + r][nb + t*16 + col] = f2bf(tv);
        pr[r] += tv * wfcv[t];
      }
    #pragma unroll
    for (int r = 0; r < 4; ++r) {
      pr[r] += __shfl_xor(pr[r], 1, 64);
      pr[r] += __shfl_xor(pr[r], 2, 64);
      pr[r] += __shfl_xor(pr[r], 4, 64);
      pr[r] += __shfl_xor(pr[r], 8, 64);
    }
    if (col == 0) {
      #pragma unroll
      for (int r = 0; r < 4; ++r) predsAll[s][wid][quad*4 + r] = pr[r];
    }
    __syncthreads();
  }
  if (tid < 16) {
    #pragma unroll 1
    for (int p = 0; p < 23; ++p) {
      float s = predsAll[p][0][tid] + predsAll[p][1][tid]
              + predsAll[p][2][tid] + predsAll[p][3][tid] + bfc;
      preds[(size_t)(bb + tid)*23 + p] = s;
    }
  }
}

// ---------------- lin epilogue: sum partials + tanh + (256 -> 12) ----------------
__global__ __launch_bounds__(256) void lin_fin(
    const float* __restrict__ t1, const float* __restrict__ w_lin2,
    const float* __restrict__ b_lin2, float* __restrict__ outc) {
  __shared__ float st[16][257];
  int tid = threadIdx.x;
  int bb = blockIdx.x * 16;
  for (int i = tid; i < 4096; i += 256) {
    int m = i >> 8, k = i & 255;
    size_t i0 = (size_t)(bb + m)*256 + k;
    float s = t1[i0] + t1[i0 + 131072] + t1[i0 + 262144] + t1[i0 + 393216];
    st[m][k] = fast_tanh(s);
  }
  __syncthreads();
  if (tid < 192) {
    int r = tid / 12, j = tid % 12;
    float s = b_lin2[j];
    #pragma unroll 1
    for (int k = 0; k < 256; ++k) s += st[r][k] * w_lin2[j*256 + k];
    outc[(size_t)(bb + r)*12 + j] = s;
  }
}

// ---------------- launch ----------------
extern "C" void kernel_launch(void* const* d_in, const int* in_sizes, int n_in,
                              void* d_out, int out_size, void* d_ws, size_t ws_size,
                              hipStream_t stream) {
  const float* x         = (const float*)d_in[0];
  const float* w1        = (const float*)d_in[1];
  const float* b1        = (const float*)d_in[2];
  const float* w2        = (const float*)d_in[3];
  const float* b2        = (const float*)d_in[4];
  const float* w3        = (const float*)d_in[5];
  const float* b3        = (const float*)d_in[6];
  const float* wih1      = (const float*)d_in[7];
  const float* whh1      = (const float*)d_in[8];
  const float* bih1      = (const float*)d_in[9];
  const float* bhh1      = (const float*)d_in[10];
  const float* wih2      = (const float*)d_in[11];
  const float* whh2      = (const float*)d_in[12];
  const float* bih2      = (const float*)d_in[13];
  const float* bhh2      = (const float*)d_in[14];
  const float* w_init_h  = (const float*)d_in[15];
  const float* b_init_h  = (const float*)d_in[16];
  const float* w_init_h2 = (const float*)d_in[17];
  const float* b_init_h2 = (const float*)d_in[18];
  const float* w_fc      = (const float*)d_in[19];
  const float* b_fc      = (const float*)d_in[20];
  const float* w_lin1    = (const float*)d_in[21];
  const float* b_lin1    = (const float*)d_in[22];
  const float* w_lin2    = (const float*)d_in[23];
  const float* b_lin2    = (const float*)d_in[24];
  float* ws  = (float*)d_ws;
  float* out = (float*)d_out;

  prep_kernel<<<1438, 256, 0, stream>>>(w1, w2, w3, w_init_h, wih1, w_init_h2,
                                        whh1, wih2, whh2, ws);
  conv1_mfma<<<7232, 256, 0, stream>>>(x, (const short*)(ws + OFF_B1P), b1,
                                       (short*)(ws + OFF_P1),
                                       w_lin1, (short*)(ws + OFF_WL1P));
  conv2_mfma<<<1024, 256, 0, stream>>>((const short*)(ws + OFF_P1),
                                       (const short*)(ws + OFF_B2P), b2,
                                       (short*)(ws + OFF_P2));
  conv3_mfma<<<512, 256, 0, stream>>>((const short*)(ws + OFF_P2),
                                      (const short*)(ws + OFF_B3P), b3,
                                      (short*)(ws + OFF_P3BF), ws + OFF_ME);
  init_kernel<<<64, 256, 0, stream>>>(ws + OFF_ME, ws + OFF_WIHT, b_init_h, ws + OFF_WIH1T,
                                      bih1, bhh1, ws + OFF_WI2T, b_init_h2,
                                      ws + OFF_H, ws + OFF_H2, ws + OFF_IHC);
  tail_kernel<<<160, 256, 0, stream>>>(ws + OFF_H, ws + OFF_H2, ws + OFF_IHC,
                                       (const short*)(ws + OFF_WHH1B),
                                       (const short*)(ws + OFF_WIH2B),
                                       (const short*)(ws + OFF_WHH2B),
                                       bih2, bhh2, w_fc, b_fc, out,
                                       (const short*)(ws + OFF_P3BF),
                                       (const short*)(ws + OFF_WL1P),
                                       b_lin1, ws + OFF_T1);
  lin_fin<<<32, 256, 0, stream>>>(ws + OFF_T1, w_lin2, b_lin2, out + 11776);
}

// Round 8
// 352.546 us; speedup vs baseline: 11.7425x; 1.0380x over previous
//
#include <hip/hip_runtime.h>
#include <hip/hip_bf16.h>

typedef __attribute__((ext_vector_type(8))) short short8;
typedef __attribute__((ext_vector_type(4))) short short4_t;
typedef __attribute__((ext_vector_type(4))) float floatx4;

// ---------------- workspace layout (float offsets) ----------------
#define OFF_B1P   0        // conv1 B frags [7][64][8] bf16
#define OFF_B2P   1792     // conv2 B frags [2][14][64][8] bf16
#define OFF_B3P   8960     // conv3 B frags [4][27][64][8] bf16
#define OFF_WIHT  36608    // w_init_h^T  (64,256)
#define OFF_WIH1T 52992    // wih1^T      (64,256)
#define OFF_WI2T  69376    // w_init_h2^T (256,256)
#define OFF_WHH1B 134912   // whh1 bf16 row-major [t][k]
#define OFF_WIH2B 167680   // wih2 bf16 row-major
#define OFF_WHH2B 200448   // whh2 bf16 row-major
#define OFF_WL1P  233216   // w_lin1 MFMA frags [nt16][c162][lane64][j8] bf16
#define OFF_ME    896768   // mean_enc (512,64)
#define OFF_H     929536   // h0  (512,256)
#define OFF_H2    1060608  // h2_0(512,256)
#define OFF_IHC   1191680  // ih_const (512,256)
#define OFF_P1    1322752  // p1 bf16 [512][1296][16]
#define OFF_P2    6631168  // p2 bf16 [512][324][32]
#define OFF_P3BF  9285376  // p3 bf16 [512][5184]
#define OFF_T1    1322752  // lin1 partials 4x(512,256) fp32 (over dead p1)

#define S2_H 88
#define S2_D 1760
#define S3_H 88
#define S3_D 1760
#define S3_HALF 14080

static __device__ inline short f2bf(float f) {
  union { __hip_bfloat16 h; short s; } u;
  u.h = __float2bfloat16(f);
  return u.s;
}
static __device__ inline float bf2f(short s) {
  union { unsigned u; float f; } v;
  v.u = ((unsigned)(unsigned short)s) << 16;
  return v.f;
}
// 5-instr tanh: 1 - 2/(e^{2x}+1); inf-safe both directions
static __device__ inline float fast_tanh(float x) {
  float e = __expf(2.f * x);
  return __builtin_fmaf(-2.f, __builtin_amdgcn_rcpf(e + 1.f), 1.f);
}

// ---------------- prep: weight frag packs + RNN packs ----------------
__global__ __launch_bounds__(256) void prep_kernel(
    const float* __restrict__ w1, const float* __restrict__ w2, const float* __restrict__ w3,
    const float* __restrict__ w_init_h, const float* __restrict__ wih1,
    const float* __restrict__ w_init_h2, const float* __restrict__ whh1,
    const float* __restrict__ wih2, const float* __restrict__ whh2,
    float* __restrict__ ws) {
  int i = blockIdx.x * 256 + threadIdx.x;
  if (i < 3584) {
    int j = i & 7, l = (i >> 3) & 63, c = i >> 9;
    int k = c*32 + ((l >> 4) << 3) + j;
    int tap = k >> 3, icp = k & 7, oc = l & 15;
    float v = (tap < 27 && icp < 6) ? w1[(oc*6 + icp)*27 + tap] : 0.f;
    ((__hip_bfloat16*)(ws + OFF_B1P))[i] = __float2bfloat16(v);
    return;
  }
  i -= 3584;
  if (i < 14336) {
    int j = i & 7, l = (i >> 3) & 63, cc = i >> 9;
    int c = cc % 14, nt = cc / 14;
    int k = c*32 + ((l >> 4) << 3) + j;
    int tap = k >> 4, ic = k & 15, oc = nt*16 + (l & 15);
    float v = (tap < 27) ? w2[(oc*16 + ic)*27 + tap] : 0.f;
    ((__hip_bfloat16*)(ws + OFF_B2P))[i] = __float2bfloat16(v);
    return;
  }
  i -= 14336;
  if (i < 55296) {
    int j = i & 7, l = (i >> 3) & 63, cc = i >> 9;
    int c = cc % 27, nt = cc / 27;
    int k = c*32 + ((l >> 4) << 3) + j;
    int ic = k & 31, oc = nt*16 + (l & 15);
    ((__hip_bfloat16*)(ws + OFF_B3P))[i] = __float2bfloat16(w3[(oc*32 + ic)*27 + c]);
    return;
  }
  i -= 55296;
  if (i < 16384) { int t = i & 255, k = i >> 8; ws[OFF_WIHT + i]  = w_init_h[t*64 + k];  return; }
  i -= 16384;
  if (i < 16384) { int t = i & 255, k = i >> 8; ws[OFF_WIH1T + i] = wih1[t*64 + k];      return; }
  i -= 16384;
  if (i < 65536) { int t = i & 255, k = i >> 8; ws[OFF_WI2T + i]  = w_init_h2[t*256 + k]; return; }
  i -= 65536;
  if (i < 65536) { ((__hip_bfloat16*)(ws + OFF_WHH1B))[i] = __float2bfloat16(whh1[i]); return; }
  i -= 65536;
  if (i < 65536) { ((__hip_bfloat16*)(ws + OFF_WIH2B))[i] = __float2bfloat16(wih2[i]); return; }
  i -= 65536;
  if (i < 65536) { ((__hip_bfloat16*)(ws + OFF_WHH2B))[i] = __float2bfloat16(whh2[i]); return; }
}

// ---------------- conv1 MFMA + w_lin1 pack tail blocks ----------------
__global__ __launch_bounds__(256) void conv1_mfma(
    const float* __restrict__ x, const short* __restrict__ b1p,
    const float* __restrict__ bias, short* __restrict__ p1,
    const float* __restrict__ w_lin1, short* __restrict__ wl1p) {
  __shared__ __align__(16) short slab[8 * 74 * 5 * 8];
  int tid = threadIdx.x;
  if (blockIdx.x >= 2048) {
    int i = (blockIdx.x - 2048)*256 + tid;
    int j = i & 7, l = (i >> 3) & 63, cc = i >> 9;
    int c = cc % 162, nt = cc / 162;
    int k = c*32 + ((l >> 4) << 3) + j;
    int n = nt*16 + (l & 15);
    wl1p[i] = f2bf(w_lin1[n*5184 + k]);
    return;
  }
  int b = blockIdx.x >> 2, q = blockIdx.x & 3;
  for (int i = tid; i < 11840; i += 256) ((unsigned*)slab)[i] = 0u;
  __syncthreads();
  for (int i = tid; i < 2592; i += 256) {
    int dslot = i / 324;
    int r = i - dslot*324;
    int ic = r / 54;
    int f4 = r - ic*54;
    int d = 6*q - 1 + dslot;
    if ((unsigned)d < 24u) {
      float4 v = *(const float4*)(x + ((size_t)(b*6 + ic)*24 + d)*216 + f4*4);
      int pos = f4*4;
      int h0 = pos / 3, w0 = pos - h0*3;
      int hh = h0 + 1, ww = w0 + 1;
      float vv[4] = {v.x, v.y, v.z, v.w};
      #pragma unroll
      for (int e = 0; e < 4; ++e) {
        slab[((dslot*74 + hh)*5 + ww)*8 + ic] = f2bf(vv[e]);
        ++ww; if (ww == 4) { ww = 1; ++hh; }
      }
    }
  }
  int lane = tid & 63, wid = tid >> 6;
  int quad = lane >> 4, col = lane & 15;
  short8 bf[7];
  #pragma unroll
  for (int c = 0; c < 7; ++c) bf[c] = *(const short8*)(b1p + (c*64 + lane)*8);
  int tapoff[7];
  #pragma unroll
  for (int c = 0; c < 7; ++c) {
    int tap = c*4 + quad;
    int tt = tap < 27 ? tap : 26;
    int kd = tt/9, rr = tt - kd*9, kh = rr/3, kw = rr - kh*3;
    tapoff[c] = ((kd*74 + kh)*5 + kw)*8;
  }
  float bv = bias[col];
  __syncthreads();
  for (int tile = wid; tile < 81; tile += 4) {
    int m = tile*16 + col;
    int dd = m & 1, dh = (m >> 1) & 1;
    int P = m >> 2;
    int t2 = P/3; int w = P - t2*3;
    int pdl = t2/36; int ph = t2 - pdl*36;
    int base = (((2*pdl + dd)*74 + 2*ph + dh)*5 + w)*8;
    floatx4 acc = {0.f, 0.f, 0.f, 0.f};
    #pragma unroll
    for (int c = 0; c < 7; ++c) {
      short8 af = *(const short8*)(slab + base + tapoff[c]);
      acc = __builtin_amdgcn_mfma_f32_16x16x32_bf16(af, bf[c], acc, 0, 0, 0);
    }
    float v = fmaxf(fmaxf(acc[0], acc[1]), fmaxf(acc[2], acc[3]));
    v = fmaxf(v + bv, 0.f);
    int Pout = q*324 + tile*4 + quad;
    p1[((size_t)b*1296 + Pout)*16 + col] = f2bf(v);
  }
}

// ---------------- conv2 MFMA, halo slab: p1 -> p2 bf16 [b][324][32] ----------------
__global__ __launch_bounds__(256) void conv2_mfma(
    const short* __restrict__ p1, const short* __restrict__ b2p,
    const float* __restrict__ bias2, short* __restrict__ p2g) {
  __shared__ __align__(16) short slab[14 * S2_D];
  int tid = threadIdx.x;
  int b = blockIdx.x >> 1, qh = blockIdx.x & 1;
  short8 z8 = {0,0,0,0,0,0,0,0};
  for (int i = tid; i < 3080; i += 256) *(short8*)(slab + i*8) = z8;
  __syncthreads();
  for (int i = tid; i < 1440; i += 256) {
    int c8 = i % 6; int r = i / 6; int hr = r % 20; int d = r / 20;
    int hg = 18*qh - 1 + hr;
    if ((unsigned)hg < 36u) {
      short8 v = *(const short8*)(p1 + ((size_t)b*1296 + (d*36 + hg)*3)*16 + c8*8);
      *(short8*)(slab + (d+1)*S2_D + hr*S2_H + 16 + c8*8) = v;
    }
  }
  int lane = tid & 63, wid = tid >> 6;
  int quad = lane >> 4, col = lane & 15;
  short8 bf[2][14];
  #pragma unroll
  for (int nt = 0; nt < 2; ++nt)
    #pragma unroll
    for (int c = 0; c < 14; ++c)
      bf[nt][c] = *(const short8*)(b2p + ((nt*14 + c)*64 + lane)*8);
  int tq = quad >> 1, icoff = (quad & 1) * 8;
  int tapoff[14];
  #pragma unroll
  for (int c = 0; c < 14; ++c) {
    int tap = 2*c + tq; if (tap > 26) tap = 26;
    int kd = tap/9, rr = tap - kd*9, kh = rr/3, kw = rr - kh*3;
    tapoff[c] = kd*S2_D + kh*S2_H + kw*16 + icoff;
  }
  float bv0 = bias2[col], bv1 = bias2[16 + col];
  __syncthreads();
  for (int tile = wid; tile < 41; tile += 4) {
    int m = tile*16 + col; if (m > 647) m = 647;
    int dd = m & 1, dh = (m >> 1) & 1;
    int P = m >> 2;
    int t = P/3; int w = P - t*3;
    int pd = t/9; int phl = t - pd*9;
    int base = (2*pd + dd)*S2_D + (2*phl + dh)*S2_H + w*16;
    floatx4 a0 = {0.f,0.f,0.f,0.f}, a1 = {0.f,0.f,0.f,0.f};
    #pragma unroll
    for (int c = 0; c < 14; ++c) {
      short8 a = *(const short8*)(slab + base + tapoff[c]);
      a0 = __builtin_amdgcn_mfma_f32_16x16x32_bf16(a, bf[0][c], a0, 0, 0, 0);
      a1 = __builtin_amdgcn_mfma_f32_16x16x32_bf16(a, bf[1][c], a1, 0, 0, 0);
    }
    int P2l = tile*4 + quad;
    if (P2l < 162) {
      float v0 = fmaxf(fmaxf(fmaxf(a0[0],a0[1]), fmaxf(a0[2],a0[3])) + bv0, 0.f);
      float v1 = fmaxf(fmaxf(fmaxf(a1[0],a1[1]), fmaxf(a1[2],a1[3])) + bv1, 0.f);
      int t2 = P2l/3; int w2 = P2l - t2*3;
      int pd2 = t2/9; int ph2 = t2 - pd2*9;
      size_t off = ((size_t)b*324 + (pd2*18 + 9*qh + ph2)*3 + w2)*32;
      p2g[off + col] = f2bf(v0);
      p2g[off + 16 + col] = f2bf(v1);
    }
  }
}

// ---------------- conv3 MFMA, dual ic-half halo slabs: p2 -> p3bf + mean ----------------
__global__ __launch_bounds__(256) void conv3_mfma(
    const short* __restrict__ p2g, const short* __restrict__ b3p,
    const float* __restrict__ bias3,
    short* __restrict__ p3bf, float* __restrict__ me) {
  __shared__ __align__(16) short slab[2 * S3_HALF];
  __shared__ float smean[4][32];
  int tid = threadIdx.x;
  int b = blockIdx.x;
  short8 z8 = {0,0,0,0,0,0,0,0};
  for (int i = tid; i < 3520; i += 256) *(short8*)(slab + i*8) = z8;
  __syncthreads();
  for (int i = tid; i < 1296; i += 256) {
    int c8 = i & 1;
    int hv = (i >> 1) & 1;
    int cell = i >> 2;
    int t = cell/3; int w = cell - t*3;
    int d = t/18; int h = t - d*18;
    short8 v = *(const short8*)(p2g + ((size_t)b*324 + cell)*32 + hv*16 + c8*8);
    *(short8*)(slab + hv*S3_HALF + (d+1)*S3_D + (h+1)*S3_H + (w+1)*16 + c8*8) = v;
  }
  int lane = tid & 63, wid = tid >> 6;
  int quad = lane >> 4, col = lane & 15;
  int ntp = (wid & 1) * 2;
  int tsel = wid >> 1;
  short8 bf[2][27];
  #pragma unroll
  for (int u = 0; u < 2; ++u)
    #pragma unroll
    for (int c = 0; c < 27; ++c)
      bf[u][c] = *(const short8*)(b3p + (((ntp+u)*27 + c)*64 + lane)*8);
  const short* sb = slab + (quad >> 1)*S3_HALF + (quad & 1)*8;
  float bva = bias3[ntp*16 + col], bvb = bias3[(ntp+1)*16 + col];
  float ms0 = 0.f, ms1 = 0.f;
  __syncthreads();
  for (int tile = tsel; tile < 21; tile += 2) {
    int m = tile*16 + col; if (m > 323) m = 323;
    int dd = m & 1, dh = (m >> 1) & 1;
    int P = m >> 2;
    int t = P/3; int w = P - t*3;
    int pd = t/9; int ph = t - pd*9;
    const short* ap = sb + (2*pd + dd)*S3_D + (2*ph + dh)*S3_H + w*16;
    floatx4 a0 = {0.f,0.f,0.f,0.f}, a1 = {0.f,0.f,0.f,0.f};
    #pragma unroll
    for (int c = 0; c < 27; ++c) {
      const int kd = c/9, rr = c - kd*9, kh = rr/3, kw = rr - kh*3;
      short8 a = *(const short8*)(ap + kd*S3_D + kh*S3_H + kw*16);
      a0 = __builtin_amdgcn_mfma_f32_16x16x32_bf16(a, bf[0][c], a0, 0, 0, 0);
      a1 = __builtin_amdgcn_mfma_f32_16x16x32_bf16(a, bf[1][c], a1, 0, 0, 0);
    }
    int Pout = tile*4 + quad;
    if (Pout < 81) {
      float v0 = fmaxf(fmaxf(fmaxf(a0[0],a0[1]), fmaxf(a0[2],a0[3])) + bva, 0.f);
      float v1 = fmaxf(fmaxf(fmaxf(a1[0],a1[1]), fmaxf(a1[2],a1[3])) + bvb, 0.f);
      size_t oi = ((size_t)b*81 + Pout)*64 + ntp*16 + col;
      p3bf[oi] = f2bf(v0);
      p3bf[oi + 16] = f2bf(v1);
      ms0 += v0; ms1 += v1;
    }
  }
  ms0 += __shfl_xor(ms0, 16, 64); ms0 += __shfl_xor(ms0, 32, 64);
  ms1 += __shfl_xor(ms1, 16, 64); ms1 += __shfl_xor(ms1, 32, 64);
  if (lane < 16) { smean[wid][lane] = ms0; smean[wid][16 + lane] = ms1; }
  __syncthreads();
  if (tid < 64) {
    float s = (tid < 32) ? (smean[0][tid] + smean[2][tid])
                         : (smean[1][tid-32] + smean[3][tid-32]);
    me[b*64 + tid] = s * (1.f / 81.f);
  }
}

// ---------------- initial projections: 64 blocks x 8 rows ----------------
__global__ __launch_bounds__(256) void init_kernel(
    const float* __restrict__ me, const float* __restrict__ wiht,
    const float* __restrict__ b_init_h, const float* __restrict__ wih1t,
    const float* __restrict__ bih1, const float* __restrict__ bhh1,
    const float* __restrict__ wi2t, const float* __restrict__ b_init_h2,
    float* __restrict__ hout, float* __restrict__ h2out, float* __restrict__ ihcout) {
  __shared__ float sme[8][64];
  __shared__ float shl[8][256];
  int t = threadIdx.x; int bb = blockIdx.x * 8;
  for (int i = t; i < 512; i += 256) {
    int m = i >> 6, c = i & 63;
    sme[m][c] = me[(bb + m)*64 + c];
  }
  __syncthreads();
  float a[8], cc[8];
  float ba = b_init_h[t], bc = bih1[t] + bhh1[t];
  #pragma unroll
  for (int r = 0; r < 8; ++r) { a[r] = ba; cc[r] = bc; }
  #pragma unroll 2
  for (int k = 0; k < 64; ++k) {
    float w1v = wiht[k*256 + t], w2v = wih1t[k*256 + t];
    #pragma unroll
    for (int r = 0; r < 8; ++r) {
      float m = sme[r][k];
      a[r]  += m * w1v;
      cc[r] += m * w2v;
    }
  }
  #pragma unroll
  for (int r = 0; r < 8; ++r) {
    hout[(size_t)(bb + r)*256 + t] = a[r];
    ihcout[(size_t)(bb + r)*256 + t] = cc[r];
    shl[r][t] = a[r];
  }
  __syncthreads();
  float a2[8];
  float b2 = b_init_h2[t];
  #pragma unroll
  for (int r = 0; r < 8; ++r) a2[r] = b2;
  #pragma unroll 2
  for (int k = 0; k < 256; ++k) {
    float wv = wi2t[k*256 + t];
    #pragma unroll
    for (int r = 0; r < 8; ++r) a2[r] += shl[r][k] * wv;
  }
  #pragma unroll
  for (int r = 0; r < 8; ++r) h2out[(size_t)(bb + r)*256 + t] = a2[r];
}

// ---------------- fused tail: blocks 0-31 RNN (transposed GEMM, 8 waves),
//                  blocks 32-95 lin1 split-K GEMM (2 sub-tiles of 4 waves) ----------
// RNN trick: compute D = W @ h^T (weights as A-operand). Then a lane's 4 accs per
// tile are 4 consecutive n at fixed m=col -> one ds_write_b64; state stays [m][k]
// so B-frag reads remain ds_read_b128. Kills all scalar LDS traffic of rnn2.
__global__ __launch_bounds__(512, 1) void tail_kernel(
    const float* __restrict__ hin, const float* __restrict__ h2in,
    const float* __restrict__ ihc,
    const short* __restrict__ whh1b, const short* __restrict__ wih2b,
    const short* __restrict__ whh2b,
    const float* __restrict__ bih2, const float* __restrict__ bhh2,
    const float* __restrict__ w_fc, const float* __restrict__ b_fc,
    float* __restrict__ preds,
    const short* __restrict__ p3bf, const short* __restrict__ wl1p,
    const float* __restrict__ b_lin1, float* __restrict__ t1) {
  __shared__ __align__(16) short hbuf[2][16][264];   // [m][k] bf16
  __shared__ __align__(16) short h2buf[2][16][264];
  __shared__ __align__(16) short p2b[16][264];       // whh2@h2^T partial, [m][n] bf16
  __shared__ float predsAll[23][8][16];
  int tid = threadIdx.x;

  if (blockIdx.x >= 32) {
    // ---- lin arm: split-K x4 GEMM (512x5184)x(5184x256); 2 sub-tiles/block ----
    int sub = tid >> 8, stid = tid & 255;
    int lane = stid & 63, w4 = stid >> 6;
    int quad = lane >> 4, col = lane & 15;
    int idx = (blockIdx.x - 32)*2 + sub;   // [0,128)
    int mt = idx & 7, ntb = (idx >> 3) & 3, kz = idx >> 5;
    int c0 = kz*41; if (kz == 3) c0 = 122;
    int c1 = c0 + ((kz >= 2) ? 40 : 41);
    int m0 = mt*64 + w4*16;
    floatx4 acc[4];
    #pragma unroll
    for (int t = 0; t < 4; ++t) {
      float bv = (kz == 0) ? b_lin1[ntb*64 + t*16 + col] : 0.f;
      #pragma unroll
      for (int r = 0; r < 4; ++r) acc[t][r] = bv;
    }
    const short* arow = p3bf + (size_t)(m0 + col)*5184 + quad*8;
    const short* bbase = wl1p + ((size_t)(ntb*4)*162)*512 + lane*8;
    #pragma unroll 2
    for (int c = c0; c < c1; ++c) {
      short8 a = *(const short8*)(arow + c*32);
      #pragma unroll
      for (int t = 0; t < 4; ++t) {
        short8 b = *(const short8*)(bbase + (size_t)(t*162 + c)*512);
        acc[t] = __builtin_amdgcn_mfma_f32_16x16x32_bf16(a, b, acc[t], 0, 0, 0);
      }
    }
    float* to = t1 + (size_t)kz * 131072;
    #pragma unroll
    for (int t = 0; t < 4; ++t)
      #pragma unroll
      for (int r = 0; r < 4; ++r)
        to[(size_t)(m0 + quad*4 + r)*256 + ntb*64 + t*16 + col] = acc[t][r];
    return;
  }

  // ---- RNN arm: 8 waves; waves 0-3 whh1 slices, 4-7 whh2 slices; all wih2 ----
  int lane = tid & 63, wid = tid >> 6;
  int quad = lane >> 4, col = lane & 15;
  int bb = blockIdx.x * 16;
  int nb = (wid & 3) * 64;            // N=64 slice for phase-1 matrices
  int nb2 = wid * 32;                 // N=32 slice for wih2
  // A-operand weight frags: A[n within tile = col][k = quad*8+j] == row-major load
  short8 wf[4][8];                    // whh1 (waves 0-3) or whh2 (waves 4-7)
  const short* wsel = (wid < 4) ? whh1b : whh2b;
  #pragma unroll
  for (int t = 0; t < 4; ++t)
    #pragma unroll
    for (int c = 0; c < 8; ++c)
      wf[t][c] = *(const short8*)(wsel + (nb + t*16 + col)*256 + c*32 + quad*8);
  short8 w2f[2][8];                   // wih2 slice
  #pragma unroll
  for (int t = 0; t < 2; ++t)
    #pragma unroll
    for (int c = 0; c < 8; ++c)
      w2f[t][c] = *(const short8*)(wih2b + (nb2 + t*16 + col)*256 + c*32 + quad*8);
  // per-lane n-vectors (4 consecutive n): bias2, w_fc, ihc (waves 0-3)
  float4 b2v[2], wfcv[2];
  #pragma unroll
  for (int t = 0; t < 2; ++t) {
    int n = nb2 + t*16 + quad*4;
    float4 bi = *(const float4*)(bih2 + n);
    float4 bh = *(const float4*)(bhh2 + n);
    b2v[t].x = bi.x + bh.x; b2v[t].y = bi.y + bh.y;
    b2v[t].z = bi.z + bh.z; b2v[t].w = bi.w + bh.w;
    wfcv[t] = *(const float4*)(w_fc + n);
  }
  float bfc = b_fc[0];
  float4 ihcr[4];
  if (wid < 4) {
    #pragma unroll
    for (int t = 0; t < 4; ++t)
      ihcr[t] = *(const float4*)(ihc + (size_t)(bb + col)*256 + nb + t*16 + quad*4);
  }

  for (int i = tid; i < 4096; i += 512) {
    int m = i >> 8, k = i & 255;
    hbuf[0][m][k]  = f2bf(hin[(size_t)(bb + m)*256 + k]);
    h2buf[0][m][k] = f2bf(h2in[(size_t)(bb + m)*256 + k]);
  }
  __syncthreads();

  for (int s = 0; s < 23; ++s) {
    int cur = s & 1, nxt = cur ^ 1;
    // phase 1: waves 0-3: a = ihc + whh1 @ h^T; waves 4-7: p = whh2 @ h2^T
    floatx4 a1[4];
    if (wid < 4) {
      #pragma unroll
      for (int t = 0; t < 4; ++t) {
        a1[t][0] = ihcr[t].x; a1[t][1] = ihcr[t].y;
        a1[t][2] = ihcr[t].z; a1[t][3] = ihcr[t].w;
      }
    } else {
      #pragma unroll
      for (int t = 0; t < 4; ++t) {
        floatx4 z = {0.f,0.f,0.f,0.f};
        a1[t] = z;
      }
    }
    const short (*src)[264] = (wid < 4) ? hbuf[cur] : h2buf[cur];
    #pragma unroll
    for (int c = 0; c < 8; ++c) {
      short8 bfrag = *(const short8*)&src[col][c*32 + quad*8];
      #pragma unroll
      for (int t = 0; t < 4; ++t)
        a1[t] = __builtin_amdgcn_mfma_f32_16x16x32_bf16(wf[t][c], bfrag, a1[t], 0, 0, 0);
    }
    if (wid < 4) {
      #pragma unroll
      for (int t = 0; t < 4; ++t) {
        short4_t pk;
        #pragma unroll
        for (int r = 0; r < 4; ++r) pk[r] = f2bf(fast_tanh(a1[t][r]));
        *(short4_t*)&hbuf[nxt][col][nb + t*16 + quad*4] = pk;
      }
    } else {
      #pragma unroll
      for (int t = 0; t < 4; ++t) {
        short4_t pk;
        #pragma unroll
        for (int r = 0; r < 4; ++r) pk[r] = f2bf(a1[t][r]);
        *(short4_t*)&p2b[col][nb + t*16 + quad*4] = pk;
      }
    }
    __syncthreads();
    // phase 2: all waves: q = wih2 @ h_new^T (N=32 slice); combine + tanh + pred
    floatx4 q0 = {0.f,0.f,0.f,0.f}, q1 = {0.f,0.f,0.f,0.f};
    #pragma unroll
    for (int c = 0; c < 8; ++c) {
      short8 bfrag = *(const short8*)&hbuf[nxt][col][c*32 + quad*8];
      q0 = __builtin_amdgcn_mfma_f32_16x16x32_bf16(w2f[0][c], bfrag, q0, 0, 0, 0);
      q1 = __builtin_amdgcn_mfma_f32_16x16x32_bf16(w2f[1][c], bfrag, q1, 0, 0, 0);
    }
    float pr = 0.f;
    {
      short4_t pv0 = *(const short4_t*)&p2b[col][nb2 + quad*4];
      short4_t pv1 = *(const short4_t*)&p2b[col][nb2 + 16 + quad*4];
      short4_t o0, o1;
      const float* b2a = (const float*)&b2v[0];
      const float* b2b = (const float*)&b2v[1];
      const float* wfa = (const float*)&wfcv[0];
      const float* wfb = (const float*)&wfcv[1];
      #pragma unroll
      for (int r = 0; r < 4; ++r) {
        float t0 = fast_tanh(q0[r] + bf2f(pv0[r]) + b2a[r]);
        float t1 = fast_tanh(q1[r] + bf2f(pv1[r]) + b2b[r]);
        o0[r] = f2bf(t0); o1[r] = f2bf(t1);
        pr += t0*wfa[r] + t1*wfb[r];
      }
      *(short4_t*)&h2buf[nxt][col][nb2 + quad*4] = o0;
      *(short4_t*)&h2buf[nxt][col][nb2 + 16 + quad*4] = o1;
    }
    pr += __shfl_xor(pr, 16, 64);
    pr += __shfl_xor(pr, 32, 64);
    if (lane < 16) predsAll[s][wid][col] = pr;
    __syncthreads();
  }
  if (tid < 16) {
    #pragma unroll 1
    for (int p = 0; p < 23; ++p) {
      float sv = bfc;
      #pragma unroll
      for (int w = 0; w < 8; ++w) sv += predsAll[p][w][tid];
      preds[(size_t)(bb + tid)*23 + p] = sv;
    }
  }
}

// ---------------- lin epilogue: sum partials + tanh + (256 -> 12) ----------------
__global__ __launch_bounds__(256) void lin_fin(
    const float* __restrict__ t1, const float* __restrict__ w_lin2,
    const float* __restrict__ b_lin2, float* __restrict__ outc) {
  __shared__ float st[16][257];
  int tid = threadIdx.x;
  int bb = blockIdx.x * 16;
  for (int i = tid; i < 4096; i += 256) {
    int m = i >> 8, k = i & 255;
    size_t i0 = (size_t)(bb + m)*256 + k;
    float s = t1[i0] + t1[i0 + 131072] + t1[i0 + 262144] + t1[i0 + 393216];
    st[m][k] = fast_tanh(s);
  }
  __syncthreads();
  if (tid < 192) {
    int r = tid / 12, j = tid % 12;
    float s = b_lin2[j];
    #pragma unroll 1
    for (int k = 0; k < 256; ++k) s += st[r][k] * w_lin2[j*256 + k];
    outc[(size_t)(bb + r)*12 + j] = s;
  }
}

// ---------------- launch ----------------
extern "C" void kernel_launch(void* const* d_in, const int* in_sizes, int n_in,
                              void* d_out, int out_size, void* d_ws, size_t ws_size,
                              hipStream_t stream) {
  const float* x         = (const float*)d_in[0];
  const float* w1        = (const float*)d_in[1];
  const float* b1        = (const float*)d_in[2];
  const float* w2        = (const float*)d_in[3];
  const float* b2        = (const float*)d_in[4];
  const float* w3        = (const float*)d_in[5];
  const float* b3        = (const float*)d_in[6];
  const float* wih1      = (const float*)d_in[7];
  const float* whh1      = (const float*)d_in[8];
  const float* bih1      = (const float*)d_in[9];
  const float* bhh1      = (const float*)d_in[10];
  const float* wih2      = (const float*)d_in[11];
  const float* whh2      = (const float*)d_in[12];
  const float* bih2      = (const float*)d_in[13];
  const float* bhh2      = (const float*)d_in[14];
  const float* w_init_h  = (const float*)d_in[15];
  const float* b_init_h  = (const float*)d_in[16];
  const float* w_init_h2 = (const float*)d_in[17];
  const float* b_init_h2 = (const float*)d_in[18];
  const float* w_fc      = (const float*)d_in[19];
  const float* b_fc      = (const float*)d_in[20];
  const float* w_lin1    = (const float*)d_in[21];
  const float* b_lin1    = (const float*)d_in[22];
  const float* w_lin2    = (const float*)d_in[23];
  const float* b_lin2    = (const float*)d_in[24];
  float* ws  = (float*)d_ws;
  float* out = (float*)d_out;

  prep_kernel<<<1438, 256, 0, stream>>>(w1, w2, w3, w_init_h, wih1, w_init_h2,
                                        whh1, wih2, whh2, ws);
  conv1_mfma<<<7232, 256, 0, stream>>>(x, (const short*)(ws + OFF_B1P), b1,
                                       (short*)(ws + OFF_P1),
                                       w_lin1, (short*)(ws + OFF_WL1P));
  conv2_mfma<<<1024, 256, 0, stream>>>((const short*)(ws + OFF_P1),
                                       (const short*)(ws + OFF_B2P), b2,
                                       (short*)(ws + OFF_P2));
  conv3_mfma<<<512, 256, 0, stream>>>((const short*)(ws + OFF_P2),
                                      (const short*)(ws + OFF_B3P), b3,
                                      (short*)(ws + OFF_P3BF), ws + OFF_ME);
  init_kernel<<<64, 256, 0, stream>>>(ws + OFF_ME, ws + OFF_WIHT, b_init_h, ws + OFF_WIH1T,
                                      bih1, bhh1, ws + OFF_WI2T, b_init_h2,
                                      ws + OFF_H, ws + OFF_H2, ws + OFF_IHC);
  tail_kernel<<<96, 512, 0, stream>>>(ws + OFF_H, ws + OFF_H2, ws + OFF_IHC,
                                      (const short*)(ws + OFF_WHH1B),
                                      (const short*)(ws + OFF_WIH2B),
                                      (const short*)(ws + OFF_WHH2B),
                                      bih2, bhh2, w_fc, b_fc, out,
                                      (const short*)(ws + OFF_P3BF),
                                      (const short*)(ws + OFF_WL1P),
                                      b_lin1, ws + OFF_T1);
  lin_fin<<<32, 256, 0, stream>>>(ws + OFF_T1, w_lin2, b_lin2, out + 11776);
}

// Round 9
// 342.831 us; speedup vs baseline: 12.0753x; 1.0283x over previous
//
#include <hip/hip_runtime.h>
#include <hip/hip_bf16.h>

typedef __attribute__((ext_vector_type(8))) short short8;
typedef __attribute__((ext_vector_type(4))) short short4_t;
typedef __attribute__((ext_vector_type(4))) float floatx4;

// ---------------- workspace layout (float offsets) ----------------
#define OFF_B1P   0        // conv1 B frags [7][64][8] bf16
#define OFF_B2P   1792     // conv2 B frags [2][14][64][8] bf16
#define OFF_B3P   8960     // conv3 B frags [4][27][64][8] bf16
#define OFF_WIHT  36608    // w_init_h^T  (64,256)
#define OFF_WIH1T 52992    // wih1^T      (64,256)
#define OFF_WI2T  69376    // w_init_h2^T (256,256)
#define OFF_WHH1B 134912   // whh1 bf16 row-major [t][k]
#define OFF_WIH2B 167680   // wih2 bf16 row-major
#define OFF_WHH2B 200448   // whh2 bf16 row-major
#define OFF_WL1P  233216   // w_lin1 MFMA frags [nt16][c162][lane64][j8] bf16
#define OFF_ME    896768   // mean_enc (512,64)
#define OFF_H     929536   // h0  (512,256)
#define OFF_H2    1060608  // h2_0(512,256)
#define OFF_IHC   1191680  // ih_const (512,256)
#define OFF_P1    1322752  // p1 bf16 [512][1296][16]
#define OFF_P2    6631168  // p2 bf16 [512][324][32]
#define OFF_P3BF  9285376  // p3 bf16 [512][5184]
#define OFF_T1    1322752  // lin1 partials 4x(512,256) fp32 (over dead p1)

#define S2_H 88
#define S2_D 1760
#define S3_H 88
#define S3_D 1760
#define S3_HALF 14080

static __device__ inline short f2bf(float f) {
  union { __hip_bfloat16 h; short s; } u;
  u.h = __float2bfloat16(f);
  return u.s;
}
static __device__ inline float bf2f(short s) {
  union { unsigned u; float f; } v;
  v.u = ((unsigned)(unsigned short)s) << 16;
  return v.f;
}
// 5-instr tanh: 1 - 2/(e^{2x}+1); inf-safe both directions
static __device__ inline float fast_tanh(float x) {
  float e = __expf(2.f * x);
  return __builtin_fmaf(-2.f, __builtin_amdgcn_rcpf(e + 1.f), 1.f);
}

// ---------------- prep: weight frag packs + RNN packs ----------------
__global__ __launch_bounds__(256) void prep_kernel(
    const float* __restrict__ w1, const float* __restrict__ w2, const float* __restrict__ w3,
    const float* __restrict__ w_init_h, const float* __restrict__ wih1,
    const float* __restrict__ w_init_h2, const float* __restrict__ whh1,
    const float* __restrict__ wih2, const float* __restrict__ whh2,
    float* __restrict__ ws) {
  int i = blockIdx.x * 256 + threadIdx.x;
  if (i < 3584) {
    int j = i & 7, l = (i >> 3) & 63, c = i >> 9;
    int k = c*32 + ((l >> 4) << 3) + j;
    int tap = k >> 3, icp = k & 7, oc = l & 15;
    float v = (tap < 27 && icp < 6) ? w1[(oc*6 + icp)*27 + tap] : 0.f;
    ((__hip_bfloat16*)(ws + OFF_B1P))[i] = __float2bfloat16(v);
    return;
  }
  i -= 3584;
  if (i < 14336) {
    int j = i & 7, l = (i >> 3) & 63, cc = i >> 9;
    int c = cc % 14, nt = cc / 14;
    int k = c*32 + ((l >> 4) << 3) + j;
    int tap = k >> 4, ic = k & 15, oc = nt*16 + (l & 15);
    float v = (tap < 27) ? w2[(oc*16 + ic)*27 + tap] : 0.f;
    ((__hip_bfloat16*)(ws + OFF_B2P))[i] = __float2bfloat16(v);
    return;
  }
  i -= 14336;
  if (i < 55296) {
    int j = i & 7, l = (i >> 3) & 63, cc = i >> 9;
    int c = cc % 27, nt = cc / 27;
    int k = c*32 + ((l >> 4) << 3) + j;
    int ic = k & 31, oc = nt*16 + (l & 15);
    ((__hip_bfloat16*)(ws + OFF_B3P))[i] = __float2bfloat16(w3[(oc*32 + ic)*27 + c]);
    return;
  }
  i -= 55296;
  if (i < 16384) { int t = i & 255, k = i >> 8; ws[OFF_WIHT + i]  = w_init_h[t*64 + k];  return; }
  i -= 16384;
  if (i < 16384) { int t = i & 255, k = i >> 8; ws[OFF_WIH1T + i] = wih1[t*64 + k];      return; }
  i -= 16384;
  if (i < 65536) { int t = i & 255, k = i >> 8; ws[OFF_WI2T + i]  = w_init_h2[t*256 + k]; return; }
  i -= 65536;
  if (i < 65536) { ((__hip_bfloat16*)(ws + OFF_WHH1B))[i] = __float2bfloat16(whh1[i]); return; }
  i -= 65536;
  if (i < 65536) { ((__hip_bfloat16*)(ws + OFF_WIH2B))[i] = __float2bfloat16(wih2[i]); return; }
  i -= 65536;
  if (i < 65536) { ((__hip_bfloat16*)(ws + OFF_WHH2B))[i] = __float2bfloat16(whh2[i]); return; }
}

// ---------------- conv1 MFMA + w_lin1 pack tail blocks ----------------
__global__ __launch_bounds__(256) void conv1_mfma(
    const float* __restrict__ x, const short* __restrict__ b1p,
    const float* __restrict__ bias, short* __restrict__ p1,
    const float* __restrict__ w_lin1, short* __restrict__ wl1p) {
  __shared__ __align__(16) short slab[8 * 74 * 5 * 8];
  int tid = threadIdx.x;
  if (blockIdx.x >= 2048) {
    int i = (blockIdx.x - 2048)*256 + tid;
    int j = i & 7, l = (i >> 3) & 63, cc = i >> 9;
    int c = cc % 162, nt = cc / 162;
    int k = c*32 + ((l >> 4) << 3) + j;
    int n = nt*16 + (l & 15);
    wl1p[i] = f2bf(w_lin1[n*5184 + k]);
    return;
  }
  int b = blockIdx.x >> 2, q = blockIdx.x & 3;
  for (int i = tid; i < 11840; i += 256) ((unsigned*)slab)[i] = 0u;
  __syncthreads();
  for (int i = tid; i < 2592; i += 256) {
    int dslot = i / 324;
    int r = i - dslot*324;
    int ic = r / 54;
    int f4 = r - ic*54;
    int d = 6*q - 1 + dslot;
    if ((unsigned)d < 24u) {
      float4 v = *(const float4*)(x + ((size_t)(b*6 + ic)*24 + d)*216 + f4*4);
      int pos = f4*4;
      int h0 = pos / 3, w0 = pos - h0*3;
      int hh = h0 + 1, ww = w0 + 1;
      float vv[4] = {v.x, v.y, v.z, v.w};
      #pragma unroll
      for (int e = 0; e < 4; ++e) {
        slab[((dslot*74 + hh)*5 + ww)*8 + ic] = f2bf(vv[e]);
        ++ww; if (ww == 4) { ww = 1; ++hh; }
      }
    }
  }
  int lane = tid & 63, wid = tid >> 6;
  int quad = lane >> 4, col = lane & 15;
  short8 bf[7];
  #pragma unroll
  for (int c = 0; c < 7; ++c) bf[c] = *(const short8*)(b1p + (c*64 + lane)*8);
  int tapoff[7];
  #pragma unroll
  for (int c = 0; c < 7; ++c) {
    int tap = c*4 + quad;
    int tt = tap < 27 ? tap : 26;
    int kd = tt/9, rr = tt - kd*9, kh = rr/3, kw = rr - kh*3;
    tapoff[c] = ((kd*74 + kh)*5 + kw)*8;
  }
  float bv = bias[col];
  __syncthreads();
  for (int tile = wid; tile < 81; tile += 4) {
    int m = tile*16 + col;
    int dd = m & 1, dh = (m >> 1) & 1;
    int P = m >> 2;
    int t2 = P/3; int w = P - t2*3;
    int pdl = t2/36; int ph = t2 - pdl*36;
    int base = (((2*pdl + dd)*74 + 2*ph + dh)*5 + w)*8;
    floatx4 acc = {0.f, 0.f, 0.f, 0.f};
    #pragma unroll
    for (int c = 0; c < 7; ++c) {
      short8 af = *(const short8*)(slab + base + tapoff[c]);
      acc = __builtin_amdgcn_mfma_f32_16x16x32_bf16(af, bf[c], acc, 0, 0, 0);
    }
    float v = fmaxf(fmaxf(acc[0], acc[1]), fmaxf(acc[2], acc[3]));
    v = fmaxf(v + bv, 0.f);
    int Pout = q*324 + tile*4 + quad;
    p1[((size_t)b*1296 + Pout)*16 + col] = f2bf(v);
  }
}

// ---------------- conv2 MFMA, halo slab: p1 -> p2 bf16 [b][324][32] ----------------
__global__ __launch_bounds__(256) void conv2_mfma(
    const short* __restrict__ p1, const short* __restrict__ b2p,
    const float* __restrict__ bias2, short* __restrict__ p2g) {
  __shared__ __align__(16) short slab[14 * S2_D];
  int tid = threadIdx.x;
  int b = blockIdx.x >> 1, qh = blockIdx.x & 1;
  short8 z8 = {0,0,0,0,0,0,0,0};
  for (int i = tid; i < 3080; i += 256) *(short8*)(slab + i*8) = z8;
  __syncthreads();
  for (int i = tid; i < 1440; i += 256) {
    int c8 = i % 6; int r = i / 6; int hr = r % 20; int d = r / 20;
    int hg = 18*qh - 1 + hr;
    if ((unsigned)hg < 36u) {
      short8 v = *(const short8*)(p1 + ((size_t)b*1296 + (d*36 + hg)*3)*16 + c8*8);
      *(short8*)(slab + (d+1)*S2_D + hr*S2_H + 16 + c8*8) = v;
    }
  }
  int lane = tid & 63, wid = tid >> 6;
  int quad = lane >> 4, col = lane & 15;
  short8 bf[2][14];
  #pragma unroll
  for (int nt = 0; nt < 2; ++nt)
    #pragma unroll
    for (int c = 0; c < 14; ++c)
      bf[nt][c] = *(const short8*)(b2p + ((nt*14 + c)*64 + lane)*8);
  int tq = quad >> 1, icoff = (quad & 1) * 8;
  int tapoff[14];
  #pragma unroll
  for (int c = 0; c < 14; ++c) {
    int tap = 2*c + tq; if (tap > 26) tap = 26;
    int kd = tap/9, rr = tap - kd*9, kh = rr/3, kw = rr - kh*3;
    tapoff[c] = kd*S2_D + kh*S2_H + kw*16 + icoff;
  }
  float bv0 = bias2[col], bv1 = bias2[16 + col];
  __syncthreads();
  for (int tile = wid; tile < 41; tile += 4) {
    int m = tile*16 + col; if (m > 647) m = 647;
    int dd = m & 1, dh = (m >> 1) & 1;
    int P = m >> 2;
    int t = P/3; int w = P - t*3;
    int pd = t/9; int phl = t - pd*9;
    int base = (2*pd + dd)*S2_D + (2*phl + dh)*S2_H + w*16;
    floatx4 a0 = {0.f,0.f,0.f,0.f}, a1 = {0.f,0.f,0.f,0.f};
    #pragma unroll
    for (int c = 0; c < 14; ++c) {
      short8 a = *(const short8*)(slab + base + tapoff[c]);
      a0 = __builtin_amdgcn_mfma_f32_16x16x32_bf16(a, bf[0][c], a0, 0, 0, 0);
      a1 = __builtin_amdgcn_mfma_f32_16x16x32_bf16(a, bf[1][c], a1, 0, 0, 0);
    }
    int P2l = tile*4 + quad;
    if (P2l < 162) {
      float v0 = fmaxf(fmaxf(fmaxf(a0[0],a0[1]), fmaxf(a0[2],a0[3])) + bv0, 0.f);
      float v1 = fmaxf(fmaxf(fmaxf(a1[0],a1[1]), fmaxf(a1[2],a1[3])) + bv1, 0.f);
      int t2 = P2l/3; int w2 = P2l - t2*3;
      int pd2 = t2/9; int ph2 = t2 - pd2*9;
      size_t off = ((size_t)b*324 + (pd2*18 + 9*qh + ph2)*3 + w2)*32;
      p2g[off + col] = f2bf(v0);
      p2g[off + 16 + col] = f2bf(v1);
    }
  }
}

// ---------------- conv3 MFMA, dual ic-half halo slabs: p2 -> p3bf + mean ----------------
__global__ __launch_bounds__(256) void conv3_mfma(
    const short* __restrict__ p2g, const short* __restrict__ b3p,
    const float* __restrict__ bias3,
    short* __restrict__ p3bf, float* __restrict__ me) {
  __shared__ __align__(16) short slab[2 * S3_HALF];
  __shared__ float smean[4][32];
  int tid = threadIdx.x;
  int b = blockIdx.x;
  short8 z8 = {0,0,0,0,0,0,0,0};
  for (int i = tid; i < 3520; i += 256) *(short8*)(slab + i*8) = z8;
  __syncthreads();
  for (int i = tid; i < 1296; i += 256) {
    int c8 = i & 1;
    int hv = (i >> 1) & 1;
    int cell = i >> 2;
    int t = cell/3; int w = cell - t*3;
    int d = t/18; int h = t - d*18;
    short8 v = *(const short8*)(p2g + ((size_t)b*324 + cell)*32 + hv*16 + c8*8);
    *(short8*)(slab + hv*S3_HALF + (d+1)*S3_D + (h+1)*S3_H + (w+1)*16 + c8*8) = v;
  }
  int lane = tid & 63, wid = tid >> 6;
  int quad = lane >> 4, col = lane & 15;
  int ntp = (wid & 1) * 2;
  int tsel = wid >> 1;
  short8 bf[2][27];
  #pragma unroll
  for (int u = 0; u < 2; ++u)
    #pragma unroll
    for (int c = 0; c < 27; ++c)
      bf[u][c] = *(const short8*)(b3p + (((ntp+u)*27 + c)*64 + lane)*8);
  const short* sb = slab + (quad >> 1)*S3_HALF + (quad & 1)*8;
  float bva = bias3[ntp*16 + col], bvb = bias3[(ntp+1)*16 + col];
  float ms0 = 0.f, ms1 = 0.f;
  __syncthreads();
  for (int tile = tsel; tile < 21; tile += 2) {
    int m = tile*16 + col; if (m > 323) m = 323;
    int dd = m & 1, dh = (m >> 1) & 1;
    int P = m >> 2;
    int t = P/3; int w = P - t*3;
    int pd = t/9; int ph = t - pd*9;
    const short* ap = sb + (2*pd + dd)*S3_D + (2*ph + dh)*S3_H + w*16;
    floatx4 a0 = {0.f,0.f,0.f,0.f}, a1 = {0.f,0.f,0.f,0.f};
    #pragma unroll
    for (int c = 0; c < 27; ++c) {
      const int kd = c/9, rr = c - kd*9, kh = rr/3, kw = rr - kh*3;
      short8 a = *(const short8*)(ap + kd*S3_D + kh*S3_H + kw*16);
      a0 = __builtin_amdgcn_mfma_f32_16x16x32_bf16(a, bf[0][c], a0, 0, 0, 0);
      a1 = __builtin_amdgcn_mfma_f32_16x16x32_bf16(a, bf[1][c], a1, 0, 0, 0);
    }
    int Pout = tile*4 + quad;
    if (Pout < 81) {
      float v0 = fmaxf(fmaxf(fmaxf(a0[0],a0[1]), fmaxf(a0[2],a0[3])) + bva, 0.f);
      float v1 = fmaxf(fmaxf(fmaxf(a1[0],a1[1]), fmaxf(a1[2],a1[3])) + bvb, 0.f);
      size_t oi = ((size_t)b*81 + Pout)*64 + ntp*16 + col;
      p3bf[oi] = f2bf(v0);
      p3bf[oi + 16] = f2bf(v1);
      ms0 += v0; ms1 += v1;
    }
  }
  ms0 += __shfl_xor(ms0, 16, 64); ms0 += __shfl_xor(ms0, 32, 64);
  ms1 += __shfl_xor(ms1, 16, 64); ms1 += __shfl_xor(ms1, 32, 64);
  if (lane < 16) { smean[wid][lane] = ms0; smean[wid][16 + lane] = ms1; }
  __syncthreads();
  if (tid < 64) {
    float s = (tid < 32) ? (smean[0][tid] + smean[2][tid])
                         : (smean[1][tid-32] + smean[3][tid-32]);
    me[b*64 + tid] = s * (1.f / 81.f);
  }
}

// ---------------- initial projections: 64 blocks x 8 rows ----------------
__global__ __launch_bounds__(256) void init_kernel(
    const float* __restrict__ me, const float* __restrict__ wiht,
    const float* __restrict__ b_init_h, const float* __restrict__ wih1t,
    const float* __restrict__ bih1, const float* __restrict__ bhh1,
    const float* __restrict__ wi2t, const float* __restrict__ b_init_h2,
    float* __restrict__ hout, float* __restrict__ h2out, float* __restrict__ ihcout) {
  __shared__ float sme[8][64];
  __shared__ float shl[8][256];
  int t = threadIdx.x; int bb = blockIdx.x * 8;
  for (int i = t; i < 512; i += 256) {
    int m = i >> 6, c = i & 63;
    sme[m][c] = me[(bb + m)*64 + c];
  }
  __syncthreads();
  float a[8], cc[8];
  float ba = b_init_h[t], bc = bih1[t] + bhh1[t];
  #pragma unroll
  for (int r = 0; r < 8; ++r) { a[r] = ba; cc[r] = bc; }
  #pragma unroll 2
  for (int k = 0; k < 64; ++k) {
    float w1v = wiht[k*256 + t], w2v = wih1t[k*256 + t];
    #pragma unroll
    for (int r = 0; r < 8; ++r) {
      float m = sme[r][k];
      a[r]  += m * w1v;
      cc[r] += m * w2v;
    }
  }
  #pragma unroll
  for (int r = 0; r < 8; ++r) {
    hout[(size_t)(bb + r)*256 + t] = a[r];
    ihcout[(size_t)(bb + r)*256 + t] = cc[r];
    shl[r][t] = a[r];
  }
  __syncthreads();
  float a2[8];
  float b2 = b_init_h2[t];
  #pragma unroll
  for (int r = 0; r < 8; ++r) a2[r] = b2;
  #pragma unroll 2
  for (int k = 0; k < 256; ++k) {
    float wv = wi2t[k*256 + t];
    #pragma unroll
    for (int r = 0; r < 8; ++r) a2[r] += shl[r][k] * wv;
  }
  #pragma unroll
  for (int r = 0; r < 8; ++r) h2out[(size_t)(bb + r)*256 + t] = a2[r];
}

// ---------------- fused tail: blocks 0-31 RNN (single-barrier pipelined),
//                  blocks 32-95 lin1 split-K GEMM ----------
// RNN: interval i computes h_{i+1} = tanh(ihc + Whh1@h_i^T)  AND
//      h2_i = tanh(Wih2@h_i^T + Whh2@h2_{i-1}^T + b2), pred_{i-1} = h2_i . wfc.
// All reads are of h_i / h2_{i-1}; all writes go to opposite-parity buffers ->
// ONE __syncthreads per interval (24 total vs 46). Whh1 and Wih2 share the same
// B-fragment (h_i^T) -> one set of 8 ds_read_b128 feeds 32 MFMA.
__global__ __launch_bounds__(512, 1) void tail_kernel(
    const float* __restrict__ hin, const float* __restrict__ h2in,
    const float* __restrict__ ihc,
    const short* __restrict__ whh1b, const short* __restrict__ wih2b,
    const short* __restrict__ whh2b,
    const float* __restrict__ bih2, const float* __restrict__ bhh2,
    const float* __restrict__ w_fc, const float* __restrict__ b_fc,
    float* __restrict__ preds,
    const short* __restrict__ p3bf, const short* __restrict__ wl1p,
    const float* __restrict__ b_lin1, float* __restrict__ t1) {
  __shared__ __align__(16) short hbuf[2][16][264];   // [m][k] bf16
  __shared__ __align__(16) short h2buf[2][16][264];
  __shared__ float predsAll[23][8][16];
  int tid = threadIdx.x;

  if (blockIdx.x >= 32) {
    // ---- lin arm: split-K x4 GEMM (512x5184)x(5184x256); 2 sub-tiles/block ----
    int sub = tid >> 8, stid = tid & 255;
    int lane = stid & 63, w4 = stid >> 6;
    int quad = lane >> 4, col = lane & 15;
    int idx = (blockIdx.x - 32)*2 + sub;   // [0,128)
    int mt = idx & 7, ntb = (idx >> 3) & 3, kz = idx >> 5;
    int c0 = kz*41; if (kz == 3) c0 = 122;
    int c1 = c0 + ((kz >= 2) ? 40 : 41);
    int m0 = mt*64 + w4*16;
    floatx4 acc[4];
    #pragma unroll
    for (int t = 0; t < 4; ++t) {
      float bv = (kz == 0) ? b_lin1[ntb*64 + t*16 + col] : 0.f;
      #pragma unroll
      for (int r = 0; r < 4; ++r) acc[t][r] = bv;
    }
    const short* arow = p3bf + (size_t)(m0 + col)*5184 + quad*8;
    const short* bbase = wl1p + ((size_t)(ntb*4)*162)*512 + lane*8;
    #pragma unroll 2
    for (int c = c0; c < c1; ++c) {
      short8 a = *(const short8*)(arow + c*32);
      #pragma unroll
      for (int t = 0; t < 4; ++t) {
        short8 b = *(const short8*)(bbase + (size_t)(t*162 + c)*512);
        acc[t] = __builtin_amdgcn_mfma_f32_16x16x32_bf16(a, b, acc[t], 0, 0, 0);
      }
    }
    float* to = t1 + (size_t)kz * 131072;
    #pragma unroll
    for (int t = 0; t < 4; ++t)
      #pragma unroll
      for (int r = 0; r < 4; ++r)
        to[(size_t)(m0 + quad*4 + r)*256 + ntb*64 + t*16 + col] = acc[t][r];
    return;
  }

  // ---- RNN arm: 8 waves, each owns n-slice [w*32, w*32+32) of ALL matrices ----
  int lane = tid & 63, wid = tid >> 6;
  int quad = lane >> 4, col = lane & 15;
  int bb = blockIdx.x * 16;
  int n0 = wid * 32;
  short8 w1f[2][8], w2f[2][8], w3f[2][8];
  #pragma unroll
  for (int t = 0; t < 2; ++t)
    #pragma unroll
    for (int c = 0; c < 8; ++c) {
      int off = (n0 + t*16 + col)*256 + c*32 + quad*8;
      w1f[t][c] = *(const short8*)(whh1b + off);   // whh1: A-operand
      w2f[t][c] = *(const short8*)(wih2b + off);   // wih2
      w3f[t][c] = *(const short8*)(whh2b + off);   // whh2
    }
  float4 b2v[2], wfcv[2], ihcr[2];
  #pragma unroll
  for (int t = 0; t < 2; ++t) {
    int n = n0 + t*16 + quad*4;
    float4 bi = *(const float4*)(bih2 + n);
    float4 bh = *(const float4*)(bhh2 + n);
    b2v[t].x = bi.x + bh.x; b2v[t].y = bi.y + bh.y;
    b2v[t].z = bi.z + bh.z; b2v[t].w = bi.w + bh.w;
    wfcv[t] = *(const float4*)(w_fc + n);
    ihcr[t] = *(const float4*)(ihc + (size_t)(bb + col)*256 + n);
  }
  float bfc = b_fc[0];

  for (int i = tid; i < 4096; i += 512) {
    int m = i >> 8, k = i & 255;
    hbuf[0][m][k]  = f2bf(hin[(size_t)(bb + m)*256 + k]);
    h2buf[0][m][k] = f2bf(h2in[(size_t)(bb + m)*256 + k]);
  }
  __syncthreads();

  #pragma unroll 1
  for (int i = 0; i < 24; ++i) {
    int cur = i & 1;
    // shared B-fragments: h_i^T (feeds whh1 AND wih2)
    short8 hb[8];
    #pragma unroll
    for (int c = 0; c < 8; ++c)
      hb[c] = *(const short8*)&hbuf[cur][col][c*32 + quad*8];
    if (i < 23) {
      // h_{i+1} = tanh(ihc + whh1 @ h_i^T)
      floatx4 a1[2];
      #pragma unroll
      for (int t = 0; t < 2; ++t) {
        a1[t][0] = ihcr[t].x; a1[t][1] = ihcr[t].y;
        a1[t][2] = ihcr[t].z; a1[t][3] = ihcr[t].w;
      }
      #pragma unroll
      for (int c = 0; c < 8; ++c) {
        a1[0] = __builtin_amdgcn_mfma_f32_16x16x32_bf16(w1f[0][c], hb[c], a1[0], 0, 0, 0);
        a1[1] = __builtin_amdgcn_mfma_f32_16x16x32_bf16(w1f[1][c], hb[c], a1[1], 0, 0, 0);
      }
      #pragma unroll
      for (int t = 0; t < 2; ++t) {
        short4_t pk;
        #pragma unroll
        for (int r = 0; r < 4; ++r) pk[r] = f2bf(fast_tanh(a1[t][r]));
        *(short4_t*)&hbuf[cur ^ 1][col][n0 + t*16 + quad*4] = pk;
      }
    }
    if (i > 0) {
      // h2_i = tanh(wih2 @ h_i^T + whh2 @ h2_{i-1}^T + b2); pred_{i-1}
      floatx4 y0 = {0.f,0.f,0.f,0.f}, y1 = {0.f,0.f,0.f,0.f};
      floatx4 z0 = {0.f,0.f,0.f,0.f}, z1 = {0.f,0.f,0.f,0.f};
      #pragma unroll
      for (int c = 0; c < 8; ++c) {
        short8 gb = *(const short8*)&h2buf[cur ^ 1][col][c*32 + quad*8];
        y0 = __builtin_amdgcn_mfma_f32_16x16x32_bf16(w2f[0][c], hb[c], y0, 0, 0, 0);
        y1 = __builtin_amdgcn_mfma_f32_16x16x32_bf16(w2f[1][c], hb[c], y1, 0, 0, 0);
        z0 = __builtin_amdgcn_mfma_f32_16x16x32_bf16(w3f[0][c], gb, z0, 0, 0, 0);
        z1 = __builtin_amdgcn_mfma_f32_16x16x32_bf16(w3f[1][c], gb, z1, 0, 0, 0);
      }
      float pr = 0.f;
      {
        short4_t o0, o1;
        const float* b2a = (const float*)&b2v[0];
        const float* b2b = (const float*)&b2v[1];
        const float* wfa = (const float*)&wfcv[0];
        const float* wfb = (const float*)&wfcv[1];
        #pragma unroll
        for (int r = 0; r < 4; ++r) {
          float t0 = fast_tanh(y0[r] + z0[r] + b2a[r]);
          float t1 = fast_tanh(y1[r] + z1[r] + b2b[r]);
          o0[r] = f2bf(t0); o1[r] = f2bf(t1);
          pr += t0*wfa[r] + t1*wfb[r];
        }
        *(short4_t*)&h2buf[cur][col][n0 + quad*4] = o0;
        *(short4_t*)&h2buf[cur][col][n0 + 16 + quad*4] = o1;
      }
      pr += __shfl_xor(pr, 16, 64);
      pr += __shfl_xor(pr, 32, 64);
      if (lane < 16) predsAll[i - 1][wid][col] = pr;
    }
    __syncthreads();
  }
  if (tid < 16) {
    #pragma unroll 1
    for (int p = 0; p < 23; ++p) {
      float sv = bfc;
      #pragma unroll
      for (int w = 0; w < 8; ++w) sv += predsAll[p][w][tid];
      preds[(size_t)(bb + tid)*23 + p] = sv;
    }
  }
}

// ---------------- lin epilogue: sum partials + tanh + (256 -> 12) ----------------
__global__ __launch_bounds__(256) void lin_fin(
    const float* __restrict__ t1, const float* __restrict__ w_lin2,
    const float* __restrict__ b_lin2, float* __restrict__ outc) {
  __shared__ float st[16][257];
  int tid = threadIdx.x;
  int bb = blockIdx.x * 16;
  for (int i = tid; i < 4096; i += 256) {
    int m = i >> 8, k = i & 255;
    size_t i0 = (size_t)(bb + m)*256 + k;
    float s = t1[i0] + t1[i0 + 131072] + t1[i0 + 262144] + t1[i0 + 393216];
    st[m][k] = fast_tanh(s);
  }
  __syncthreads();
  if (tid < 192) {
    int r = tid / 12, j = tid % 12;
    float s = b_lin2[j];
    #pragma unroll 1
    for (int k = 0; k < 256; ++k) s += st[r][k] * w_lin2[j*256 + k];
    outc[(size_t)(bb + r)*12 + j] = s;
  }
}

// ---------------- launch ----------------
extern "C" void kernel_launch(void* const* d_in, const int* in_sizes, int n_in,
                              void* d_out, int out_size, void* d_ws, size_t ws_size,
                              hipStream_t stream) {
  const float* x         = (const float*)d_in[0];
  const float* w1        = (const float*)d_in[1];
  const float* b1        = (const float*)d_in[2];
  const float* w2        = (const float*)d_in[3];
  const float* b2        = (const float*)d_in[4];
  const float* w3        = (const float*)d_in[5];
  const float* b3        = (const float*)d_in[6];
  const float* wih1      = (const float*)d_in[7];
  const float* whh1      = (const float*)d_in[8];
  const float* bih1      = (const float*)d_in[9];
  const float* bhh1      = (const float*)d_in[10];
  const float* wih2      = (const float*)d_in[11];
  const float* whh2      = (const float*)d_in[12];
  const float* bih2      = (const float*)d_in[13];
  const float* bhh2      = (const float*)d_in[14];
  const float* w_init_h  = (const float*)d_in[15];
  const float* b_init_h  = (const float*)d_in[16];
  const float* w_init_h2 = (const float*)d_in[17];
  const float* b_init_h2 = (const float*)d_in[18];
  const float* w_fc      = (const float*)d_in[19];
  const float* b_fc      = (const float*)d_in[20];
  const float* w_lin1    = (const float*)d_in[21];
  const float* b_lin1    = (const float*)d_in[22];
  const float* w_lin2    = (const float*)d_in[23];
  const float* b_lin2    = (const float*)d_in[24];
  float* ws  = (float*)d_ws;
  float* out = (float*)d_out;

  prep_kernel<<<1438, 256, 0, stream>>>(w1, w2, w3, w_init_h, wih1, w_init_h2,
                                        whh1, wih2, whh2, ws);
  conv1_mfma<<<7232, 256, 0, stream>>>(x, (const short*)(ws + OFF_B1P), b1,
                                       (short*)(ws + OFF_P1),
                                       w_lin1, (short*)(ws + OFF_WL1P));
  conv2_mfma<<<1024, 256, 0, stream>>>((const short*)(ws + OFF_P1),
                                       (const short*)(ws + OFF_B2P), b2,
                                       (short*)(ws + OFF_P2));
  conv3_mfma<<<512, 256, 0, stream>>>((const short*)(ws + OFF_P2),
                                      (const short*)(ws + OFF_B3P), b3,
                                      (short*)(ws + OFF_P3BF), ws + OFF_ME);
  init_kernel<<<64, 256, 0, stream>>>(ws + OFF_ME, ws + OFF_WIHT, b_init_h, ws + OFF_WIH1T,
                                      bih1, bhh1, ws + OFF_WI2T, b_init_h2,
                                      ws + OFF_H, ws + OFF_H2, ws + OFF_IHC);
  tail_kernel<<<96, 512, 0, stream>>>(ws + OFF_H, ws + OFF_H2, ws + OFF_IHC,
                                      (const short*)(ws + OFF_WHH1B),
                                      (const short*)(ws + OFF_WIH2B),
                                      (const short*)(ws + OFF_WHH2B),
                                      bih2, bhh2, w_fc, b_fc, out,
                                      (const short*)(ws + OFF_P3BF),
                                      (const short*)(ws + OFF_WL1P),
                                      b_lin1, ws + OFF_T1);
  lin_fin<<<32, 256, 0, stream>>>(ws + OFF_T1, w_lin2, b_lin2, out + 11776);
}